// Round 1
// baseline (4494.087 us; speedup 1.0000x reference)
//
#include <hip/hip_runtime.h>
#include <math.h>

// ---------------- dims (fixed by the problem) ----------------
#define D_IN     1280
#define D_MODEL  512
#define N_LAYER  4
#define D_STATE  16
#define D_CONV   4
#define D_INNER  1024
#define DT_RANK  32
#define BB       8
#define LL       512
#define M_ROWS   (BB*LL)          // 4096

// ---------------- GEMM: C[M,N] = A[M,K(lda)] @ W[N,K]^T (+bias)(+act)(+accum C) ----
// BM=BN=64, BK=16, 256 threads, 4x4 micro-tile per thread.
template<bool BIAS, bool ACCUM, int ACT>
__global__ __launch_bounds__(256) void gemm_tn(
    const float* __restrict__ A, int lda,
    const float* __restrict__ W,          // [N,K] dense
    const float* __restrict__ bias,       // [N] or null
    float* __restrict__ C,                // [M,N] dense
    int M, int N, int K)
{
    constexpr int BM = 64, BN = 64, BK = 16;
    __shared__ float As[BK][BM + 4];
    __shared__ float Ws[BK][BN + 4];
    const int tid = threadIdx.x;
    const int bm = blockIdx.y * BM;
    const int bn = blockIdx.x * BN;
    const int lr = tid >> 2;            // 0..63
    const int kg = (tid & 3) * 4;       // 0,4,8,12
    const float* Aptr = A + (size_t)(bm + lr) * lda + kg;
    const float* Wptr = W + (size_t)(bn + lr) * K + kg;
    const int tx = tid & 15, ty = tid >> 4;
    float acc[4][4] = {};

    for (int kk = 0; kk < K; kk += BK) {
        float4 a4 = *(const float4*)(Aptr + kk);
        float4 w4 = *(const float4*)(Wptr + kk);
        __syncthreads();
        As[kg + 0][lr] = a4.x; As[kg + 1][lr] = a4.y;
        As[kg + 2][lr] = a4.z; As[kg + 3][lr] = a4.w;
        Ws[kg + 0][lr] = w4.x; Ws[kg + 1][lr] = w4.y;
        Ws[kg + 2][lr] = w4.z; Ws[kg + 3][lr] = w4.w;
        __syncthreads();
#pragma unroll
        for (int k = 0; k < BK; ++k) {
            float4 av = *(const float4*)&As[k][ty * 4];
            float4 wv = *(const float4*)&Ws[k][tx * 4];
            float a[4] = {av.x, av.y, av.z, av.w};
            float w[4] = {wv.x, wv.y, wv.z, wv.w};
#pragma unroll
            for (int i = 0; i < 4; ++i)
#pragma unroll
                for (int j = 0; j < 4; ++j) acc[i][j] += a[i] * w[j];
        }
    }

#pragma unroll
    for (int i = 0; i < 4; ++i) {
        int m = bm + ty * 4 + i;
        int n = bn + tx * 4;
        float r[4] = {acc[i][0], acc[i][1], acc[i][2], acc[i][3]};
        if (BIAS) {
            float4 bv = *(const float4*)(bias + n);
            r[0] += bv.x; r[1] += bv.y; r[2] += bv.z; r[3] += bv.w;
        }
        if (ACT == 1) {  // softplus
#pragma unroll
            for (int j = 0; j < 4; ++j)
                r[j] = (r[j] > 20.f) ? r[j] : log1pf(expf(r[j]));
        }
        float* cp = C + (size_t)m * N + n;
        if (ACCUM) {
            float4 cv = *(const float4*)cp;
            r[0] += cv.x; r[1] += cv.y; r[2] += cv.z; r[3] += cv.w;
        }
        *(float4*)cp = make_float4(r[0], r[1], r[2], r[3]);
    }
}

// ---------------- RMSNorm over last dim D=512, one block per row --------------
__global__ __launch_bounds__(256) void rmsnorm_k(
    const float* __restrict__ X, const float* __restrict__ w,
    float* __restrict__ Y)
{
    const int r = blockIdx.x;
    const float* x = X + (size_t)r * D_MODEL;
    float2 v = *(const float2*)(x + threadIdx.x * 2);
    float ss = v.x * v.x + v.y * v.y;
#pragma unroll
    for (int off = 32; off > 0; off >>= 1) ss += __shfl_down(ss, off);
    __shared__ float wsum[4];
    if ((threadIdx.x & 63) == 0) wsum[threadIdx.x >> 6] = ss;
    __syncthreads();
    float tot = wsum[0] + wsum[1] + wsum[2] + wsum[3];
    float rs = rsqrtf(tot * (1.f / D_MODEL) + 1e-5f);
    float2 wv = *(const float2*)(w + threadIdx.x * 2);
    float2 o;
    o.x = v.x * rs * wv.x;
    o.y = v.y * rs * wv.y;
    *(float2*)(Y + (size_t)r * D_MODEL + threadIdx.x * 2) = o;
}

// ---------------- depthwise causal conv1d (k=4) + bias + silu -----------------
// input xs = xr[:, :D_INNER] with row stride 2*D_INNER; output dense [M,D_INNER]
__global__ __launch_bounds__(256) void conv_silu_k(
    const float* __restrict__ xr, const float* __restrict__ cw,
    const float* __restrict__ cb, float* __restrict__ xs)
{
    const int idx = blockIdx.x * 256 + threadIdx.x;   // M*D_INNER
    const int d = idx & (D_INNER - 1);
    const int r = idx >> 10;          // b*L + l
    const int l = r & (LL - 1);
    const float* base = xr + (size_t)r * (2 * D_INNER) + d;
    float4 w = *(const float4*)(cw + d * 4);
    float acc = cb[d];
    if (l >= 3) acc += base[-3 * 2 * D_INNER] * w.x;
    if (l >= 2) acc += base[-2 * 2 * D_INNER] * w.y;
    if (l >= 1) acc += base[-1 * 2 * D_INNER] * w.z;
    acc += base[0] * w.w;
    xs[idx] = acc / (1.f + expf(-acc));   // silu
}

// ---------------- selective scan: one thread per (b,d), serial over L ---------
// also applies +xs*Dp and *silu(res) gate.
__global__ __launch_bounds__(256) void scan_k(
    const float* __restrict__ delta,  // [M, D_INNER]
    const float* __restrict__ xs,     // [M, D_INNER]
    const float* __restrict__ dbc,    // [M, 64]: B at col 32..47, C at 48..63
    const float* __restrict__ xr,     // res at col D_INNER+d, stride 2*D_INNER
    const float* __restrict__ A_log,  // [D_INNER, D_STATE]
    const float* __restrict__ Dp,     // [D_INNER]
    float* __restrict__ y)            // [M, D_INNER]
{
    const int b = blockIdx.x >> 2;
    const int d = ((blockIdx.x & 3) << 8) + threadIdx.x;
    float A[D_STATE];
#pragma unroll
    for (int n = 0; n < D_STATE; ++n) A[n] = -expf(A_log[d * D_STATE + n]);
    const float Dd = Dp[d];
    float h[D_STATE] = {};
    __shared__ float sBC[32];
    const int r0 = b * LL;
    for (int l = 0; l < LL; ++l) {
        const int r = r0 + l;
        __syncthreads();
        if (threadIdx.x < 32) sBC[threadIdx.x] = dbc[(size_t)r * 64 + 32 + threadIdx.x];
        __syncthreads();
        const float dt = delta[(size_t)r * D_INNER + d];
        const float x  = xs[(size_t)r * D_INNER + d];
        const float dx = dt * x;
        float yv = 0.f;
#pragma unroll
        for (int n = 0; n < D_STATE; ++n) {
            float dA = expf(dt * A[n]);
            h[n] = dA * h[n] + dx * sBC[n];
            yv += h[n] * sBC[16 + n];
        }
        const float res = xr[(size_t)r * (2 * D_INNER) + D_INNER + d];
        const float g = res / (1.f + expf(-res));
        y[(size_t)r * D_INNER + d] = (yv + x * Dd) * g;
    }
}

// ---------------- final stats: mean + std(ddof=1) over L per (b, dm) ----------
__global__ __launch_bounds__(512) void stats_k(
    const float* __restrict__ m, float* __restrict__ out)
{
    const int b = blockIdx.x;
    const int dm = threadIdx.x;
    const float* p = m + (size_t)b * LL * D_MODEL + dm;
    float s = 0.f;
    for (int l = 0; l < LL; ++l) s += p[(size_t)l * D_MODEL];
    const float mean = s * (1.f / LL);
    float ss = 0.f;
    for (int l = 0; l < LL; ++l) {
        float v = p[(size_t)l * D_MODEL] - mean;
        ss += v * v;
    }
    out[b * (2 * D_MODEL) + dm] = mean;
    out[b * (2 * D_MODEL) + D_MODEL + dm] = sqrtf(ss * (1.f / (LL - 1)));
}

// ---------------- host ----------------
extern "C" void kernel_launch(void* const* d_in, const int* in_sizes, int n_in,
                              void* d_out, int out_size, void* d_ws, size_t ws_size,
                              hipStream_t stream) {
    const float* x            = (const float*)d_in[0];
    const float* proj_w       = (const float*)d_in[1];
    const float* proj_b       = (const float*)d_in[2];
    const float* norm_w       = (const float*)d_in[3];
    const float* in_w         = (const float*)d_in[4];
    const float* conv_w       = (const float*)d_in[5];
    const float* conv_b       = (const float*)d_in[6];
    const float* xproj_w      = (const float*)d_in[7];
    const float* dt_w         = (const float*)d_in[8];
    const float* dt_b         = (const float*)d_in[9];
    const float* A_log        = (const float*)d_in[10];
    const float* Dp           = (const float*)d_in[11];
    const float* out_w        = (const float*)d_in[12];
    const float* final_norm_w = (const float*)d_in[13];

    float* ws   = (float*)d_ws;
    float* h    = ws;                          // [4096,512]
    float* xn   = h    + (size_t)M_ROWS * D_MODEL;       // [4096,512]
    float* xr   = xn   + (size_t)M_ROWS * D_MODEL;       // [4096,2048]
    float* xs   = xr   + (size_t)M_ROWS * 2 * D_INNER;   // [4096,1024]
    float* dbc  = xs   + (size_t)M_ROWS * D_INNER;       // [4096,64]
    float* dlt  = dbc  + (size_t)M_ROWS * 64;            // [4096,1024]
    float* y    = dlt  + (size_t)M_ROWS * D_INNER;       // [4096,1024]

    // h = x @ proj_w^T + proj_b
    gemm_tn<true, false, 0><<<dim3(D_MODEL / 64, M_ROWS / 64), 256, 0, stream>>>(
        x, D_IN, proj_w, proj_b, h, M_ROWS, D_MODEL, D_IN);

    for (int i = 0; i < N_LAYER; ++i) {
        rmsnorm_k<<<M_ROWS, 256, 0, stream>>>(h, norm_w + (size_t)i * D_MODEL, xn);
        gemm_tn<false, false, 0><<<dim3(2 * D_INNER / 64, M_ROWS / 64), 256, 0, stream>>>(
            xn, D_MODEL, in_w + (size_t)i * 2 * D_INNER * D_MODEL, nullptr, xr,
            M_ROWS, 2 * D_INNER, D_MODEL);
        conv_silu_k<<<M_ROWS * D_INNER / 256, 256, 0, stream>>>(
            xr, conv_w + (size_t)i * D_INNER * D_CONV, conv_b + (size_t)i * D_INNER, xs);
        gemm_tn<false, false, 0><<<dim3(64 / 64, M_ROWS / 64), 256, 0, stream>>>(
            xs, D_INNER, xproj_w + (size_t)i * 64 * D_INNER, nullptr, dbc,
            M_ROWS, 64, D_INNER);
        gemm_tn<true, false, 1><<<dim3(D_INNER / 64, M_ROWS / 64), 256, 0, stream>>>(
            dbc, 64, dt_w + (size_t)i * D_INNER * DT_RANK, dt_b + (size_t)i * D_INNER,
            dlt, M_ROWS, D_INNER, DT_RANK);
        scan_k<<<BB * (D_INNER / 256), 256, 0, stream>>>(
            dlt, xs, dbc, xr, A_log + (size_t)i * D_INNER * D_STATE,
            Dp + (size_t)i * D_INNER, y);
        gemm_tn<false, true, 0><<<dim3(D_MODEL / 64, M_ROWS / 64), 256, 0, stream>>>(
            y, D_INNER, out_w + (size_t)i * D_MODEL * D_INNER, nullptr, h,
            M_ROWS, D_MODEL, D_INNER);
    }

    rmsnorm_k<<<M_ROWS, 256, 0, stream>>>(h, final_norm_w, xn);
    stats_k<<<BB, D_MODEL, 0, stream>>>(xn, (float*)d_out);
}

// Round 2
// 1815.319 us; speedup vs baseline: 2.4756x; 2.4756x over previous
//
#include <hip/hip_runtime.h>
#include <math.h>

// ---------------- dims (fixed by the problem) ----------------
#define D_IN     1280
#define D_MODEL  512
#define N_LAYER  4
#define D_STATE  16
#define D_CONV   4
#define D_INNER  1024
#define DT_RANK  32
#define BB       8
#define LL       512
#define M_ROWS   (BB*LL)          // 4096

// ---------------- GEMM: C[M,N] = A[M,K(lda)] @ W[N,K]^T (+bias)(+act)(+accum C) ----
// BM=BN=64, BK=16, 256 threads, 4x4 micro-tile per thread.
template<bool BIAS, bool ACCUM, int ACT>
__global__ __launch_bounds__(256) void gemm_tn(
    const float* __restrict__ A, int lda,
    const float* __restrict__ W,          // [N,K] dense
    const float* __restrict__ bias,       // [N] or null
    float* __restrict__ C,                // [M,N] dense
    int M, int N, int K)
{
    constexpr int BM = 64, BN = 64, BK = 16;
    __shared__ float As[BK][BM + 4];
    __shared__ float Ws[BK][BN + 4];
    const int tid = threadIdx.x;
    const int bm = blockIdx.y * BM;
    const int bn = blockIdx.x * BN;
    const int lr = tid >> 2;            // 0..63
    const int kg = (tid & 3) * 4;       // 0,4,8,12
    const float* Aptr = A + (size_t)(bm + lr) * lda + kg;
    const float* Wptr = W + (size_t)(bn + lr) * K + kg;
    const int tx = tid & 15, ty = tid >> 4;
    float acc[4][4] = {};

    for (int kk = 0; kk < K; kk += BK) {
        float4 a4 = *(const float4*)(Aptr + kk);
        float4 w4 = *(const float4*)(Wptr + kk);
        __syncthreads();
        As[kg + 0][lr] = a4.x; As[kg + 1][lr] = a4.y;
        As[kg + 2][lr] = a4.z; As[kg + 3][lr] = a4.w;
        Ws[kg + 0][lr] = w4.x; Ws[kg + 1][lr] = w4.y;
        Ws[kg + 2][lr] = w4.z; Ws[kg + 3][lr] = w4.w;
        __syncthreads();
#pragma unroll
        for (int k = 0; k < BK; ++k) {
            float4 av = *(const float4*)&As[k][ty * 4];
            float4 wv = *(const float4*)&Ws[k][tx * 4];
            float a[4] = {av.x, av.y, av.z, av.w};
            float w[4] = {wv.x, wv.y, wv.z, wv.w};
#pragma unroll
            for (int i = 0; i < 4; ++i)
#pragma unroll
                for (int j = 0; j < 4; ++j) acc[i][j] += a[i] * w[j];
        }
    }

#pragma unroll
    for (int i = 0; i < 4; ++i) {
        int m = bm + ty * 4 + i;
        int n = bn + tx * 4;
        float r[4] = {acc[i][0], acc[i][1], acc[i][2], acc[i][3]};
        if (BIAS) {
            float4 bv = *(const float4*)(bias + n);
            r[0] += bv.x; r[1] += bv.y; r[2] += bv.z; r[3] += bv.w;
        }
        if (ACT == 1) {  // softplus
#pragma unroll
            for (int j = 0; j < 4; ++j)
                r[j] = (r[j] > 20.f) ? r[j] : log1pf(expf(r[j]));
        }
        float* cp = C + (size_t)m * N + n;
        if (ACCUM) {
            float4 cv = *(const float4*)cp;
            r[0] += cv.x; r[1] += cv.y; r[2] += cv.z; r[3] += cv.w;
        }
        *(float4*)cp = make_float4(r[0], r[1], r[2], r[3]);
    }
}

// ---------------- RMSNorm over last dim D=512, one block per row --------------
__global__ __launch_bounds__(256) void rmsnorm_k(
    const float* __restrict__ X, const float* __restrict__ w,
    float* __restrict__ Y)
{
    const int r = blockIdx.x;
    const float* x = X + (size_t)r * D_MODEL;
    float2 v = *(const float2*)(x + threadIdx.x * 2);
    float ss = v.x * v.x + v.y * v.y;
#pragma unroll
    for (int off = 32; off > 0; off >>= 1) ss += __shfl_down(ss, off);
    __shared__ float wsum[4];
    if ((threadIdx.x & 63) == 0) wsum[threadIdx.x >> 6] = ss;
    __syncthreads();
    float tot = wsum[0] + wsum[1] + wsum[2] + wsum[3];
    float rs = rsqrtf(tot * (1.f / D_MODEL) + 1e-5f);
    float2 wv = *(const float2*)(w + threadIdx.x * 2);
    float2 o;
    o.x = v.x * rs * wv.x;
    o.y = v.y * rs * wv.y;
    *(float2*)(Y + (size_t)r * D_MODEL + threadIdx.x * 2) = o;
}

// ---------------- depthwise causal conv1d (k=4) + bias + silu -----------------
__global__ __launch_bounds__(256) void conv_silu_k(
    const float* __restrict__ xr, const float* __restrict__ cw,
    const float* __restrict__ cb, float* __restrict__ xs)
{
    const int idx = blockIdx.x * 256 + threadIdx.x;   // M*D_INNER
    const int d = idx & (D_INNER - 1);
    const int r = idx >> 10;          // b*L + l
    const int l = r & (LL - 1);
    const float* base = xr + (size_t)r * (2 * D_INNER) + d;
    float4 w = *(const float4*)(cw + d * 4);
    float acc = cb[d];
    if (l >= 3) acc += base[-3 * 2 * D_INNER] * w.x;
    if (l >= 2) acc += base[-2 * 2 * D_INNER] * w.y;
    if (l >= 1) acc += base[-1 * 2 * D_INNER] * w.z;
    acc += base[0] * w.w;
    xs[idx] = acc / (1.f + __expf(-acc));   // silu
}

// ---------------- selective scan: one thread per (b,d,n) ----------------------
// 16 lanes (n=0..15) per d; shfl_xor reduce for y = sum_n h[n]*C[n].
// Prefetches next timestep's operands to hide L2 latency. All one-row
// over-reads on the last iteration stay inside d_ws (buffers are adjacent).
__global__ __launch_bounds__(256) void scan_k(
    const float* __restrict__ delta,  // [M, D_INNER]
    const float* __restrict__ xs,     // [M, D_INNER]
    const float* __restrict__ dbc,    // [M, 64]: B at col 32..47, C at 48..63
    const float* __restrict__ xr,     // res at col D_INNER+d, stride 2*D_INNER
    const float* __restrict__ A_log,  // [D_INNER, D_STATE]
    const float* __restrict__ Dp,     // [D_INNER]
    float* __restrict__ y)            // [M, D_INNER]
{
    const int b = blockIdx.x >> 6;                       // 64 blocks per batch
    const int d = ((blockIdx.x & 63) << 4) + (threadIdx.x >> 4);
    const int n = threadIdx.x & 15;

    const float A  = -__expf(A_log[d * D_STATE + n]);
    const float Dd = Dp[d];

    const int r0 = b * LL;
    const float* pd = delta + (size_t)r0 * D_INNER + d;
    const float* px = xs    + (size_t)r0 * D_INNER + d;
    const float* pB = dbc   + (size_t)r0 * 64 + 32 + n;
    const float* pC = dbc   + (size_t)r0 * 64 + 48 + n;
    const float* pr = xr    + (size_t)r0 * 2 * D_INNER + D_INNER + d;
    float*       py = y     + (size_t)r0 * D_INNER + d;

    float dt = *pd, x = *px, Bn = *pB, Cn = *pC, res = *pr;
    float h = 0.f;

    for (int l = 0; l < LL; ++l) {
        // prefetch next timestep (last iteration over-reads stay inside d_ws)
        pd += D_INNER; px += D_INNER; pB += 64; pC += 64; pr += 2 * D_INNER;
        const float dt_n = *pd, x_n = *px, Bn_n = *pB, Cn_n = *pC, res_n = *pr;

        const float dA = __expf(dt * A);
        h = fmaf(dA, h, (dt * x) * Bn);
        float p = h * Cn;
        p += __shfl_xor(p, 1, 16);
        p += __shfl_xor(p, 2, 16);
        p += __shfl_xor(p, 4, 16);
        p += __shfl_xor(p, 8, 16);
        if (n == 0) {
            const float g = res / (1.f + __expf(-res));
            *py = (p + x * Dd) * g;
        }
        py += D_INNER;
        dt = dt_n; x = x_n; Bn = Bn_n; Cn = Cn_n; res = res_n;
    }
}

// ---------------- final stats: mean + std(ddof=1) over L per (b, dm) ----------
__global__ __launch_bounds__(512) void stats_k(
    const float* __restrict__ m, float* __restrict__ out)
{
    const int b = blockIdx.x;
    const int dm = threadIdx.x;
    const float* p = m + (size_t)b * LL * D_MODEL + dm;
    float s = 0.f;
    for (int l = 0; l < LL; ++l) s += p[(size_t)l * D_MODEL];
    const float mean = s * (1.f / LL);
    float ss = 0.f;
    for (int l = 0; l < LL; ++l) {
        float v = p[(size_t)l * D_MODEL] - mean;
        ss += v * v;
    }
    out[b * (2 * D_MODEL) + dm] = mean;
    out[b * (2 * D_MODEL) + D_MODEL + dm] = sqrtf(ss * (1.f / (LL - 1)));
}

// ---------------- host ----------------
extern "C" void kernel_launch(void* const* d_in, const int* in_sizes, int n_in,
                              void* d_out, int out_size, void* d_ws, size_t ws_size,
                              hipStream_t stream) {
    const float* x            = (const float*)d_in[0];
    const float* proj_w       = (const float*)d_in[1];
    const float* proj_b       = (const float*)d_in[2];
    const float* norm_w       = (const float*)d_in[3];
    const float* in_w         = (const float*)d_in[4];
    const float* conv_w       = (const float*)d_in[5];
    const float* conv_b       = (const float*)d_in[6];
    const float* xproj_w      = (const float*)d_in[7];
    const float* dt_w         = (const float*)d_in[8];
    const float* dt_b         = (const float*)d_in[9];
    const float* A_log        = (const float*)d_in[10];
    const float* Dp           = (const float*)d_in[11];
    const float* out_w        = (const float*)d_in[12];
    const float* final_norm_w = (const float*)d_in[13];

    float* ws   = (float*)d_ws;
    float* h    = ws;                          // [4096,512]
    float* xn   = h    + (size_t)M_ROWS * D_MODEL;       // [4096,512]
    float* xr   = xn   + (size_t)M_ROWS * D_MODEL;       // [4096,2048]
    float* xs   = xr   + (size_t)M_ROWS * 2 * D_INNER;   // [4096,1024]
    float* dbc  = xs   + (size_t)M_ROWS * D_INNER;       // [4096,64]
    float* dlt  = dbc  + (size_t)M_ROWS * 64;            // [4096,1024]
    float* y    = dlt  + (size_t)M_ROWS * D_INNER;       // [4096,1024]

    // h = x @ proj_w^T + proj_b
    gemm_tn<true, false, 0><<<dim3(D_MODEL / 64, M_ROWS / 64), 256, 0, stream>>>(
        x, D_IN, proj_w, proj_b, h, M_ROWS, D_MODEL, D_IN);

    for (int i = 0; i < N_LAYER; ++i) {
        rmsnorm_k<<<M_ROWS, 256, 0, stream>>>(h, norm_w + (size_t)i * D_MODEL, xn);
        gemm_tn<false, false, 0><<<dim3(2 * D_INNER / 64, M_ROWS / 64), 256, 0, stream>>>(
            xn, D_MODEL, in_w + (size_t)i * 2 * D_INNER * D_MODEL, nullptr, xr,
            M_ROWS, 2 * D_INNER, D_MODEL);
        conv_silu_k<<<M_ROWS * D_INNER / 256, 256, 0, stream>>>(
            xr, conv_w + (size_t)i * D_INNER * D_CONV, conv_b + (size_t)i * D_INNER, xs);
        gemm_tn<false, false, 0><<<dim3(64 / 64, M_ROWS / 64), 256, 0, stream>>>(
            xs, D_INNER, xproj_w + (size_t)i * 64 * D_INNER, nullptr, dbc,
            M_ROWS, 64, D_INNER);
        gemm_tn<true, false, 1><<<dim3(D_INNER / 64, M_ROWS / 64), 256, 0, stream>>>(
            dbc, 64, dt_w + (size_t)i * D_INNER * DT_RANK, dt_b + (size_t)i * D_INNER,
            dlt, M_ROWS, D_INNER, DT_RANK);
        scan_k<<<BB * (D_INNER / 16), 256, 0, stream>>>(
            dlt, xs, dbc, xr, A_log + (size_t)i * D_INNER * D_STATE,
            Dp + (size_t)i * D_INNER, y);
        gemm_tn<false, true, 0><<<dim3(D_MODEL / 64, M_ROWS / 64), 256, 0, stream>>>(
            y, D_INNER, out_w + (size_t)i * D_MODEL * D_INNER, nullptr, h,
            M_ROWS, D_MODEL, D_INNER);
    }

    rmsnorm_k<<<M_ROWS, 256, 0, stream>>>(h, final_norm_w, xn);
    stats_k<<<BB, D_MODEL, 0, stream>>>(xn, (float*)d_out);
}

// Round 3
// 1393.721 us; speedup vs baseline: 3.2245x; 1.3025x over previous
//
#include <hip/hip_runtime.h>
#include <math.h>

// ---------------- dims (fixed by the problem) ----------------
#define D_IN     1280
#define D_MODEL  512
#define N_LAYER  4
#define D_STATE  16
#define D_CONV   4
#define D_INNER  1024
#define DT_RANK  32
#define BB       8
#define LL       512
#define M_ROWS   (BB*LL)          // 4096

typedef short bf16x8 __attribute__((ext_vector_type(8)));
typedef float f32x4  __attribute__((ext_vector_type(4)));

__device__ __forceinline__ ushort f2bf(float f) {
    unsigned u = __float_as_uint(f);
    u = (u + 0x7FFF + ((u >> 16) & 1)) >> 16;   // RNE
    return (ushort)u;
}

// ---------------- fp32 -> bf16 cast (n multiple of 4) ----------------
__global__ __launch_bounds__(256) void cast_bf16_k(
    const float* __restrict__ in, ushort* __restrict__ out, int n4)
{
    int i = blockIdx.x * 256 + threadIdx.x;
    if (i < n4) {
        float4 v = *(const float4*)(in + (size_t)i * 4);
        *(ushort4*)(out + (size_t)i * 4) =
            make_ushort4(f2bf(v.x), f2bf(v.y), f2bf(v.z), f2bf(v.w));
    }
}

// ---------------- bf16 MFMA GEMM: C[M,N] = A[M,K] @ W[N,K]^T ------------------
// BM=128, BK=32, 256 threads = 4 waves (2x2), wave tile 64 x BN/2.
template<int BN, bool BIAS, bool ACCUM>
__global__ __launch_bounds__(256) void gemm_bf16(
    const ushort* __restrict__ A, const ushort* __restrict__ W,
    const float* __restrict__ bias, float* __restrict__ C,
    int M, int N, int K)
{
    constexpr int BM = 128, BK = 32;
    constexpr int LDA = BK + 8;           // 40 ushorts = 80 B rows (16B-aligned)
    constexpr int FN = BN / 32;           // N-frags per wave
    constexpr int HN = BN / 2;            // wave N-tile
    __shared__ ushort lA[BM * LDA];
    __shared__ ushort lB[BN * LDA];
    const int tid  = threadIdx.x;
    const int lane = tid & 63;
    const int wid  = tid >> 6;
    const int wr = wid >> 1, wc = wid & 1;
    const int bm = blockIdx.y * BM, bn = blockIdx.x * BN;
    const int l15 = lane & 15, lk = lane >> 4;     // lk = 0..3

    f32x4 acc[4][FN];
#pragma unroll
    for (int i = 0; i < 4; ++i)
#pragma unroll
        for (int j = 0; j < FN; ++j) acc[i][j] = (f32x4)0.f;

    for (int kk = 0; kk < K; kk += BK) {
        uint4 va[2], vb[BN / 64 ? BN / 64 : 1];
#pragma unroll
        for (int i = 0; i < 2; ++i) {
            int c = i * 256 + tid, row = c >> 2, k0 = (c & 3) * 8;
            va[i] = *(const uint4*)(A + (size_t)(bm + row) * K + kk + k0);
        }
#pragma unroll
        for (int i = 0; i < BN / 64; ++i) {
            int c = i * 256 + tid, row = c >> 2, k0 = (c & 3) * 8;
            vb[i] = *(const uint4*)(W + (size_t)(bn + row) * K + kk + k0);
        }
        __syncthreads();
#pragma unroll
        for (int i = 0; i < 2; ++i) {
            int c = i * 256 + tid, row = c >> 2, k0 = (c & 3) * 8;
            *(uint4*)&lA[row * LDA + k0] = va[i];
        }
#pragma unroll
        for (int i = 0; i < BN / 64; ++i) {
            int c = i * 256 + tid, row = c >> 2, k0 = (c & 3) * 8;
            *(uint4*)&lB[row * LDA + k0] = vb[i];
        }
        __syncthreads();

        bf16x8 af[4], bw[FN];
#pragma unroll
        for (int fm = 0; fm < 4; ++fm)
            af[fm] = *(const bf16x8*)&lA[(wr * 64 + fm * 16 + l15) * LDA + lk * 8];
#pragma unroll
        for (int fn = 0; fn < FN; ++fn)
            bw[fn] = *(const bf16x8*)&lB[(wc * HN + fn * 16 + l15) * LDA + lk * 8];
#pragma unroll
        for (int fm = 0; fm < 4; ++fm)
#pragma unroll
            for (int fn = 0; fn < FN; ++fn)
                acc[fm][fn] = __builtin_amdgcn_mfma_f32_16x16x32_bf16(
                    af[fm], bw[fn], acc[fm][fn], 0, 0, 0);
    }

#pragma unroll
    for (int fm = 0; fm < 4; ++fm) {
#pragma unroll
        for (int fn = 0; fn < FN; ++fn) {
            int col = bn + wc * HN + fn * 16 + l15;
            float bv = BIAS ? bias[col] : 0.f;
#pragma unroll
            for (int j = 0; j < 4; ++j) {
                int row = bm + wr * 64 + fm * 16 + lk * 4 + j;
                float r = acc[fm][fn][j] + bv;
                float* cp = C + (size_t)row * N + col;
                if (ACCUM) r += *cp;
                *cp = r;
            }
        }
    }
}

// ---------------- fp32 GEMM (kept for small N / small K) ----------------------
template<bool BIAS, bool ACCUM, int ACT>
__global__ __launch_bounds__(256) void gemm_tn(
    const float* __restrict__ A, int lda,
    const float* __restrict__ W, const float* __restrict__ bias,
    float* __restrict__ C, int M, int N, int K)
{
    constexpr int BM = 64, BN = 64, BK = 16;
    __shared__ float As[BK][BM + 4];
    __shared__ float Ws[BK][BN + 4];
    const int tid = threadIdx.x;
    const int bm = blockIdx.y * BM;
    const int bn = blockIdx.x * BN;
    const int lr = tid >> 2;
    const int kg = (tid & 3) * 4;
    const float* Aptr = A + (size_t)(bm + lr) * lda + kg;
    const float* Wptr = W + (size_t)(bn + lr) * K + kg;
    const int tx = tid & 15, ty = tid >> 4;
    float acc[4][4] = {};

    for (int kk = 0; kk < K; kk += BK) {
        float4 a4 = *(const float4*)(Aptr + kk);
        float4 w4 = *(const float4*)(Wptr + kk);
        __syncthreads();
        As[kg + 0][lr] = a4.x; As[kg + 1][lr] = a4.y;
        As[kg + 2][lr] = a4.z; As[kg + 3][lr] = a4.w;
        Ws[kg + 0][lr] = w4.x; Ws[kg + 1][lr] = w4.y;
        Ws[kg + 2][lr] = w4.z; Ws[kg + 3][lr] = w4.w;
        __syncthreads();
#pragma unroll
        for (int k = 0; k < BK; ++k) {
            float4 av = *(const float4*)&As[k][ty * 4];
            float4 wv = *(const float4*)&Ws[k][tx * 4];
            float a[4] = {av.x, av.y, av.z, av.w};
            float w[4] = {wv.x, wv.y, wv.z, wv.w};
#pragma unroll
            for (int i = 0; i < 4; ++i)
#pragma unroll
                for (int j = 0; j < 4; ++j) acc[i][j] += a[i] * w[j];
        }
    }
#pragma unroll
    for (int i = 0; i < 4; ++i) {
        int m = bm + ty * 4 + i;
        int n = bn + tx * 4;
        float r[4] = {acc[i][0], acc[i][1], acc[i][2], acc[i][3]};
        if (BIAS) {
            float4 bv = *(const float4*)(bias + n);
            r[0] += bv.x; r[1] += bv.y; r[2] += bv.z; r[3] += bv.w;
        }
        if (ACT == 1) {
#pragma unroll
            for (int j = 0; j < 4; ++j)
                r[j] = (r[j] > 20.f) ? r[j] : log1pf(expf(r[j]));
        }
        float* cp = C + (size_t)m * N + n;
        if (ACCUM) {
            float4 cv = *(const float4*)cp;
            r[0] += cv.x; r[1] += cv.y; r[2] += cv.z; r[3] += cv.w;
        }
        *(float4*)cp = make_float4(r[0], r[1], r[2], r[3]);
    }
}

// ---------------- RMSNorm over last dim D=512 ---------------------------------
template<bool BF16OUT>
__global__ __launch_bounds__(256) void rmsnorm_k(
    const float* __restrict__ X, const float* __restrict__ w,
    float* __restrict__ Yf, ushort* __restrict__ Yb)
{
    const int r = blockIdx.x;
    const float* x = X + (size_t)r * D_MODEL;
    float2 v = *(const float2*)(x + threadIdx.x * 2);
    float ss = v.x * v.x + v.y * v.y;
#pragma unroll
    for (int off = 32; off > 0; off >>= 1) ss += __shfl_down(ss, off);
    __shared__ float wsum[4];
    if ((threadIdx.x & 63) == 0) wsum[threadIdx.x >> 6] = ss;
    __syncthreads();
    float tot = wsum[0] + wsum[1] + wsum[2] + wsum[3];
    float rs = rsqrtf(tot * (1.f / D_MODEL) + 1e-5f);
    float2 wv = *(const float2*)(w + threadIdx.x * 2);
    float a = v.x * rs * wv.x, b = v.y * rs * wv.y;
    if (BF16OUT)
        *(ushort2*)(Yb + (size_t)r * D_MODEL + threadIdx.x * 2) =
            make_ushort2(f2bf(a), f2bf(b));
    else
        *(float2*)(Yf + (size_t)r * D_MODEL + threadIdx.x * 2) = make_float2(a, b);
}

// ---------------- depthwise causal conv1d (k=4) + bias + silu -----------------
__global__ __launch_bounds__(256) void conv_silu_k(
    const float* __restrict__ xr, const float* __restrict__ cw,
    const float* __restrict__ cb, float* __restrict__ xs)
{
    const int idx = blockIdx.x * 256 + threadIdx.x;
    const int d = idx & (D_INNER - 1);
    const int r = idx >> 10;
    const int l = r & (LL - 1);
    const float* base = xr + (size_t)r * (2 * D_INNER) + d;
    float4 w = *(const float4*)(cw + d * 4);
    float acc = cb[d];
    if (l >= 3) acc += base[-3 * 2 * D_INNER] * w.x;
    if (l >= 2) acc += base[-2 * 2 * D_INNER] * w.y;
    if (l >= 1) acc += base[-1 * 2 * D_INNER] * w.z;
    acc += base[0] * w.w;
    xs[idx] = acc / (1.f + __expf(-acc));
}

// ---------------- selective scan: one thread per (b,d,n); bf16 y out ----------
__global__ __launch_bounds__(256) void scan_k(
    const float* __restrict__ delta, const float* __restrict__ xs,
    const float* __restrict__ dbc, const float* __restrict__ xr,
    const float* __restrict__ A_log, const float* __restrict__ Dp,
    ushort* __restrict__ yb)
{
    const int b = blockIdx.x >> 6;
    const int d = ((blockIdx.x & 63) << 4) + (threadIdx.x >> 4);
    const int n = threadIdx.x & 15;

    const float A  = -__expf(A_log[d * D_STATE + n]);
    const float Dd = Dp[d];

    const int r0 = b * LL;
    const float* pd = delta + (size_t)r0 * D_INNER + d;
    const float* px = xs    + (size_t)r0 * D_INNER + d;
    const float* pB = dbc   + (size_t)r0 * 64 + 32 + n;
    const float* pC = dbc   + (size_t)r0 * 64 + 48 + n;
    const float* pr = xr    + (size_t)r0 * 2 * D_INNER + D_INNER + d;
    ushort*      py = yb    + (size_t)r0 * D_INNER + d;

    float dt = *pd, x = *px, Bn = *pB, Cn = *pC, res = *pr;
    float h = 0.f;

    for (int l = 0; l < LL; ++l) {
        pd += D_INNER; px += D_INNER; pB += 64; pC += 64; pr += 2 * D_INNER;
        const float dt_n = *pd, x_n = *px, Bn_n = *pB, Cn_n = *pC, res_n = *pr;

        const float dA = __expf(dt * A);
        h = fmaf(dA, h, (dt * x) * Bn);
        float p = h * Cn;
        p += __shfl_xor(p, 1, 16);
        p += __shfl_xor(p, 2, 16);
        p += __shfl_xor(p, 4, 16);
        p += __shfl_xor(p, 8, 16);
        if (n == 0) {
            const float g = res / (1.f + __expf(-res));
            *py = f2bf((p + x * Dd) * g);
        }
        py += D_INNER;
        dt = dt_n; x = x_n; Bn = Bn_n; Cn = Cn_n; res = res_n;
    }
}

// ---------------- final stats ----------------
__global__ __launch_bounds__(512) void stats_k(
    const float* __restrict__ m, float* __restrict__ out)
{
    const int b = blockIdx.x;
    const int dm = threadIdx.x;
    const float* p = m + (size_t)b * LL * D_MODEL + dm;
    float s = 0.f;
    for (int l = 0; l < LL; ++l) s += p[(size_t)l * D_MODEL];
    const float mean = s * (1.f / LL);
    float ss = 0.f;
    for (int l = 0; l < LL; ++l) {
        float v = p[(size_t)l * D_MODEL] - mean;
        ss += v * v;
    }
    out[b * (2 * D_MODEL) + dm] = mean;
    out[b * (2 * D_MODEL) + D_MODEL + dm] = sqrtf(ss * (1.f / (LL - 1)));
}

// ---------------- host ----------------
extern "C" void kernel_launch(void* const* d_in, const int* in_sizes, int n_in,
                              void* d_out, int out_size, void* d_ws, size_t ws_size,
                              hipStream_t stream) {
    const float* x            = (const float*)d_in[0];
    const float* proj_w       = (const float*)d_in[1];
    const float* proj_b       = (const float*)d_in[2];
    const float* norm_w       = (const float*)d_in[3];
    const float* in_w         = (const float*)d_in[4];
    const float* conv_w       = (const float*)d_in[5];
    const float* conv_b       = (const float*)d_in[6];
    const float* xproj_w      = (const float*)d_in[7];
    const float* dt_w         = (const float*)d_in[8];
    const float* dt_b         = (const float*)d_in[9];
    const float* A_log        = (const float*)d_in[10];
    const float* Dp           = (const float*)d_in[11];
    const float* out_w        = (const float*)d_in[12];
    const float* final_norm_w = (const float*)d_in[13];

    // fp32 region (floats); xn(final) aliases xs
    float* ws  = (float*)d_ws;
    float* h   = ws;                                   // 4096*512
    float* xr  = h   + (size_t)M_ROWS * D_MODEL;       // 4096*2048
    float* xs  = xr  + (size_t)M_ROWS * 2 * D_INNER;   // 4096*1024
    float* dbc = xs  + (size_t)M_ROWS * D_INNER;       // 4096*64
    float* dlt = dbc + (size_t)M_ROWS * 64;            // 4096*1024
    // bf16 region (ushorts); x_bf and y_bf share (x_bf dead after proj GEMM)
    ushort* xyb = (ushort*)(dlt + (size_t)M_ROWS * D_INNER);  // max(4096*1280, 4096*1024)
    ushort* xnb = xyb + (size_t)M_ROWS * D_IN;         // 4096*512
    ushort* pwb = xnb + (size_t)M_ROWS * D_MODEL;      // 512*1280
    ushort* iwb = pwb + (size_t)D_MODEL * D_IN;        // 2048*512 (per-layer)
    ushort* owb = iwb + (size_t)2 * D_INNER * D_MODEL; // 512*1024 (per-layer)

    // one-time casts
    cast_bf16_k<<<(M_ROWS * D_IN / 4 + 255) / 256, 256, 0, stream>>>(x, xyb, M_ROWS * D_IN / 4);
    cast_bf16_k<<<(D_MODEL * D_IN / 4 + 255) / 256, 256, 0, stream>>>(proj_w, pwb, D_MODEL * D_IN / 4);

    // h = x @ proj_w^T + proj_b   (bf16 MFMA, BN=64 -> 256 blocks)
    gemm_bf16<64, true, false><<<dim3(D_MODEL / 64, M_ROWS / 128), 256, 0, stream>>>(
        xyb, pwb, proj_b, h, M_ROWS, D_MODEL, D_IN);

    for (int i = 0; i < N_LAYER; ++i) {
        cast_bf16_k<<<(2 * D_INNER * D_MODEL / 4 + 255) / 256, 256, 0, stream>>>(
            in_w + (size_t)i * 2 * D_INNER * D_MODEL, iwb, 2 * D_INNER * D_MODEL / 4);
        cast_bf16_k<<<(D_MODEL * D_INNER / 4 + 255) / 256, 256, 0, stream>>>(
            out_w + (size_t)i * D_MODEL * D_INNER, owb, D_MODEL * D_INNER / 4);

        rmsnorm_k<true><<<M_ROWS, 256, 0, stream>>>(h, norm_w + (size_t)i * D_MODEL, nullptr, xnb);

        gemm_bf16<128, false, false><<<dim3(2 * D_INNER / 128, M_ROWS / 128), 256, 0, stream>>>(
            xnb, iwb, nullptr, xr, M_ROWS, 2 * D_INNER, D_MODEL);

        conv_silu_k<<<M_ROWS * D_INNER / 256, 256, 0, stream>>>(
            xr, conv_w + (size_t)i * D_INNER * D_CONV, conv_b + (size_t)i * D_INNER, xs);

        gemm_tn<false, false, 0><<<dim3(1, M_ROWS / 64), 256, 0, stream>>>(
            xs, D_INNER, xproj_w + (size_t)i * 64 * D_INNER, nullptr, dbc,
            M_ROWS, 64, D_INNER);

        gemm_tn<true, false, 1><<<dim3(D_INNER / 64, M_ROWS / 64), 256, 0, stream>>>(
            dbc, 64, dt_w + (size_t)i * D_INNER * DT_RANK, dt_b + (size_t)i * D_INNER,
            dlt, M_ROWS, D_INNER, DT_RANK);

        scan_k<<<BB * (D_INNER / 16), 256, 0, stream>>>(
            dlt, xs, dbc, xr, A_log + (size_t)i * D_INNER * D_STATE,
            Dp + (size_t)i * D_INNER, xyb);

        gemm_bf16<64, false, true><<<dim3(D_MODEL / 64, M_ROWS / 128), 256, 0, stream>>>(
            xyb, owb, nullptr, h, M_ROWS, D_MODEL, D_INNER);
    }

    rmsnorm_k<false><<<M_ROWS, 256, 0, stream>>>(h, final_norm_w, xs, nullptr);
    stats_k<<<BB, D_MODEL, 0, stream>>>(xs, (float*)d_out);
}

// Round 4
// 1303.447 us; speedup vs baseline: 3.4478x; 1.0693x over previous
//
#include <hip/hip_runtime.h>
#include <math.h>

// ---------------- dims (fixed by the problem) ----------------
#define D_IN     1280
#define D_MODEL  512
#define N_LAYER  4
#define D_STATE  16
#define D_CONV   4
#define D_INNER  1024
#define DT_RANK  32
#define BB       8
#define LL       512
#define M_ROWS   (BB*LL)          // 4096

typedef short bf16x8 __attribute__((ext_vector_type(8)));
typedef float f32x4  __attribute__((ext_vector_type(4)));

__device__ __forceinline__ ushort f2bf(float f) {
    unsigned u = __float_as_uint(f);
    u = (u + 0x7FFF + ((u >> 16) & 1)) >> 16;   // RNE
    return (ushort)u;
}

// ---------------- fp32 -> bf16 cast (n multiple of 4) ----------------
__global__ __launch_bounds__(256) void cast_bf16_k(
    const float* __restrict__ in, ushort* __restrict__ out, int n4)
{
    int i = blockIdx.x * 256 + threadIdx.x;
    if (i < n4) {
        float4 v = *(const float4*)(in + (size_t)i * 4);
        *(ushort4*)(out + (size_t)i * 4) =
            make_ushort4(f2bf(v.x), f2bf(v.y), f2bf(v.z), f2bf(v.w));
    }
}

// ---------------- bf16 MFMA GEMM: C[M,N] = A[M,K] @ W[N,K]^T ------------------
template<int BN, bool BIAS, bool ACCUM>
__global__ __launch_bounds__(256) void gemm_bf16(
    const ushort* __restrict__ A, const ushort* __restrict__ W,
    const float* __restrict__ bias, float* __restrict__ C,
    int M, int N, int K)
{
    constexpr int BM = 128, BK = 32;
    constexpr int LDA = BK + 8;
    constexpr int FN = BN / 32;
    constexpr int HN = BN / 2;
    __shared__ ushort lA[BM * LDA];
    __shared__ ushort lB[BN * LDA];
    const int tid  = threadIdx.x;
    const int lane = tid & 63;
    const int wid  = tid >> 6;
    const int wr = wid >> 1, wc = wid & 1;
    const int bm = blockIdx.y * BM, bn = blockIdx.x * BN;
    const int l15 = lane & 15, lk = lane >> 4;

    f32x4 acc[4][FN];
#pragma unroll
    for (int i = 0; i < 4; ++i)
#pragma unroll
        for (int j = 0; j < FN; ++j) acc[i][j] = (f32x4)0.f;

    for (int kk = 0; kk < K; kk += BK) {
        uint4 va[2], vb[BN / 64 ? BN / 64 : 1];
#pragma unroll
        for (int i = 0; i < 2; ++i) {
            int c = i * 256 + tid, row = c >> 2, k0 = (c & 3) * 8;
            va[i] = *(const uint4*)(A + (size_t)(bm + row) * K + kk + k0);
        }
#pragma unroll
        for (int i = 0; i < BN / 64; ++i) {
            int c = i * 256 + tid, row = c >> 2, k0 = (c & 3) * 8;
            vb[i] = *(const uint4*)(W + (size_t)(bn + row) * K + kk + k0);
        }
        __syncthreads();
#pragma unroll
        for (int i = 0; i < 2; ++i) {
            int c = i * 256 + tid, row = c >> 2, k0 = (c & 3) * 8;
            *(uint4*)&lA[row * LDA + k0] = va[i];
        }
#pragma unroll
        for (int i = 0; i < BN / 64; ++i) {
            int c = i * 256 + tid, row = c >> 2, k0 = (c & 3) * 8;
            *(uint4*)&lB[row * LDA + k0] = vb[i];
        }
        __syncthreads();

        bf16x8 af[4], bw[FN];
#pragma unroll
        for (int fm = 0; fm < 4; ++fm)
            af[fm] = *(const bf16x8*)&lA[(wr * 64 + fm * 16 + l15) * LDA + lk * 8];
#pragma unroll
        for (int fn = 0; fn < FN; ++fn)
            bw[fn] = *(const bf16x8*)&lB[(wc * HN + fn * 16 + l15) * LDA + lk * 8];
#pragma unroll
        for (int fm = 0; fm < 4; ++fm)
#pragma unroll
            for (int fn = 0; fn < FN; ++fn)
                acc[fm][fn] = __builtin_amdgcn_mfma_f32_16x16x32_bf16(
                    af[fm], bw[fn], acc[fm][fn], 0, 0, 0);
    }

#pragma unroll
    for (int fm = 0; fm < 4; ++fm) {
#pragma unroll
        for (int fn = 0; fn < FN; ++fn) {
            int col = bn + wc * HN + fn * 16 + l15;
            float bv = BIAS ? bias[col] : 0.f;
#pragma unroll
            for (int j = 0; j < 4; ++j) {
                int row = bm + wr * 64 + fm * 16 + lk * 4 + j;
                float r = acc[fm][fn][j] + bv;
                float* cp = C + (size_t)row * N + col;
                if (ACCUM) r += *cp;
                *cp = r;
            }
        }
    }
}

// ---------------- fp32 GEMM (small N / small K) -------------------------------
template<bool BIAS, bool ACCUM, int ACT>
__global__ __launch_bounds__(256) void gemm_tn(
    const float* __restrict__ A, int lda,
    const float* __restrict__ W, const float* __restrict__ bias,
    float* __restrict__ C, int M, int N, int K)
{
    constexpr int BM = 64, BN = 64, BK = 16;
    __shared__ float As[BK][BM + 4];
    __shared__ float Ws[BK][BN + 4];
    const int tid = threadIdx.x;
    const int bm = blockIdx.y * BM;
    const int bn = blockIdx.x * BN;
    const int lr = tid >> 2;
    const int kg = (tid & 3) * 4;
    const float* Aptr = A + (size_t)(bm + lr) * lda + kg;
    const float* Wptr = W + (size_t)(bn + lr) * K + kg;
    const int tx = tid & 15, ty = tid >> 4;
    float acc[4][4] = {};

    for (int kk = 0; kk < K; kk += BK) {
        float4 a4 = *(const float4*)(Aptr + kk);
        float4 w4 = *(const float4*)(Wptr + kk);
        __syncthreads();
        As[kg + 0][lr] = a4.x; As[kg + 1][lr] = a4.y;
        As[kg + 2][lr] = a4.z; As[kg + 3][lr] = a4.w;
        Ws[kg + 0][lr] = w4.x; Ws[kg + 1][lr] = w4.y;
        Ws[kg + 2][lr] = w4.z; Ws[kg + 3][lr] = w4.w;
        __syncthreads();
#pragma unroll
        for (int k = 0; k < BK; ++k) {
            float4 av = *(const float4*)&As[k][ty * 4];
            float4 wv = *(const float4*)&Ws[k][tx * 4];
            float a[4] = {av.x, av.y, av.z, av.w};
            float w[4] = {wv.x, wv.y, wv.z, wv.w};
#pragma unroll
            for (int i = 0; i < 4; ++i)
#pragma unroll
                for (int j = 0; j < 4; ++j) acc[i][j] += a[i] * w[j];
        }
    }
#pragma unroll
    for (int i = 0; i < 4; ++i) {
        int m = bm + ty * 4 + i;
        int n = bn + tx * 4;
        float r[4] = {acc[i][0], acc[i][1], acc[i][2], acc[i][3]};
        if (BIAS) {
            float4 bv = *(const float4*)(bias + n);
            r[0] += bv.x; r[1] += bv.y; r[2] += bv.z; r[3] += bv.w;
        }
        if (ACT == 1) {
#pragma unroll
            for (int j = 0; j < 4; ++j)
                r[j] = (r[j] > 20.f) ? r[j] : log1pf(expf(r[j]));
        }
        float* cp = C + (size_t)m * N + n;
        if (ACCUM) {
            float4 cv = *(const float4*)cp;
            r[0] += cv.x; r[1] += cv.y; r[2] += cv.z; r[3] += cv.w;
        }
        *(float4*)cp = make_float4(r[0], r[1], r[2], r[3]);
    }
}

// ---------------- RMSNorm over last dim D=512 ---------------------------------
template<bool BF16OUT>
__global__ __launch_bounds__(256) void rmsnorm_k(
    const float* __restrict__ X, const float* __restrict__ w,
    float* __restrict__ Yf, ushort* __restrict__ Yb)
{
    const int r = blockIdx.x;
    const float* x = X + (size_t)r * D_MODEL;
    float2 v = *(const float2*)(x + threadIdx.x * 2);
    float ss = v.x * v.x + v.y * v.y;
#pragma unroll
    for (int off = 32; off > 0; off >>= 1) ss += __shfl_down(ss, off);
    __shared__ float wsum[4];
    if ((threadIdx.x & 63) == 0) wsum[threadIdx.x >> 6] = ss;
    __syncthreads();
    float tot = wsum[0] + wsum[1] + wsum[2] + wsum[3];
    float rs = rsqrtf(tot * (1.f / D_MODEL) + 1e-5f);
    float2 wv = *(const float2*)(w + threadIdx.x * 2);
    float a = v.x * rs * wv.x, b = v.y * rs * wv.y;
    if (BF16OUT)
        *(ushort2*)(Yb + (size_t)r * D_MODEL + threadIdx.x * 2) =
            make_ushort2(f2bf(a), f2bf(b));
    else
        *(float2*)(Yf + (size_t)r * D_MODEL + threadIdx.x * 2) = make_float2(a, b);
}

// ---------------- depthwise causal conv1d (k=4) + bias + silu -----------------
__global__ __launch_bounds__(256) void conv_silu_k(
    const float* __restrict__ xr, const float* __restrict__ cw,
    const float* __restrict__ cb, float* __restrict__ xs)
{
    const int idx = blockIdx.x * 256 + threadIdx.x;
    const int d = idx & (D_INNER - 1);
    const int r = idx >> 10;
    const int l = r & (LL - 1);
    const float* base = xr + (size_t)r * (2 * D_INNER) + d;
    float4 w = *(const float4*)(cw + d * 4);
    float acc = cb[d];
    if (l >= 3) acc += base[-3 * 2 * D_INNER] * w.x;
    if (l >= 2) acc += base[-2 * 2 * D_INNER] * w.y;
    if (l >= 1) acc += base[-1 * 2 * D_INNER] * w.z;
    acc += base[0] * w.w;
    xs[idx] = acc / (1.f + __expf(-acc));
}

// ---------------- selective scan: thread per (b,d,n), 8-step SW pipeline ------
// Double-buffered register staging: issue the next 8 timesteps' 40 loads while
// computing the current 8. All buffer indices compile-time (named A/B arrays).
#define SU 8
__global__ __launch_bounds__(256) void scan_k(
    const float* __restrict__ delta, const float* __restrict__ xs,
    const float* __restrict__ dbc, const float* __restrict__ xr,
    const float* __restrict__ A_log, const float* __restrict__ Dp,
    ushort* __restrict__ yb)
{
    const int b = blockIdx.x >> 6;
    const int d = ((blockIdx.x & 63) << 4) + (threadIdx.x >> 4);
    const int n = threadIdx.x & 15;

    const float A  = -__expf(A_log[d * D_STATE + n]);
    const float Dd = Dp[d];

    const int r0 = b * LL;
    const float* pd = delta + (size_t)r0 * D_INNER + d;
    const float* px = xs    + (size_t)r0 * D_INNER + d;
    const float* pB = dbc   + (size_t)r0 * 64 + 32 + n;
    const float* pC = dbc   + (size_t)r0 * 64 + 48 + n;
    const float* pr = xr    + (size_t)r0 * 2 * D_INNER + D_INNER + d;
    ushort*      py = yb    + (size_t)r0 * D_INNER + d;

    float dtA[SU], xvA[SU], BnA[SU], CnA[SU], rsA[SU];
    float dtB[SU], xvB[SU], BnB[SU], CnB[SU], rsB[SU];
    float h = 0.f;

#define LOADG(SFX, L0) \
    _Pragma("unroll") \
    for (int u = 0; u < SU; ++u) { \
        const int l = (L0) + u; \
        dt##SFX[u] = pd[(size_t)l * D_INNER]; \
        xv##SFX[u] = px[(size_t)l * D_INNER]; \
        Bn##SFX[u] = pB[(size_t)l * 64]; \
        Cn##SFX[u] = pC[(size_t)l * 64]; \
        rs##SFX[u] = pr[(size_t)l * 2 * D_INNER]; \
    }

#define COMPG(SFX, L0) \
    _Pragma("unroll") \
    for (int u = 0; u < SU; ++u) { \
        const float dA = __expf(dt##SFX[u] * A); \
        h = fmaf(dA, h, (dt##SFX[u] * xv##SFX[u]) * Bn##SFX[u]); \
        float p = h * Cn##SFX[u]; \
        p += __shfl_xor(p, 1, 16); \
        p += __shfl_xor(p, 2, 16); \
        p += __shfl_xor(p, 4, 16); \
        p += __shfl_xor(p, 8, 16); \
        if (n == 0) { \
            const float res = rs##SFX[u]; \
            const float g2 = res / (1.f + __expf(-res)); \
            py[(size_t)((L0) + u) * D_INNER] = f2bf((p + xv##SFX[u] * Dd) * g2); \
        } \
    }

    LOADG(A, 0)
    for (int g = 0; g < 31; ++g) {
        const int l0 = g * 2 * SU;
        LOADG(B, l0 + SU)
        COMPG(A, l0)
        LOADG(A, l0 + 2 * SU)
        COMPG(B, l0 + SU)
    }
    LOADG(B, LL - SU)
    COMPG(A, LL - 2 * SU)
    COMPG(B, LL - SU)
#undef LOADG
#undef COMPG
}

// ---------------- final stats ----------------
__global__ __launch_bounds__(512) void stats_k(
    const float* __restrict__ m, float* __restrict__ out)
{
    const int b = blockIdx.x;
    const int dm = threadIdx.x;
    const float* p = m + (size_t)b * LL * D_MODEL + dm;
    float s = 0.f;
    for (int l = 0; l < LL; ++l) s += p[(size_t)l * D_MODEL];
    const float mean = s * (1.f / LL);
    float ss = 0.f;
    for (int l = 0; l < LL; ++l) {
        float v = p[(size_t)l * D_MODEL] - mean;
        ss += v * v;
    }
    out[b * (2 * D_MODEL) + dm] = mean;
    out[b * (2 * D_MODEL) + D_MODEL + dm] = sqrtf(ss * (1.f / (LL - 1)));
}

// ---------------- host ----------------
extern "C" void kernel_launch(void* const* d_in, const int* in_sizes, int n_in,
                              void* d_out, int out_size, void* d_ws, size_t ws_size,
                              hipStream_t stream) {
    const float* x            = (const float*)d_in[0];
    const float* proj_w       = (const float*)d_in[1];
    const float* proj_b       = (const float*)d_in[2];
    const float* norm_w       = (const float*)d_in[3];
    const float* in_w         = (const float*)d_in[4];
    const float* conv_w       = (const float*)d_in[5];
    const float* conv_b       = (const float*)d_in[6];
    const float* xproj_w      = (const float*)d_in[7];
    const float* dt_w         = (const float*)d_in[8];
    const float* dt_b         = (const float*)d_in[9];
    const float* A_log        = (const float*)d_in[10];
    const float* Dp           = (const float*)d_in[11];
    const float* out_w        = (const float*)d_in[12];
    const float* final_norm_w = (const float*)d_in[13];

    float* ws  = (float*)d_ws;
    float* h   = ws;                                   // 4096*512
    float* xr  = h   + (size_t)M_ROWS * D_MODEL;       // 4096*2048
    float* xs  = xr  + (size_t)M_ROWS * 2 * D_INNER;   // 4096*1024
    float* dbc = xs  + (size_t)M_ROWS * D_INNER;       // 4096*64
    float* dlt = dbc + (size_t)M_ROWS * 64;            // 4096*1024
    ushort* xyb = (ushort*)(dlt + (size_t)M_ROWS * D_INNER);
    ushort* xnb = xyb + (size_t)M_ROWS * D_IN;
    ushort* pwb = xnb + (size_t)M_ROWS * D_MODEL;
    ushort* iwb = pwb + (size_t)D_MODEL * D_IN;
    ushort* owb = iwb + (size_t)2 * D_INNER * D_MODEL;

    cast_bf16_k<<<(M_ROWS * D_IN / 4 + 255) / 256, 256, 0, stream>>>(x, xyb, M_ROWS * D_IN / 4);
    cast_bf16_k<<<(D_MODEL * D_IN / 4 + 255) / 256, 256, 0, stream>>>(proj_w, pwb, D_MODEL * D_IN / 4);

    gemm_bf16<64, true, false><<<dim3(D_MODEL / 64, M_ROWS / 128), 256, 0, stream>>>(
        xyb, pwb, proj_b, h, M_ROWS, D_MODEL, D_IN);

    for (int i = 0; i < N_LAYER; ++i) {
        cast_bf16_k<<<(2 * D_INNER * D_MODEL / 4 + 255) / 256, 256, 0, stream>>>(
            in_w + (size_t)i * 2 * D_INNER * D_MODEL, iwb, 2 * D_INNER * D_MODEL / 4);
        cast_bf16_k<<<(D_MODEL * D_INNER / 4 + 255) / 256, 256, 0, stream>>>(
            out_w + (size_t)i * D_MODEL * D_INNER, owb, D_MODEL * D_INNER / 4);

        rmsnorm_k<true><<<M_ROWS, 256, 0, stream>>>(h, norm_w + (size_t)i * D_MODEL, nullptr, xnb);

        gemm_bf16<128, false, false><<<dim3(2 * D_INNER / 128, M_ROWS / 128), 256, 0, stream>>>(
            xnb, iwb, nullptr, xr, M_ROWS, 2 * D_INNER, D_MODEL);

        conv_silu_k<<<M_ROWS * D_INNER / 256, 256, 0, stream>>>(
            xr, conv_w + (size_t)i * D_INNER * D_CONV, conv_b + (size_t)i * D_INNER, xs);

        gemm_tn<false, false, 0><<<dim3(1, M_ROWS / 64), 256, 0, stream>>>(
            xs, D_INNER, xproj_w + (size_t)i * 64 * D_INNER, nullptr, dbc,
            M_ROWS, 64, D_INNER);

        gemm_tn<true, false, 1><<<dim3(D_INNER / 64, M_ROWS / 64), 256, 0, stream>>>(
            dbc, 64, dt_w + (size_t)i * D_INNER * DT_RANK, dt_b + (size_t)i * D_INNER,
            dlt, M_ROWS, D_INNER, DT_RANK);

        scan_k<<<BB * (D_INNER / 16), 256, 0, stream>>>(
            dlt, xs, dbc, xr, A_log + (size_t)i * D_INNER * D_STATE,
            Dp + (size_t)i * D_INNER, xyb);

        gemm_bf16<64, false, true><<<dim3(D_MODEL / 64, M_ROWS / 128), 256, 0, stream>>>(
            xyb, owb, nullptr, h, M_ROWS, D_MODEL, D_INNER);
    }

    rmsnorm_k<false><<<M_ROWS, 256, 0, stream>>>(h, final_norm_w, xs, nullptr);
    stats_k<<<BB, D_MODEL, 0, stream>>>(xs, (float*)d_out);
}

// Round 5
// 1221.917 us; speedup vs baseline: 3.6779x; 1.0667x over previous
//
#include <hip/hip_runtime.h>
#include <math.h>

// ---------------- dims (fixed by the problem) ----------------
#define D_IN     1280
#define D_MODEL  512
#define N_LAYER  4
#define D_STATE  16
#define D_CONV   4
#define D_INNER  1024
#define DT_RANK  32
#define BB       8
#define LL       512
#define M_ROWS   (BB*LL)          // 4096
#define NCHUNK   4
#define LC       (LL/NCHUNK)      // 128

typedef short bf16x8 __attribute__((ext_vector_type(8)));
typedef float f32x4  __attribute__((ext_vector_type(4)));

__device__ __forceinline__ ushort f2bf(float f) {
    unsigned u = __float_as_uint(f);
    u = (u + 0x7FFF + ((u >> 16) & 1)) >> 16;   // RNE
    return (ushort)u;
}

// ---------------- fp32 -> bf16 cast (n multiple of 4) ----------------
__global__ __launch_bounds__(256) void cast_bf16_k(
    const float* __restrict__ in, ushort* __restrict__ out, int n4)
{
    int i = blockIdx.x * 256 + threadIdx.x;
    if (i < n4) {
        float4 v = *(const float4*)(in + (size_t)i * 4);
        *(ushort4*)(out + (size_t)i * 4) =
            make_ushort4(f2bf(v.x), f2bf(v.y), f2bf(v.z), f2bf(v.w));
    }
}

// ---------------- bf16 MFMA GEMM: C[M,N] = A[M,K] @ W[N,K]^T ------------------
template<int BN, bool BIAS, bool ACCUM>
__global__ __launch_bounds__(256) void gemm_bf16(
    const ushort* __restrict__ A, const ushort* __restrict__ W,
    const float* __restrict__ bias, float* __restrict__ C,
    int M, int N, int K)
{
    constexpr int BM = 128, BK = 32;
    constexpr int LDA = BK + 8;
    constexpr int FN = BN / 32;
    constexpr int HN = BN / 2;
    __shared__ ushort lA[BM * LDA];
    __shared__ ushort lB[BN * LDA];
    const int tid  = threadIdx.x;
    const int lane = tid & 63;
    const int wid  = tid >> 6;
    const int wr = wid >> 1, wc = wid & 1;
    const int bm = blockIdx.y * BM, bn = blockIdx.x * BN;
    const int l15 = lane & 15, lk = lane >> 4;

    f32x4 acc[4][FN];
#pragma unroll
    for (int i = 0; i < 4; ++i)
#pragma unroll
        for (int j = 0; j < FN; ++j) acc[i][j] = (f32x4)0.f;

    for (int kk = 0; kk < K; kk += BK) {
        uint4 va[2], vb[BN / 64 ? BN / 64 : 1];
#pragma unroll
        for (int i = 0; i < 2; ++i) {
            int c = i * 256 + tid, row = c >> 2, k0 = (c & 3) * 8;
            va[i] = *(const uint4*)(A + (size_t)(bm + row) * K + kk + k0);
        }
#pragma unroll
        for (int i = 0; i < BN / 64; ++i) {
            int c = i * 256 + tid, row = c >> 2, k0 = (c & 3) * 8;
            vb[i] = *(const uint4*)(W + (size_t)(bn + row) * K + kk + k0);
        }
        __syncthreads();
#pragma unroll
        for (int i = 0; i < 2; ++i) {
            int c = i * 256 + tid, row = c >> 2, k0 = (c & 3) * 8;
            *(uint4*)&lA[row * LDA + k0] = va[i];
        }
#pragma unroll
        for (int i = 0; i < BN / 64; ++i) {
            int c = i * 256 + tid, row = c >> 2, k0 = (c & 3) * 8;
            *(uint4*)&lB[row * LDA + k0] = vb[i];
        }
        __syncthreads();

        bf16x8 af[4], bw[FN];
#pragma unroll
        for (int fm = 0; fm < 4; ++fm)
            af[fm] = *(const bf16x8*)&lA[(wr * 64 + fm * 16 + l15) * LDA + lk * 8];
#pragma unroll
        for (int fn = 0; fn < FN; ++fn)
            bw[fn] = *(const bf16x8*)&lB[(wc * HN + fn * 16 + l15) * LDA + lk * 8];
#pragma unroll
        for (int fm = 0; fm < 4; ++fm)
#pragma unroll
            for (int fn = 0; fn < FN; ++fn)
                acc[fm][fn] = __builtin_amdgcn_mfma_f32_16x16x32_bf16(
                    af[fm], bw[fn], acc[fm][fn], 0, 0, 0);
    }

#pragma unroll
    for (int fm = 0; fm < 4; ++fm) {
#pragma unroll
        for (int fn = 0; fn < FN; ++fn) {
            int col = bn + wc * HN + fn * 16 + l15;
            float bv = BIAS ? bias[col] : 0.f;
#pragma unroll
            for (int j = 0; j < 4; ++j) {
                int row = bm + wr * 64 + fm * 16 + lk * 4 + j;
                float r = acc[fm][fn][j] + bv;
                float* cp = C + (size_t)row * N + col;
                if (ACCUM) r += *cp;
                *cp = r;
            }
        }
    }
}

// ---------------- fp32 GEMM (small N / small K) -------------------------------
template<bool BIAS, bool ACCUM, int ACT>
__global__ __launch_bounds__(256) void gemm_tn(
    const float* __restrict__ A, int lda,
    const float* __restrict__ W, const float* __restrict__ bias,
    float* __restrict__ C, int M, int N, int K)
{
    constexpr int BM = 64, BN = 64, BK = 16;
    __shared__ float As[BK][BM + 4];
    __shared__ float Ws[BK][BN + 4];
    const int tid = threadIdx.x;
    const int bm = blockIdx.y * BM;
    const int bn = blockIdx.x * BN;
    const int lr = tid >> 2;
    const int kg = (tid & 3) * 4;
    const float* Aptr = A + (size_t)(bm + lr) * lda + kg;
    const float* Wptr = W + (size_t)(bn + lr) * K + kg;
    const int tx = tid & 15, ty = tid >> 4;
    float acc[4][4] = {};

    for (int kk = 0; kk < K; kk += BK) {
        float4 a4 = *(const float4*)(Aptr + kk);
        float4 w4 = *(const float4*)(Wptr + kk);
        __syncthreads();
        As[kg + 0][lr] = a4.x; As[kg + 1][lr] = a4.y;
        As[kg + 2][lr] = a4.z; As[kg + 3][lr] = a4.w;
        Ws[kg + 0][lr] = w4.x; Ws[kg + 1][lr] = w4.y;
        Ws[kg + 2][lr] = w4.z; Ws[kg + 3][lr] = w4.w;
        __syncthreads();
#pragma unroll
        for (int k = 0; k < BK; ++k) {
            float4 av = *(const float4*)&As[k][ty * 4];
            float4 wv = *(const float4*)&Ws[k][tx * 4];
            float a[4] = {av.x, av.y, av.z, av.w};
            float w[4] = {wv.x, wv.y, wv.z, wv.w};
#pragma unroll
            for (int i = 0; i < 4; ++i)
#pragma unroll
                for (int j = 0; j < 4; ++j) acc[i][j] += a[i] * w[j];
        }
    }
#pragma unroll
    for (int i = 0; i < 4; ++i) {
        int m = bm + ty * 4 + i;
        int n = bn + tx * 4;
        float r[4] = {acc[i][0], acc[i][1], acc[i][2], acc[i][3]};
        if (BIAS) {
            float4 bv = *(const float4*)(bias + n);
            r[0] += bv.x; r[1] += bv.y; r[2] += bv.z; r[3] += bv.w;
        }
        if (ACT == 1) {
#pragma unroll
            for (int j = 0; j < 4; ++j)
                r[j] = (r[j] > 20.f) ? r[j] : log1pf(expf(r[j]));
        }
        float* cp = C + (size_t)m * N + n;
        if (ACCUM) {
            float4 cv = *(const float4*)cp;
            r[0] += cv.x; r[1] += cv.y; r[2] += cv.z; r[3] += cv.w;
        }
        *(float4*)cp = make_float4(r[0], r[1], r[2], r[3]);
    }
}

// ---------------- RMSNorm over last dim D=512 ---------------------------------
template<bool BF16OUT>
__global__ __launch_bounds__(256) void rmsnorm_k(
    const float* __restrict__ X, const float* __restrict__ w,
    float* __restrict__ Yf, ushort* __restrict__ Yb)
{
    const int r = blockIdx.x;
    const float* x = X + (size_t)r * D_MODEL;
    float2 v = *(const float2*)(x + threadIdx.x * 2);
    float ss = v.x * v.x + v.y * v.y;
#pragma unroll
    for (int off = 32; off > 0; off >>= 1) ss += __shfl_down(ss, off);
    __shared__ float wsum[4];
    if ((threadIdx.x & 63) == 0) wsum[threadIdx.x >> 6] = ss;
    __syncthreads();
    float tot = wsum[0] + wsum[1] + wsum[2] + wsum[3];
    float rs = rsqrtf(tot * (1.f / D_MODEL) + 1e-5f);
    float2 wv = *(const float2*)(w + threadIdx.x * 2);
    float a = v.x * rs * wv.x, b = v.y * rs * wv.y;
    if (BF16OUT)
        *(ushort2*)(Yb + (size_t)r * D_MODEL + threadIdx.x * 2) =
            make_ushort2(f2bf(a), f2bf(b));
    else
        *(float2*)(Yf + (size_t)r * D_MODEL + threadIdx.x * 2) = make_float2(a, b);
}

// ---------------- depthwise causal conv1d (k=4) + bias + silu -----------------
__global__ __launch_bounds__(256) void conv_silu_k(
    const float* __restrict__ xr, const float* __restrict__ cw,
    const float* __restrict__ cb, float* __restrict__ xs)
{
    const int idx = blockIdx.x * 256 + threadIdx.x;
    const int d = idx & (D_INNER - 1);
    const int r = idx >> 10;
    const int l = r & (LL - 1);
    const float* base = xr + (size_t)r * (2 * D_INNER) + d;
    float4 w = *(const float4*)(cw + d * 4);
    float acc = cb[d];
    if (l >= 3) acc += base[-3 * 2 * D_INNER] * w.x;
    if (l >= 2) acc += base[-2 * 2 * D_INNER] * w.y;
    if (l >= 1) acc += base[-1 * 2 * D_INNER] * w.z;
    acc += base[0] * w.w;
    xs[idx] = acc / (1.f + __expf(-acc));
}

// ---------------- selective scan, chunk-parallel (two phases) -----------------
// Phase 1: each (b,d,n,c) thread scans its 128-step chunk from h=0 and stores
//          {S = sum(dt*A), h_local} to cb[b][c][d][n] (float2, n-contiguous).
__global__ __launch_bounds__(256) void scan1_k(
    const float* __restrict__ delta, const float* __restrict__ xs,
    const float* __restrict__ dbc, const float* __restrict__ A_log,
    float2* __restrict__ cb)
{
    const int b  = blockIdx.x >> 8;
    const int c  = (blockIdx.x >> 6) & 3;
    const int dg = blockIdx.x & 63;
    const int d  = (dg << 4) + (threadIdx.x >> 4);
    const int n  = threadIdx.x & 15;

    const float A = -__expf(A_log[d * D_STATE + n]);
    const int r0 = b * LL + c * LC;
    const float* pd = delta + (size_t)r0 * D_INNER + d;
    const float* px = xs    + (size_t)r0 * D_INNER + d;
    const float* pB = dbc   + (size_t)r0 * 64 + 32 + n;

    float h = 0.f, S = 0.f;
#pragma unroll 4
    for (int l = 0; l < LC; ++l) {
        const float dt = pd[(size_t)l * D_INNER];
        const float x  = px[(size_t)l * D_INNER];
        const float Bn = pB[(size_t)l * 64];
        const float sA = dt * A;
        S += sA;
        h = fmaf(__expf(sA), h, (dt * x) * Bn);
    }
    cb[((size_t)(b * NCHUNK + c) * D_INNER + d) * D_STATE + n] = make_float2(S, h);
}

// Phase 2: combine predecessor chunk summaries into h0, re-scan chunk, emit y.
__global__ __launch_bounds__(256) void scan2_k(
    const float* __restrict__ delta, const float* __restrict__ xs,
    const float* __restrict__ dbc, const float* __restrict__ xr,
    const float* __restrict__ A_log, const float* __restrict__ Dp,
    const float2* __restrict__ cb, ushort* __restrict__ yb)
{
    const int b  = blockIdx.x >> 8;
    const int c  = (blockIdx.x >> 6) & 3;
    const int dg = blockIdx.x & 63;
    const int d  = (dg << 4) + (threadIdx.x >> 4);
    const int n  = threadIdx.x & 15;

    const float A  = -__expf(A_log[d * D_STATE + n]);
    const float Dd = Dp[d];

    // h0 = sum_{j<c} hl[j] * prod_{j<k<c} P[k]   (P = exp(S))
    float h = 0.f;
#pragma unroll
    for (int j = 0; j < NCHUNK - 1; ++j) {
        if (j < c) {
            float2 v = cb[((size_t)(b * NCHUNK + j) * D_INNER + d) * D_STATE + n];
            h = fmaf(__expf(v.x), h, v.y);
        }
    }

    const int r0 = b * LL + c * LC;
    const float* pd = delta + (size_t)r0 * D_INNER + d;
    const float* px = xs    + (size_t)r0 * D_INNER + d;
    const float* pB = dbc   + (size_t)r0 * 64 + 32 + n;
    const float* pC = dbc   + (size_t)r0 * 64 + 48 + n;
    const float* pr = xr    + (size_t)r0 * 2 * D_INNER + D_INNER + d;
    ushort*      py = yb    + (size_t)r0 * D_INNER + d;

    float dt = *pd, x = *px, Bn = *pB, Cn = *pC, res = *pr;

#pragma unroll 4
    for (int l = 0; l < LC; ++l) {
        // prefetch next step (tail over-reads stay inside d_ws)
        pd += D_INNER; px += D_INNER; pB += 64; pC += 64; pr += 2 * D_INNER;
        const float dt_n = *pd, x_n = *px, Bn_n = *pB, Cn_n = *pC, res_n = *pr;

        h = fmaf(__expf(dt * A), h, (dt * x) * Bn);
        float p = h * Cn;
        p += __shfl_xor(p, 1, 16);
        p += __shfl_xor(p, 2, 16);
        p += __shfl_xor(p, 4, 16);
        p += __shfl_xor(p, 8, 16);
        if (n == 0) {
            const float g = res / (1.f + __expf(-res));
            py[(size_t)l * D_INNER] = f2bf((p + x * Dd) * g);
        }
        dt = dt_n; x = x_n; Bn = Bn_n; Cn = Cn_n; res = res_n;
    }
}

// ---------------- final stats ----------------
__global__ __launch_bounds__(512) void stats_k(
    const float* __restrict__ m, float* __restrict__ out)
{
    const int b = blockIdx.x;
    const int dm = threadIdx.x;
    const float* p = m + (size_t)b * LL * D_MODEL + dm;
    float s = 0.f;
    for (int l = 0; l < LL; ++l) s += p[(size_t)l * D_MODEL];
    const float mean = s * (1.f / LL);
    float ss = 0.f;
    for (int l = 0; l < LL; ++l) {
        float v = p[(size_t)l * D_MODEL] - mean;
        ss += v * v;
    }
    out[b * (2 * D_MODEL) + dm] = mean;
    out[b * (2 * D_MODEL) + D_MODEL + dm] = sqrtf(ss * (1.f / (LL - 1)));
}

// ---------------- host ----------------
extern "C" void kernel_launch(void* const* d_in, const int* in_sizes, int n_in,
                              void* d_out, int out_size, void* d_ws, size_t ws_size,
                              hipStream_t stream) {
    const float* x            = (const float*)d_in[0];
    const float* proj_w       = (const float*)d_in[1];
    const float* proj_b       = (const float*)d_in[2];
    const float* norm_w       = (const float*)d_in[3];
    const float* in_w         = (const float*)d_in[4];
    const float* conv_w       = (const float*)d_in[5];
    const float* conv_b       = (const float*)d_in[6];
    const float* xproj_w      = (const float*)d_in[7];
    const float* dt_w         = (const float*)d_in[8];
    const float* dt_b         = (const float*)d_in[9];
    const float* A_log        = (const float*)d_in[10];
    const float* Dp           = (const float*)d_in[11];
    const float* out_w        = (const float*)d_in[12];
    const float* final_norm_w = (const float*)d_in[13];

    float* ws  = (float*)d_ws;
    float* h   = ws;                                   // 4096*512
    float* xr  = h   + (size_t)M_ROWS * D_MODEL;       // 4096*2048
    float* xs  = xr  + (size_t)M_ROWS * 2 * D_INNER;   // 4096*1024
    float* dbc = xs  + (size_t)M_ROWS * D_INNER;       // 4096*64
    float* dlt = dbc + (size_t)M_ROWS * 64;            // 4096*1024
    ushort* xyb = (ushort*)(dlt + (size_t)M_ROWS * D_INNER);
    ushort* xnb = xyb + (size_t)M_ROWS * D_IN;
    ushort* pwb = xnb + (size_t)M_ROWS * D_MODEL;
    ushort* iwb = pwb + (size_t)D_MODEL * D_IN;
    ushort* owb = iwb + (size_t)2 * D_INNER * D_MODEL;
    float2* cbuf = (float2*)(owb + (size_t)D_MODEL * D_INNER);  // 8*4*1024*16 float2 = 4MB

    cast_bf16_k<<<(M_ROWS * D_IN / 4 + 255) / 256, 256, 0, stream>>>(x, xyb, M_ROWS * D_IN / 4);
    cast_bf16_k<<<(D_MODEL * D_IN / 4 + 255) / 256, 256, 0, stream>>>(proj_w, pwb, D_MODEL * D_IN / 4);

    gemm_bf16<64, true, false><<<dim3(D_MODEL / 64, M_ROWS / 128), 256, 0, stream>>>(
        xyb, pwb, proj_b, h, M_ROWS, D_MODEL, D_IN);

    for (int i = 0; i < N_LAYER; ++i) {
        cast_bf16_k<<<(2 * D_INNER * D_MODEL / 4 + 255) / 256, 256, 0, stream>>>(
            in_w + (size_t)i * 2 * D_INNER * D_MODEL, iwb, 2 * D_INNER * D_MODEL / 4);
        cast_bf16_k<<<(D_MODEL * D_INNER / 4 + 255) / 256, 256, 0, stream>>>(
            out_w + (size_t)i * D_MODEL * D_INNER, owb, D_MODEL * D_INNER / 4);

        rmsnorm_k<true><<<M_ROWS, 256, 0, stream>>>(h, norm_w + (size_t)i * D_MODEL, nullptr, xnb);

        gemm_bf16<128, false, false><<<dim3(2 * D_INNER / 128, M_ROWS / 128), 256, 0, stream>>>(
            xnb, iwb, nullptr, xr, M_ROWS, 2 * D_INNER, D_MODEL);

        conv_silu_k<<<M_ROWS * D_INNER / 256, 256, 0, stream>>>(
            xr, conv_w + (size_t)i * D_INNER * D_CONV, conv_b + (size_t)i * D_INNER, xs);

        gemm_tn<false, false, 0><<<dim3(1, M_ROWS / 64), 256, 0, stream>>>(
            xs, D_INNER, xproj_w + (size_t)i * 64 * D_INNER, nullptr, dbc,
            M_ROWS, 64, D_INNER);

        gemm_tn<true, false, 1><<<dim3(D_INNER / 64, M_ROWS / 64), 256, 0, stream>>>(
            dbc, 64, dt_w + (size_t)i * D_INNER * DT_RANK, dt_b + (size_t)i * D_INNER,
            dlt, M_ROWS, D_INNER, DT_RANK);

        scan1_k<<<BB * NCHUNK * (D_INNER / 16), 256, 0, stream>>>(
            dlt, xs, dbc, A_log + (size_t)i * D_INNER * D_STATE, cbuf);
        scan2_k<<<BB * NCHUNK * (D_INNER / 16), 256, 0, stream>>>(
            dlt, xs, dbc, xr, A_log + (size_t)i * D_INNER * D_STATE,
            Dp + (size_t)i * D_INNER, cbuf, xyb);

        gemm_bf16<64, false, true><<<dim3(D_MODEL / 64, M_ROWS / 128), 256, 0, stream>>>(
            xyb, owb, nullptr, h, M_ROWS, D_MODEL, D_INNER);
    }

    rmsnorm_k<false><<<M_ROWS, 256, 0, stream>>>(h, final_norm_w, xs, nullptr);
    stats_k<<<BB, D_MODEL, 0, stream>>>(xs, (float*)d_out);
}

// Round 6
// 1081.085 us; speedup vs baseline: 4.1570x; 1.1303x over previous
//
#include <hip/hip_runtime.h>
#include <math.h>

// ---------------- dims (fixed by the problem) ----------------
#define D_IN     1280
#define D_MODEL  512
#define N_LAYER  4
#define D_STATE  16
#define D_CONV   4
#define D_INNER  1024
#define DT_RANK  32
#define BB       8
#define LL       512
#define M_ROWS   (BB*LL)          // 4096
#define NCHUNK   8
#define LC       (LL/NCHUNK)      // 64

typedef short bf16x8 __attribute__((ext_vector_type(8)));
typedef float f32x4  __attribute__((ext_vector_type(4)));

__device__ __forceinline__ ushort f2bf(float f) {
    unsigned u = __float_as_uint(f);
    u = (u + 0x7FFF + ((u >> 16) & 1)) >> 16;   // RNE
    return (ushort)u;
}

// ---------------- fp32 -> bf16 cast (n multiple of 4) ----------------
__global__ __launch_bounds__(256) void cast_bf16_k(
    const float* __restrict__ in, ushort* __restrict__ out, int n4)
{
    int i = blockIdx.x * 256 + threadIdx.x;
    if (i < n4) {
        float4 v = *(const float4*)(in + (size_t)i * 4);
        *(ushort4*)(out + (size_t)i * 4) =
            make_ushort4(f2bf(v.x), f2bf(v.y), f2bf(v.z), f2bf(v.w));
    }
}

// ---------------- bf16 MFMA GEMM: C[M,N] = A[M,K] @ W[N,K]^T ------------------
template<int BN, bool BIAS, bool ACCUM>
__global__ __launch_bounds__(256) void gemm_bf16(
    const ushort* __restrict__ A, const ushort* __restrict__ W,
    const float* __restrict__ bias, float* __restrict__ C,
    int M, int N, int K)
{
    constexpr int BM = 128, BK = 32;
    constexpr int LDA = BK + 8;
    constexpr int FN = BN / 32;
    constexpr int HN = BN / 2;
    __shared__ ushort lA[BM * LDA];
    __shared__ ushort lB[BN * LDA];
    const int tid  = threadIdx.x;
    const int lane = tid & 63;
    const int wid  = tid >> 6;
    const int wr = wid >> 1, wc = wid & 1;
    const int bm = blockIdx.y * BM, bn = blockIdx.x * BN;
    const int l15 = lane & 15, lk = lane >> 4;

    f32x4 acc[4][FN];
#pragma unroll
    for (int i = 0; i < 4; ++i)
#pragma unroll
        for (int j = 0; j < FN; ++j) acc[i][j] = (f32x4)0.f;

    for (int kk = 0; kk < K; kk += BK) {
        uint4 va[2], vb[BN / 64 ? BN / 64 : 1];
#pragma unroll
        for (int i = 0; i < 2; ++i) {
            int c = i * 256 + tid, row = c >> 2, k0 = (c & 3) * 8;
            va[i] = *(const uint4*)(A + (size_t)(bm + row) * K + kk + k0);
        }
#pragma unroll
        for (int i = 0; i < BN / 64; ++i) {
            int c = i * 256 + tid, row = c >> 2, k0 = (c & 3) * 8;
            vb[i] = *(const uint4*)(W + (size_t)(bn + row) * K + kk + k0);
        }
        __syncthreads();
#pragma unroll
        for (int i = 0; i < 2; ++i) {
            int c = i * 256 + tid, row = c >> 2, k0 = (c & 3) * 8;
            *(uint4*)&lA[row * LDA + k0] = va[i];
        }
#pragma unroll
        for (int i = 0; i < BN / 64; ++i) {
            int c = i * 256 + tid, row = c >> 2, k0 = (c & 3) * 8;
            *(uint4*)&lB[row * LDA + k0] = vb[i];
        }
        __syncthreads();

        bf16x8 af[4], bw[FN];
#pragma unroll
        for (int fm = 0; fm < 4; ++fm)
            af[fm] = *(const bf16x8*)&lA[(wr * 64 + fm * 16 + l15) * LDA + lk * 8];
#pragma unroll
        for (int fn = 0; fn < FN; ++fn)
            bw[fn] = *(const bf16x8*)&lB[(wc * HN + fn * 16 + l15) * LDA + lk * 8];
#pragma unroll
        for (int fm = 0; fm < 4; ++fm)
#pragma unroll
            for (int fn = 0; fn < FN; ++fn)
                acc[fm][fn] = __builtin_amdgcn_mfma_f32_16x16x32_bf16(
                    af[fm], bw[fn], acc[fm][fn], 0, 0, 0);
    }

#pragma unroll
    for (int fm = 0; fm < 4; ++fm) {
#pragma unroll
        for (int fn = 0; fn < FN; ++fn) {
            int col = bn + wc * HN + fn * 16 + l15;
            float bv = BIAS ? bias[col] : 0.f;
#pragma unroll
            for (int j = 0; j < 4; ++j) {
                int row = bm + wr * 64 + fm * 16 + lk * 4 + j;
                float r = acc[fm][fn][j] + bv;
                float* cp = C + (size_t)row * N + col;
                if (ACCUM) r += *cp;
                *cp = r;
            }
        }
    }
}

// ---------------- fp32 GEMM (small N / small K) -------------------------------
template<bool BIAS, bool ACCUM, int ACT>
__global__ __launch_bounds__(256) void gemm_tn(
    const float* __restrict__ A, int lda,
    const float* __restrict__ W, const float* __restrict__ bias,
    float* __restrict__ C, int M, int N, int K)
{
    constexpr int BM = 64, BN = 64, BK = 16;
    __shared__ float As[BK][BM + 4];
    __shared__ float Ws[BK][BN + 4];
    const int tid = threadIdx.x;
    const int bm = blockIdx.y * BM;
    const int bn = blockIdx.x * BN;
    const int lr = tid >> 2;
    const int kg = (tid & 3) * 4;
    const float* Aptr = A + (size_t)(bm + lr) * lda + kg;
    const float* Wptr = W + (size_t)(bn + lr) * K + kg;
    const int tx = tid & 15, ty = tid >> 4;
    float acc[4][4] = {};

    for (int kk = 0; kk < K; kk += BK) {
        float4 a4 = *(const float4*)(Aptr + kk);
        float4 w4 = *(const float4*)(Wptr + kk);
        __syncthreads();
        As[kg + 0][lr] = a4.x; As[kg + 1][lr] = a4.y;
        As[kg + 2][lr] = a4.z; As[kg + 3][lr] = a4.w;
        Ws[kg + 0][lr] = w4.x; Ws[kg + 1][lr] = w4.y;
        Ws[kg + 2][lr] = w4.z; Ws[kg + 3][lr] = w4.w;
        __syncthreads();
#pragma unroll
        for (int k = 0; k < BK; ++k) {
            float4 av = *(const float4*)&As[k][ty * 4];
            float4 wv = *(const float4*)&Ws[k][tx * 4];
            float a[4] = {av.x, av.y, av.z, av.w};
            float w[4] = {wv.x, wv.y, wv.z, wv.w};
#pragma unroll
            for (int i = 0; i < 4; ++i)
#pragma unroll
                for (int j = 0; j < 4; ++j) acc[i][j] += a[i] * w[j];
        }
    }
#pragma unroll
    for (int i = 0; i < 4; ++i) {
        int m = bm + ty * 4 + i;
        int n = bn + tx * 4;
        float r[4] = {acc[i][0], acc[i][1], acc[i][2], acc[i][3]};
        if (BIAS) {
            float4 bv = *(const float4*)(bias + n);
            r[0] += bv.x; r[1] += bv.y; r[2] += bv.z; r[3] += bv.w;
        }
        if (ACT == 1) {
#pragma unroll
            for (int j = 0; j < 4; ++j)
                r[j] = (r[j] > 20.f) ? r[j] : log1pf(expf(r[j]));
        }
        float* cp = C + (size_t)m * N + n;
        if (ACCUM) {
            float4 cv = *(const float4*)cp;
            r[0] += cv.x; r[1] += cv.y; r[2] += cv.z; r[3] += cv.w;
        }
        *(float4*)cp = make_float4(r[0], r[1], r[2], r[3]);
    }
}

// ---------------- RMSNorm over last dim D=512 ---------------------------------
template<bool BF16OUT>
__global__ __launch_bounds__(256) void rmsnorm_k(
    const float* __restrict__ X, const float* __restrict__ w,
    float* __restrict__ Yf, ushort* __restrict__ Yb)
{
    const int r = blockIdx.x;
    const float* x = X + (size_t)r * D_MODEL;
    float2 v = *(const float2*)(x + threadIdx.x * 2);
    float ss = v.x * v.x + v.y * v.y;
#pragma unroll
    for (int off = 32; off > 0; off >>= 1) ss += __shfl_down(ss, off);
    __shared__ float wsum[4];
    if ((threadIdx.x & 63) == 0) wsum[threadIdx.x >> 6] = ss;
    __syncthreads();
    float tot = wsum[0] + wsum[1] + wsum[2] + wsum[3];
    float rs = rsqrtf(tot * (1.f / D_MODEL) + 1e-5f);
    float2 wv = *(const float2*)(w + threadIdx.x * 2);
    float a = v.x * rs * wv.x, b = v.y * rs * wv.y;
    if (BF16OUT)
        *(ushort2*)(Yb + (size_t)r * D_MODEL + threadIdx.x * 2) =
            make_ushort2(f2bf(a), f2bf(b));
    else
        *(float2*)(Yf + (size_t)r * D_MODEL + threadIdx.x * 2) = make_float2(a, b);
}

// ---------------- depthwise causal conv1d (k=4) + bias + silu -----------------
__global__ __launch_bounds__(256) void conv_silu_k(
    const float* __restrict__ xr, const float* __restrict__ cw,
    const float* __restrict__ cb, float* __restrict__ xs)
{
    const int idx = blockIdx.x * 256 + threadIdx.x;
    const int d = idx & (D_INNER - 1);
    const int r = idx >> 10;
    const int l = r & (LL - 1);
    const float* base = xr + (size_t)r * (2 * D_INNER) + d;
    float4 w = *(const float4*)(cw + d * 4);
    float acc = cb[d];
    if (l >= 3) acc += base[-3 * 2 * D_INNER] * w.x;
    if (l >= 2) acc += base[-2 * 2 * D_INNER] * w.y;
    if (l >= 1) acc += base[-1 * 2 * D_INNER] * w.z;
    acc += base[0] * w.w;
    xs[idx] = acc / (1.f + __expf(-acc));
}

// ---------------- selective scan, chunk-parallel, 8 states/thread -------------
// Lane layout: j = tid&1 selects states n = j*8..j*8+7; d = dblk*128 + (tid>>1).
// Phase 1: scan chunk from h=0, store {S_sum, h_local} per state (float2).
__global__ __launch_bounds__(256) void scan1_k(
    const float* __restrict__ delta, const float* __restrict__ xs,
    const float* __restrict__ dbc, const float* __restrict__ A_log,
    float2* __restrict__ cb)
{
    const int b    = blockIdx.x >> 6;
    const int c    = (blockIdx.x >> 3) & 7;
    const int dblk = blockIdx.x & 7;
    const int d = dblk * 128 + (threadIdx.x >> 1);
    const int j = threadIdx.x & 1;

    float A[8];
#pragma unroll
    for (int s = 0; s < 8; ++s) A[s] = -__expf(A_log[d * D_STATE + j * 8 + s]);

    const int r0 = b * LL + c * LC;
    const float* pd = delta + (size_t)r0 * D_INNER + d;
    const float* px = xs    + (size_t)r0 * D_INNER + d;
    const float* pB = dbc   + (size_t)r0 * 64 + 32 + j * 8;

    float h[8] = {}, S[8] = {};
    float dt = *pd, x = *px;
    float4 B0 = *(const float4*)pB, B1 = *(const float4*)(pB + 4);

    for (int l = 0; l < LC; ++l) {
        pd += D_INNER; px += D_INNER; pB += 64;
        const float dt_n = *pd, x_n = *px;
        const float4 B0_n = *(const float4*)pB, B1_n = *(const float4*)(pB + 4);

        const float dx = dt * x;
        float Bs[8] = {B0.x, B0.y, B0.z, B0.w, B1.x, B1.y, B1.z, B1.w};
#pragma unroll
        for (int s = 0; s < 8; ++s) {
            const float sA = dt * A[s];
            S[s] += sA;
            h[s] = fmaf(__expf(sA), h[s], dx * Bs[s]);
        }
        dt = dt_n; x = x_n; B0 = B0_n; B1 = B1_n;
    }
    float2* cp = cb + ((size_t)(b * NCHUNK + c) * D_INNER + d) * D_STATE + j * 8;
#pragma unroll
    for (int s = 0; s < 8; ++s) cp[s] = make_float2(S[s], h[s]);
}

// Phase 2: fold predecessor summaries into h0, re-scan chunk, emit y (bf16).
__global__ __launch_bounds__(256) void scan2_k(
    const float* __restrict__ delta, const float* __restrict__ xs,
    const float* __restrict__ dbc, const float* __restrict__ xr,
    const float* __restrict__ A_log, const float* __restrict__ Dp,
    const float2* __restrict__ cb, ushort* __restrict__ yb)
{
    const int b    = blockIdx.x >> 6;
    const int c    = (blockIdx.x >> 3) & 7;
    const int dblk = blockIdx.x & 7;
    const int d = dblk * 128 + (threadIdx.x >> 1);
    const int j = threadIdx.x & 1;

    float A[8];
#pragma unroll
    for (int s = 0; s < 8; ++s) A[s] = -__expf(A_log[d * D_STATE + j * 8 + s]);
    const float Dd = Dp[d];

    float h[8] = {};
    for (int q = 0; q < NCHUNK - 1; ++q) {
        if (q < c) {
            const float2* cp = cb + ((size_t)(b * NCHUNK + q) * D_INNER + d) * D_STATE + j * 8;
#pragma unroll
            for (int s = 0; s < 8; ++s) {
                float2 v = cp[s];
                h[s] = fmaf(__expf(v.x), h[s], v.y);
            }
        }
    }

    const int r0 = b * LL + c * LC;
    const float* pd = delta + (size_t)r0 * D_INNER + d;
    const float* px = xs    + (size_t)r0 * D_INNER + d;
    const float* pB = dbc   + (size_t)r0 * 64 + 32 + j * 8;
    const float* pC = dbc   + (size_t)r0 * 64 + 48 + j * 8;
    const float* pr = xr    + (size_t)r0 * 2 * D_INNER + D_INNER + d;
    ushort*      py = yb    + (size_t)r0 * D_INNER + d;

    float dt = *pd, x = *px, res = *pr;
    float4 B0 = *(const float4*)pB, B1 = *(const float4*)(pB + 4);
    float4 C0 = *(const float4*)pC, C1 = *(const float4*)(pC + 4);

    for (int l = 0; l < LC; ++l) {
        // prefetch next step (tail over-reads stay inside d_ws)
        pd += D_INNER; px += D_INNER; pB += 64; pC += 64; pr += 2 * D_INNER;
        const float dt_n = *pd, x_n = *px, res_n = *pr;
        const float4 B0_n = *(const float4*)pB, B1_n = *(const float4*)(pB + 4);
        const float4 C0_n = *(const float4*)pC, C1_n = *(const float4*)(pC + 4);

        const float dx = dt * x;
        float Bs[8] = {B0.x, B0.y, B0.z, B0.w, B1.x, B1.y, B1.z, B1.w};
        float Cs[8] = {C0.x, C0.y, C0.z, C0.w, C1.x, C1.y, C1.z, C1.w};
        float p = 0.f;
#pragma unroll
        for (int s = 0; s < 8; ++s) {
            h[s] = fmaf(__expf(dt * A[s]), h[s], dx * Bs[s]);
            p = fmaf(h[s], Cs[s], p);
        }
        p += __shfl_xor(p, 1);
        if (j == 0) {
            const float g = res / (1.f + __expf(-res));
            py[(size_t)l * D_INNER] = f2bf((p + x * Dd) * g);
        }
        dt = dt_n; x = x_n; res = res_n;
        B0 = B0_n; B1 = B1_n; C0 = C0_n; C1 = C1_n;
    }
}

// ---------------- final stats ----------------
__global__ __launch_bounds__(512) void stats_k(
    const float* __restrict__ m, float* __restrict__ out)
{
    const int b = blockIdx.x;
    const int dm = threadIdx.x;
    const float* p = m + (size_t)b * LL * D_MODEL + dm;
    float s = 0.f;
    for (int l = 0; l < LL; ++l) s += p[(size_t)l * D_MODEL];
    const float mean = s * (1.f / LL);
    float ss = 0.f;
    for (int l = 0; l < LL; ++l) {
        float v = p[(size_t)l * D_MODEL] - mean;
        ss += v * v;
    }
    out[b * (2 * D_MODEL) + dm] = mean;
    out[b * (2 * D_MODEL) + D_MODEL + dm] = sqrtf(ss * (1.f / (LL - 1)));
}

// ---------------- host ----------------
extern "C" void kernel_launch(void* const* d_in, const int* in_sizes, int n_in,
                              void* d_out, int out_size, void* d_ws, size_t ws_size,
                              hipStream_t stream) {
    const float* x            = (const float*)d_in[0];
    const float* proj_w       = (const float*)d_in[1];
    const float* proj_b       = (const float*)d_in[2];
    const float* norm_w       = (const float*)d_in[3];
    const float* in_w         = (const float*)d_in[4];
    const float* conv_w       = (const float*)d_in[5];
    const float* conv_b       = (const float*)d_in[6];
    const float* xproj_w      = (const float*)d_in[7];
    const float* dt_w         = (const float*)d_in[8];
    const float* dt_b         = (const float*)d_in[9];
    const float* A_log        = (const float*)d_in[10];
    const float* Dp           = (const float*)d_in[11];
    const float* out_w        = (const float*)d_in[12];
    const float* final_norm_w = (const float*)d_in[13];

    float* ws  = (float*)d_ws;
    float* h   = ws;                                   // 4096*512
    float* xr  = h   + (size_t)M_ROWS * D_MODEL;       // 4096*2048
    float* xs  = xr  + (size_t)M_ROWS * 2 * D_INNER;   // 4096*1024
    float* dbc = xs  + (size_t)M_ROWS * D_INNER;       // 4096*64
    float* dlt = dbc + (size_t)M_ROWS * 64;            // 4096*1024
    ushort* xyb = (ushort*)(dlt + (size_t)M_ROWS * D_INNER);
    ushort* xnb = xyb + (size_t)M_ROWS * D_IN;
    ushort* pwb = xnb + (size_t)M_ROWS * D_MODEL;
    ushort* iwb = pwb + (size_t)D_MODEL * D_IN;
    ushort* owb = iwb + (size_t)2 * D_INNER * D_MODEL;
    float2* cbuf = (float2*)(owb + (size_t)D_MODEL * D_INNER);  // 8*8*1024*16 float2 = 8.4MB

    cast_bf16_k<<<(M_ROWS * D_IN / 4 + 255) / 256, 256, 0, stream>>>(x, xyb, M_ROWS * D_IN / 4);
    cast_bf16_k<<<(D_MODEL * D_IN / 4 + 255) / 256, 256, 0, stream>>>(proj_w, pwb, D_MODEL * D_IN / 4);

    gemm_bf16<64, true, false><<<dim3(D_MODEL / 64, M_ROWS / 128), 256, 0, stream>>>(
        xyb, pwb, proj_b, h, M_ROWS, D_MODEL, D_IN);

    for (int i = 0; i < N_LAYER; ++i) {
        cast_bf16_k<<<(2 * D_INNER * D_MODEL / 4 + 255) / 256, 256, 0, stream>>>(
            in_w + (size_t)i * 2 * D_INNER * D_MODEL, iwb, 2 * D_INNER * D_MODEL / 4);
        cast_bf16_k<<<(D_MODEL * D_INNER / 4 + 255) / 256, 256, 0, stream>>>(
            out_w + (size_t)i * D_MODEL * D_INNER, owb, D_MODEL * D_INNER / 4);

        rmsnorm_k<true><<<M_ROWS, 256, 0, stream>>>(h, norm_w + (size_t)i * D_MODEL, nullptr, xnb);

        gemm_bf16<128, false, false><<<dim3(2 * D_INNER / 128, M_ROWS / 128), 256, 0, stream>>>(
            xnb, iwb, nullptr, xr, M_ROWS, 2 * D_INNER, D_MODEL);

        conv_silu_k<<<M_ROWS * D_INNER / 256, 256, 0, stream>>>(
            xr, conv_w + (size_t)i * D_INNER * D_CONV, conv_b + (size_t)i * D_INNER, xs);

        gemm_tn<false, false, 0><<<dim3(1, M_ROWS / 64), 256, 0, stream>>>(
            xs, D_INNER, xproj_w + (size_t)i * 64 * D_INNER, nullptr, dbc,
            M_ROWS, 64, D_INNER);

        gemm_tn<true, false, 1><<<dim3(D_INNER / 64, M_ROWS / 64), 256, 0, stream>>>(
            dbc, 64, dt_w + (size_t)i * D_INNER * DT_RANK, dt_b + (size_t)i * D_INNER,
            dlt, M_ROWS, D_INNER, DT_RANK);

        scan1_k<<<BB * NCHUNK * (D_INNER / 128), 256, 0, stream>>>(
            dlt, xs, dbc, A_log + (size_t)i * D_INNER * D_STATE, cbuf);
        scan2_k<<<BB * NCHUNK * (D_INNER / 128), 256, 0, stream>>>(
            dlt, xs, dbc, xr, A_log + (size_t)i * D_INNER * D_STATE,
            Dp + (size_t)i * D_INNER, cbuf, xyb);

        gemm_bf16<64, false, true><<<dim3(D_MODEL / 64, M_ROWS / 128), 256, 0, stream>>>(
            xyb, owb, nullptr, h, M_ROWS, D_MODEL, D_INNER);
    }

    rmsnorm_k<false><<<M_ROWS, 256, 0, stream>>>(h, final_norm_w, xs, nullptr);
    stats_k<<<BB, D_MODEL, 0, stream>>>(xs, (float*)d_out);
}

// Round 7
// 1064.192 us; speedup vs baseline: 4.2230x; 1.0159x over previous
//
#include <hip/hip_runtime.h>
#include <math.h>

// ---------------- dims (fixed by the problem) ----------------
#define D_IN     1280
#define D_MODEL  512
#define N_LAYER  4
#define D_STATE  16
#define D_CONV   4
#define D_INNER  1024
#define DT_RANK  32
#define BB       8
#define LL       512
#define M_ROWS   (BB*LL)          // 4096
#define NCHUNK   8
#define LC       (LL/NCHUNK)      // 64

typedef short bf16x8 __attribute__((ext_vector_type(8)));
typedef float f32x4  __attribute__((ext_vector_type(4)));

__device__ __forceinline__ ushort f2bf(float f) {
    unsigned u = __float_as_uint(f);
    u = (u + 0x7FFF + ((u >> 16) & 1)) >> 16;   // RNE
    return (ushort)u;
}
__device__ __forceinline__ float bf2f(ushort u) {
    return __uint_as_float((unsigned)u << 16);
}

// ---------------- fp32 -> bf16 cast (n multiple of 4) ----------------
__global__ __launch_bounds__(256) void cast_bf16_k(
    const float* __restrict__ in, ushort* __restrict__ out, int n4)
{
    int i = blockIdx.x * 256 + threadIdx.x;
    if (i < n4) {
        float4 v = *(const float4*)(in + (size_t)i * 4);
        *(ushort4*)(out + (size_t)i * 4) =
            make_ushort4(f2bf(v.x), f2bf(v.y), f2bf(v.z), f2bf(v.w));
    }
}

// ---- extract+cast delta cols: dbc[4096,64] cols 0..31 -> bf16 [4096,32] ------
__global__ __launch_bounds__(256) void cast_delta_k(
    const float* __restrict__ dbc, ushort* __restrict__ out)
{
    int i = blockIdx.x * 256 + threadIdx.x;   // over 4096*16 float2
    int r = i >> 4;
    int c = (i & 15) * 2;
    float2 v = *(const float2*)(dbc + (size_t)r * 64 + c);
    *(ushort2*)(out + (size_t)r * 32 + c) = make_ushort2(f2bf(v.x), f2bf(v.y));
}

// ---------------- bf16 MFMA GEMM: C[M,N] = A[M,K] @ W[N,K]^T ------------------
// BM=128, BK=32, 256 threads = 4 waves (2x2), wave tile 64 x BN/2.
// ACT: 0 = none, 1 = softplus (for dt path).
template<int BN, bool BIAS, bool ACCUM, int ACT>
__global__ __launch_bounds__(256) void gemm_bf16(
    const ushort* __restrict__ A, const ushort* __restrict__ W,
    const float* __restrict__ bias, float* __restrict__ C,
    int M, int N, int K)
{
    constexpr int BM = 128, BK = 32;
    constexpr int LDA = BK + 8;
    constexpr int FN = (BN >= 32) ? BN / 32 : 1;
    constexpr int HN = BN / 2;
    constexpr int BL = (BN * 4 + 255) / 256;       // B-tile uint4 loads/thread
    __shared__ ushort lA[BM * LDA];
    __shared__ ushort lB[BN * LDA];
    const int tid  = threadIdx.x;
    const int lane = tid & 63;
    const int wid  = tid >> 6;
    const int wr = wid >> 1, wc = wid & 1;
    const int bm = blockIdx.y * BM, bn = blockIdx.x * BN;
    const int l15 = lane & 15, lk = lane >> 4;

    f32x4 acc[4][FN];
#pragma unroll
    for (int i = 0; i < 4; ++i)
#pragma unroll
        for (int j = 0; j < FN; ++j) acc[i][j] = (f32x4)0.f;

    for (int kk = 0; kk < K; kk += BK) {
        uint4 va[2], vb[BL];
#pragma unroll
        for (int i = 0; i < 2; ++i) {
            int c = i * 256 + tid, row = c >> 2, k0 = (c & 3) * 8;
            va[i] = *(const uint4*)(A + (size_t)(bm + row) * K + kk + k0);
        }
#pragma unroll
        for (int i = 0; i < BL; ++i) {
            int c = i * 256 + tid;
            if ((BN * 4 % 256 == 0) || c < BN * 4) {
                int row = c >> 2, k0 = (c & 3) * 8;
                vb[i] = *(const uint4*)(W + (size_t)(bn + row) * K + kk + k0);
            }
        }
        __syncthreads();
#pragma unroll
        for (int i = 0; i < 2; ++i) {
            int c = i * 256 + tid, row = c >> 2, k0 = (c & 3) * 8;
            *(uint4*)&lA[row * LDA + k0] = va[i];
        }
#pragma unroll
        for (int i = 0; i < BL; ++i) {
            int c = i * 256 + tid;
            if ((BN * 4 % 256 == 0) || c < BN * 4) {
                int row = c >> 2, k0 = (c & 3) * 8;
                *(uint4*)&lB[row * LDA + k0] = vb[i];
            }
        }
        __syncthreads();

        bf16x8 af[4], bw[FN];
#pragma unroll
        for (int fm = 0; fm < 4; ++fm)
            af[fm] = *(const bf16x8*)&lA[(wr * 64 + fm * 16 + l15) * LDA + lk * 8];
#pragma unroll
        for (int fn = 0; fn < FN; ++fn)
            bw[fn] = *(const bf16x8*)&lB[(wc * HN + fn * 16 + l15) * LDA + lk * 8];
#pragma unroll
        for (int fm = 0; fm < 4; ++fm)
#pragma unroll
            for (int fn = 0; fn < FN; ++fn)
                acc[fm][fn] = __builtin_amdgcn_mfma_f32_16x16x32_bf16(
                    af[fm], bw[fn], acc[fm][fn], 0, 0, 0);
    }

#pragma unroll
    for (int fm = 0; fm < 4; ++fm) {
#pragma unroll
        for (int fn = 0; fn < FN; ++fn) {
            int col = bn + wc * HN + fn * 16 + l15;
            float bv = BIAS ? bias[col] : 0.f;
#pragma unroll
            for (int j = 0; j < 4; ++j) {
                int row = bm + wr * 64 + fm * 16 + lk * 4 + j;
                float r = acc[fm][fn][j] + bv;
                if (ACT == 1) r = (r > 20.f) ? r : log1pf(expf(r));
                float* cp = C + (size_t)row * N + col;
                if (ACCUM) r += *cp;
                *cp = r;
            }
        }
    }
}

// ---------------- RMSNorm over last dim D=512 ---------------------------------
template<bool BF16OUT>
__global__ __launch_bounds__(256) void rmsnorm_k(
    const float* __restrict__ X, const float* __restrict__ w,
    float* __restrict__ Yf, ushort* __restrict__ Yb)
{
    const int r = blockIdx.x;
    const float* x = X + (size_t)r * D_MODEL;
    float2 v = *(const float2*)(x + threadIdx.x * 2);
    float ss = v.x * v.x + v.y * v.y;
#pragma unroll
    for (int off = 32; off > 0; off >>= 1) ss += __shfl_down(ss, off);
    __shared__ float wsum[4];
    if ((threadIdx.x & 63) == 0) wsum[threadIdx.x >> 6] = ss;
    __syncthreads();
    float tot = wsum[0] + wsum[1] + wsum[2] + wsum[3];
    float rs = rsqrtf(tot * (1.f / D_MODEL) + 1e-5f);
    float2 wv = *(const float2*)(w + threadIdx.x * 2);
    float a = v.x * rs * wv.x, b = v.y * rs * wv.y;
    if (BF16OUT)
        *(ushort2*)(Yb + (size_t)r * D_MODEL + threadIdx.x * 2) =
            make_ushort2(f2bf(a), f2bf(b));
    else
        *(float2*)(Yf + (size_t)r * D_MODEL + threadIdx.x * 2) = make_float2(a, b);
}

// ------- depthwise causal conv1d (k=4) + bias + silu -> bf16 xs ---------------
__global__ __launch_bounds__(256) void conv_silu_k(
    const float* __restrict__ xr, const float* __restrict__ cw,
    const float* __restrict__ cb, ushort* __restrict__ xsb)
{
    const int idx = blockIdx.x * 256 + threadIdx.x;
    const int d = idx & (D_INNER - 1);
    const int r = idx >> 10;
    const int l = r & (LL - 1);
    const float* base = xr + (size_t)r * (2 * D_INNER) + d;
    float4 w = *(const float4*)(cw + d * 4);
    float acc = cb[d];
    if (l >= 3) acc += base[-3 * 2 * D_INNER] * w.x;
    if (l >= 2) acc += base[-2 * 2 * D_INNER] * w.y;
    if (l >= 1) acc += base[-1 * 2 * D_INNER] * w.z;
    acc += base[0] * w.w;
    xsb[idx] = f2bf(acc / (1.f + __expf(-acc)));
}

// ---------------- selective scan, chunk-parallel, 8 states/thread -------------
// Lane layout: j = tid&1 selects states n = j*8..j*8+7; d = dblk*128 + (tid>>1).
__global__ __launch_bounds__(256) void scan1_k(
    const float* __restrict__ delta, const ushort* __restrict__ xsb,
    const float* __restrict__ dbc, const float* __restrict__ A_log,
    float2* __restrict__ cb)
{
    const int b    = blockIdx.x >> 6;
    const int c    = (blockIdx.x >> 3) & 7;
    const int dblk = blockIdx.x & 7;
    const int d = dblk * 128 + (threadIdx.x >> 1);
    const int j = threadIdx.x & 1;

    float A[8];
#pragma unroll
    for (int s = 0; s < 8; ++s) A[s] = -__expf(A_log[d * D_STATE + j * 8 + s]);

    const int r0 = b * LL + c * LC;
    const float* pd  = delta + (size_t)r0 * D_INNER + d;
    const ushort* px = xsb   + (size_t)r0 * D_INNER + d;
    const float* pB  = dbc   + (size_t)r0 * 64 + 32 + j * 8;

    float h[8] = {}, S[8] = {};
    float dt = *pd, x = bf2f(*px);
    float4 B0 = *(const float4*)pB, B1 = *(const float4*)(pB + 4);

    for (int l = 0; l < LC; ++l) {
        pd += D_INNER; px += D_INNER; pB += 64;
        const float dt_n = *pd, x_n = bf2f(*px);
        const float4 B0_n = *(const float4*)pB, B1_n = *(const float4*)(pB + 4);

        const float dx = dt * x;
        float Bs[8] = {B0.x, B0.y, B0.z, B0.w, B1.x, B1.y, B1.z, B1.w};
#pragma unroll
        for (int s = 0; s < 8; ++s) {
            const float sA = dt * A[s];
            S[s] += sA;
            h[s] = fmaf(__expf(sA), h[s], dx * Bs[s]);
        }
        dt = dt_n; x = x_n; B0 = B0_n; B1 = B1_n;
    }
    float2* cp = cb + ((size_t)(b * NCHUNK + c) * D_INNER + d) * D_STATE + j * 8;
#pragma unroll
    for (int s = 0; s < 8; ++s) cp[s] = make_float2(S[s], h[s]);
}

// Phase 2: fold predecessor summaries into h0, re-scan chunk, emit y (bf16).
__global__ __launch_bounds__(256) void scan2_k(
    const float* __restrict__ delta, const ushort* __restrict__ xsb,
    const float* __restrict__ dbc, const float* __restrict__ xr,
    const float* __restrict__ A_log, const float* __restrict__ Dp,
    const float2* __restrict__ cb, ushort* __restrict__ yb)
{
    const int b    = blockIdx.x >> 6;
    const int c    = (blockIdx.x >> 3) & 7;
    const int dblk = blockIdx.x & 7;
    const int d = dblk * 128 + (threadIdx.x >> 1);
    const int j = threadIdx.x & 1;

    float A[8];
#pragma unroll
    for (int s = 0; s < 8; ++s) A[s] = -__expf(A_log[d * D_STATE + j * 8 + s]);
    const float Dd = Dp[d];

    float h[8] = {};
    for (int q = 0; q < NCHUNK - 1; ++q) {
        if (q < c) {
            const float2* cp = cb + ((size_t)(b * NCHUNK + q) * D_INNER + d) * D_STATE + j * 8;
#pragma unroll
            for (int s = 0; s < 8; ++s) {
                float2 v = cp[s];
                h[s] = fmaf(__expf(v.x), h[s], v.y);
            }
        }
    }

    const int r0 = b * LL + c * LC;
    const float* pd  = delta + (size_t)r0 * D_INNER + d;
    const ushort* px = xsb   + (size_t)r0 * D_INNER + d;
    const float* pB  = dbc   + (size_t)r0 * 64 + 32 + j * 8;
    const float* pC  = dbc   + (size_t)r0 * 64 + 48 + j * 8;
    const float* pr  = xr    + (size_t)r0 * 2 * D_INNER + D_INNER + d;
    ushort*      py  = yb    + (size_t)r0 * D_INNER + d;

    float dt = *pd, x = bf2f(*px), res = *pr;
    float4 B0 = *(const float4*)pB, B1 = *(const float4*)(pB + 4);
    float4 C0 = *(const float4*)pC, C1 = *(const float4*)(pC + 4);

    for (int l = 0; l < LC; ++l) {
        // prefetch next step (tail over-reads stay inside d_ws)
        pd += D_INNER; px += D_INNER; pB += 64; pC += 64; pr += 2 * D_INNER;
        const float dt_n = *pd, x_n = bf2f(*px), res_n = *pr;
        const float4 B0_n = *(const float4*)pB, B1_n = *(const float4*)(pB + 4);
        const float4 C0_n = *(const float4*)pC, C1_n = *(const float4*)(pC + 4);

        const float dx = dt * x;
        float Bs[8] = {B0.x, B0.y, B0.z, B0.w, B1.x, B1.y, B1.z, B1.w};
        float Cs[8] = {C0.x, C0.y, C0.z, C0.w, C1.x, C1.y, C1.z, C1.w};
        float p = 0.f;
#pragma unroll
        for (int s = 0; s < 8; ++s) {
            h[s] = fmaf(__expf(dt * A[s]), h[s], dx * Bs[s]);
            p = fmaf(h[s], Cs[s], p);
        }
        p += __shfl_xor(p, 1);
        if (j == 0) {
            const float g = res / (1.f + __expf(-res));
            py[(size_t)l * D_INNER] = f2bf((p + x * Dd) * g);
        }
        dt = dt_n; x = x_n; res = res_n;
        B0 = B0_n; B1 = B1_n; C0 = C0_n; C1 = C1_n;
    }
}

// ---------------- final stats ----------------
__global__ __launch_bounds__(512) void stats_k(
    const float* __restrict__ m, float* __restrict__ out)
{
    const int b = blockIdx.x;
    const int dm = threadIdx.x;
    const float* p = m + (size_t)b * LL * D_MODEL + dm;
    float s = 0.f;
    for (int l = 0; l < LL; ++l) s += p[(size_t)l * D_MODEL];
    const float mean = s * (1.f / LL);
    float ss = 0.f;
    for (int l = 0; l < LL; ++l) {
        float v = p[(size_t)l * D_MODEL] - mean;
        ss += v * v;
    }
    out[b * (2 * D_MODEL) + dm] = mean;
    out[b * (2 * D_MODEL) + D_MODEL + dm] = sqrtf(ss * (1.f / (LL - 1)));
}

// ---------------- host ----------------
extern "C" void kernel_launch(void* const* d_in, const int* in_sizes, int n_in,
                              void* d_out, int out_size, void* d_ws, size_t ws_size,
                              hipStream_t stream) {
    const float* x            = (const float*)d_in[0];
    const float* proj_w       = (const float*)d_in[1];
    const float* proj_b       = (const float*)d_in[2];
    const float* norm_w       = (const float*)d_in[3];
    const float* in_w         = (const float*)d_in[4];
    const float* conv_w       = (const float*)d_in[5];
    const float* conv_b       = (const float*)d_in[6];
    const float* xproj_w      = (const float*)d_in[7];
    const float* dt_w         = (const float*)d_in[8];
    const float* dt_b         = (const float*)d_in[9];
    const float* A_log        = (const float*)d_in[10];
    const float* Dp           = (const float*)d_in[11];
    const float* out_w        = (const float*)d_in[12];
    const float* final_norm_w = (const float*)d_in[13];

    // fp32 region
    float* ws  = (float*)d_ws;
    float* h   = ws;                                   // 4096*512
    float* xr  = h   + (size_t)M_ROWS * D_MODEL;       // 4096*2048
    float* dbc = xr  + (size_t)M_ROWS * 2 * D_INNER;   // 4096*64
    float* dlt = dbc + (size_t)M_ROWS * 64;            // 4096*1024 (also final-norm buf)
    // bf16 region
    ushort* xyb  = (ushort*)(dlt + (size_t)M_ROWS * D_INNER);  // max(4096*1280, 4096*1024)
    ushort* xnb  = xyb  + (size_t)M_ROWS * D_IN;       // 4096*512
    ushort* xsb  = xnb  + (size_t)M_ROWS * D_MODEL;    // 4096*1024
    ushort* pwb  = xsb  + (size_t)M_ROWS * D_INNER;    // 512*1280
    ushort* iwb  = pwb  + (size_t)D_MODEL * D_IN;      // 2048*512 (per-layer)
    ushort* owb  = iwb  + (size_t)2 * D_INNER * D_MODEL; // 512*1024 (per-layer)
    ushort* xpwb = owb  + (size_t)D_MODEL * D_INNER;   // 64*1024 (per-layer)
    ushort* dtwb = xpwb + (size_t)64 * D_INNER;        // 1024*32 (per-layer)
    ushort* dltb = dtwb + (size_t)D_INNER * DT_RANK;   // 4096*32
    float2* cbuf = (float2*)(dltb + (size_t)M_ROWS * DT_RANK); // 8*8*1024*16 float2

    cast_bf16_k<<<(M_ROWS * D_IN / 4 + 255) / 256, 256, 0, stream>>>(x, xyb, M_ROWS * D_IN / 4);
    cast_bf16_k<<<(D_MODEL * D_IN / 4 + 255) / 256, 256, 0, stream>>>(proj_w, pwb, D_MODEL * D_IN / 4);

    gemm_bf16<64, true, false, 0><<<dim3(D_MODEL / 64, M_ROWS / 128), 256, 0, stream>>>(
        xyb, pwb, proj_b, h, M_ROWS, D_MODEL, D_IN);

    for (int i = 0; i < N_LAYER; ++i) {
        cast_bf16_k<<<(2 * D_INNER * D_MODEL / 4 + 255) / 256, 256, 0, stream>>>(
            in_w + (size_t)i * 2 * D_INNER * D_MODEL, iwb, 2 * D_INNER * D_MODEL / 4);
        cast_bf16_k<<<(D_MODEL * D_INNER / 4 + 255) / 256, 256, 0, stream>>>(
            out_w + (size_t)i * D_MODEL * D_INNER, owb, D_MODEL * D_INNER / 4);
        cast_bf16_k<<<(64 * D_INNER / 4 + 255) / 256, 256, 0, stream>>>(
            xproj_w + (size_t)i * 64 * D_INNER, xpwb, 64 * D_INNER / 4);
        cast_bf16_k<<<(D_INNER * DT_RANK / 4 + 255) / 256, 256, 0, stream>>>(
            dt_w + (size_t)i * D_INNER * DT_RANK, dtwb, D_INNER * DT_RANK / 4);

        rmsnorm_k<true><<<M_ROWS, 256, 0, stream>>>(h, norm_w + (size_t)i * D_MODEL, nullptr, xnb);

        gemm_bf16<128, false, false, 0><<<dim3(2 * D_INNER / 128, M_ROWS / 128), 256, 0, stream>>>(
            xnb, iwb, nullptr, xr, M_ROWS, 2 * D_INNER, D_MODEL);

        conv_silu_k<<<M_ROWS * D_INNER / 256, 256, 0, stream>>>(
            xr, conv_w + (size_t)i * D_INNER * D_CONV, conv_b + (size_t)i * D_INNER, xsb);

        // dbc = xs @ xproj_w^T   (bf16 MFMA, BN=32 -> 64 blocks)
        gemm_bf16<32, false, false, 0><<<dim3(64 / 32, M_ROWS / 128), 256, 0, stream>>>(
            xsb, xpwb, nullptr, dbc, M_ROWS, 64, D_INNER);

        cast_delta_k<<<M_ROWS * 16 / 256, 256, 0, stream>>>(dbc, dltb);

        // dlt = softplus(delta @ dt_w^T + dt_b)   (bf16 MFMA, K=32)
        gemm_bf16<128, true, false, 1><<<dim3(D_INNER / 128, M_ROWS / 128), 256, 0, stream>>>(
            dltb, dtwb, dt_b + (size_t)i * D_INNER, dlt, M_ROWS, D_INNER, DT_RANK);

        scan1_k<<<BB * NCHUNK * (D_INNER / 128), 256, 0, stream>>>(
            dlt, xsb, dbc, A_log + (size_t)i * D_INNER * D_STATE, cbuf);
        scan2_k<<<BB * NCHUNK * (D_INNER / 128), 256, 0, stream>>>(
            dlt, xsb, dbc, xr, A_log + (size_t)i * D_INNER * D_STATE,
            Dp + (size_t)i * D_INNER, cbuf, xyb);

        gemm_bf16<64, false, true, 0><<<dim3(D_MODEL / 64, M_ROWS / 128), 256, 0, stream>>>(
            xyb, owb, nullptr, h, M_ROWS, D_MODEL, D_INNER);
    }

    rmsnorm_k<false><<<M_ROWS, 256, 0, stream>>>(h, final_norm_w, dlt, nullptr);
    stats_k<<<BB, D_MODEL, 0, stream>>>(dlt, (float*)d_out);
}

// Round 8
// 845.037 us; speedup vs baseline: 5.3182x; 1.2593x over previous
//
#include <hip/hip_runtime.h>
#include <math.h>

// ---------------- dims (fixed by the problem) ----------------
#define D_IN     1280
#define D_MODEL  512
#define N_LAYER  4
#define D_STATE  16
#define D_CONV   4
#define D_INNER  1024
#define DT_RANK  32
#define BB       8
#define LL       512
#define M_ROWS   (BB*LL)          // 4096
#define NCHUNK   8
#define LC       (LL/NCHUNK)      // 64

typedef short bf16x8 __attribute__((ext_vector_type(8)));
typedef float f32x4  __attribute__((ext_vector_type(4)));

__device__ __forceinline__ ushort f2bf(float f) {
    unsigned u = __float_as_uint(f);
    u = (u + 0x7FFF + ((u >> 16) & 1)) >> 16;   // RNE
    return (ushort)u;
}
__device__ __forceinline__ float bf2f(ushort u) {
    return __uint_as_float((unsigned)u << 16);
}

// ---------------- fp32 -> bf16 cast (n multiple of 4) ----------------
__global__ __launch_bounds__(256) void cast_bf16_k(
    const float* __restrict__ in, ushort* __restrict__ out, int n4)
{
    int i = blockIdx.x * 256 + threadIdx.x;
    if (i < n4) {
        float4 v = *(const float4*)(in + (size_t)i * 4);
        *(ushort4*)(out + (size_t)i * 4) =
            make_ushort4(f2bf(v.x), f2bf(v.y), f2bf(v.z), f2bf(v.w));
    }
}

// ---- split-K reduce for dbc: sum 4 partials; also emit delta cols as bf16 ----
__global__ __launch_bounds__(256) void reduce_dbc_k(
    const float* __restrict__ part, float* __restrict__ dbc,
    ushort* __restrict__ dltb)
{
    const int i = blockIdx.x * 256 + threadIdx.x;   // over 4096*64
    const int c = i & 63;
    float s = part[i] + part[i + M_ROWS * 64] + part[i + 2 * M_ROWS * 64]
            + part[i + 3 * M_ROWS * 64];
    dbc[i] = s;
    if (c < 32) dltb[(i >> 6) * 32 + c] = f2bf(s);
}

// ---------------- bf16 MFMA GEMM: C[M,N] = A[M,K] @ W[N,K]^T ------------------
// BM=128: 4 waves 2x2 (wave tile 64 x BN/2). BM=64: 4 waves 1x4 (64 x BN/4).
// Split-K via gridDim.z: K arg = per-split iter count; C += z*M*N.
// ACT: 0=none, 1=softplus. OUTBF: write bf16 (no ACCUM support combined).
template<int BM, int BN, bool BIAS, bool ACCUM, int ACT, bool OUTBF>
__global__ __launch_bounds__(256) void gemm_bf16(
    const ushort* __restrict__ A, const ushort* __restrict__ W,
    const float* __restrict__ bias, void* __restrict__ Cv,
    int M, int N, int K, int lda, int ldw)
{
    constexpr int BK = 32;
    constexpr int LDA = BK + 8;                 // 40 ushorts = 80 B rows
    constexpr int WC = (BM == 128) ? 2 : 4;     // wave cols
    constexpr int HN = BN / WC;                 // wave N-tile
    constexpr int FN = HN / 16;                 // N frags per wave
    constexpr int AL = BM / 64;                 // A-tile uint4 loads/thread
    constexpr int BL = (BN * 4 + 255) / 256;    // B-tile uint4 loads/thread
    __shared__ ushort lA[BM * LDA];
    __shared__ ushort lB[BN * LDA];
    const int tid  = threadIdx.x;
    const int lane = tid & 63;
    const int wid  = tid >> 6;
    const int wr = (BM == 128) ? (wid >> 1) : 0;
    const int wc = (BM == 128) ? (wid & 1) : wid;
    const int bm = blockIdx.y * BM, bn = blockIdx.x * BN;
    const int koff = blockIdx.z * K;
    const size_t cz = (size_t)blockIdx.z * M * N;
    const int l15 = lane & 15, lk = lane >> 4;

    f32x4 acc[4][FN];
#pragma unroll
    for (int i = 0; i < 4; ++i)
#pragma unroll
        for (int j = 0; j < FN; ++j) acc[i][j] = (f32x4)0.f;

    for (int kk = 0; kk < K; kk += BK) {
        uint4 va[AL], vb[BL];
#pragma unroll
        for (int i = 0; i < AL; ++i) {
            int c = i * 256 + tid, row = c >> 2, k0 = (c & 3) * 8;
            va[i] = *(const uint4*)(A + (size_t)(bm + row) * lda + koff + kk + k0);
        }
#pragma unroll
        for (int i = 0; i < BL; ++i) {
            int c = i * 256 + tid;
            if ((BN * 4 % 256 == 0) || c < BN * 4) {
                int row = c >> 2, k0 = (c & 3) * 8;
                vb[i] = *(const uint4*)(W + (size_t)(bn + row) * ldw + koff + kk + k0);
            }
        }
        __syncthreads();
#pragma unroll
        for (int i = 0; i < AL; ++i) {
            int c = i * 256 + tid, row = c >> 2, k0 = (c & 3) * 8;
            *(uint4*)&lA[row * LDA + k0] = va[i];
        }
#pragma unroll
        for (int i = 0; i < BL; ++i) {
            int c = i * 256 + tid;
            if ((BN * 4 % 256 == 0) || c < BN * 4) {
                int row = c >> 2, k0 = (c & 3) * 8;
                *(uint4*)&lB[row * LDA + k0] = vb[i];
            }
        }
        __syncthreads();

        bf16x8 af[4], bw[FN];
#pragma unroll
        for (int fm = 0; fm < 4; ++fm)
            af[fm] = *(const bf16x8*)&lA[(wr * 64 + fm * 16 + l15) * LDA + lk * 8];
#pragma unroll
        for (int fn = 0; fn < FN; ++fn)
            bw[fn] = *(const bf16x8*)&lB[(wc * HN + fn * 16 + l15) * LDA + lk * 8];
#pragma unroll
        for (int fm = 0; fm < 4; ++fm)
#pragma unroll
            for (int fn = 0; fn < FN; ++fn)
                acc[fm][fn] = __builtin_amdgcn_mfma_f32_16x16x32_bf16(
                    af[fm], bw[fn], acc[fm][fn], 0, 0, 0);
    }

    float*  Cf = (float*)Cv + cz;
    ushort* Cb = (ushort*)Cv + cz;
#pragma unroll
    for (int fm = 0; fm < 4; ++fm) {
#pragma unroll
        for (int fn = 0; fn < FN; ++fn) {
            int col = bn + wc * HN + fn * 16 + l15;
            float bv = BIAS ? bias[col] : 0.f;
#pragma unroll
            for (int j = 0; j < 4; ++j) {
                int row = bm + wr * 64 + fm * 16 + lk * 4 + j;
                float r = acc[fm][fn][j] + bv;
                if (ACT == 1) r = (r > 20.f) ? r : log1pf(expf(r));
                if (OUTBF) {
                    Cb[(size_t)row * N + col] = f2bf(r);
                } else {
                    float* cp = Cf + (size_t)row * N + col;
                    if (ACCUM) r += *cp;
                    *cp = r;
                }
            }
        }
    }
}

// ---------------- RMSNorm over last dim D=512 ---------------------------------
template<bool BF16OUT>
__global__ __launch_bounds__(256) void rmsnorm_k(
    const float* __restrict__ X, const float* __restrict__ w,
    float* __restrict__ Yf, ushort* __restrict__ Yb)
{
    const int r = blockIdx.x;
    const float* x = X + (size_t)r * D_MODEL;
    float2 v = *(const float2*)(x + threadIdx.x * 2);
    float ss = v.x * v.x + v.y * v.y;
#pragma unroll
    for (int off = 32; off > 0; off >>= 1) ss += __shfl_down(ss, off);
    __shared__ float wsum[4];
    if ((threadIdx.x & 63) == 0) wsum[threadIdx.x >> 6] = ss;
    __syncthreads();
    float tot = wsum[0] + wsum[1] + wsum[2] + wsum[3];
    float rs = rsqrtf(tot * (1.f / D_MODEL) + 1e-5f);
    float2 wv = *(const float2*)(w + threadIdx.x * 2);
    float a = v.x * rs * wv.x, b = v.y * rs * wv.y;
    if (BF16OUT)
        *(ushort2*)(Yb + (size_t)r * D_MODEL + threadIdx.x * 2) =
            make_ushort2(f2bf(a), f2bf(b));
    else
        *(float2*)(Yf + (size_t)r * D_MODEL + threadIdx.x * 2) = make_float2(a, b);
}

// ------- depthwise causal conv1d (k=4, bf16 in) + bias + silu -> bf16 xs ------
__global__ __launch_bounds__(256) void conv_silu_k(
    const ushort* __restrict__ xrb, const float* __restrict__ cw,
    const float* __restrict__ cb, ushort* __restrict__ xsb)
{
    const int idx = blockIdx.x * 256 + threadIdx.x;
    const int d = idx & (D_INNER - 1);
    const int r = idx >> 10;
    const int l = r & (LL - 1);
    const ushort* base = xrb + (size_t)r * (2 * D_INNER) + d;
    float4 w = *(const float4*)(cw + d * 4);
    float acc = cb[d];
    if (l >= 3) acc += bf2f(base[-3 * 2 * D_INNER]) * w.x;
    if (l >= 2) acc += bf2f(base[-2 * 2 * D_INNER]) * w.y;
    if (l >= 1) acc += bf2f(base[-1 * 2 * D_INNER]) * w.z;
    acc += bf2f(base[0]) * w.w;
    xsb[idx] = f2bf(acc / (1.f + __expf(-acc)));
}

// ---------------- selective scan, chunk-parallel, 8 states/thread -------------
__global__ __launch_bounds__(256) void scan1_k(
    const float* __restrict__ delta, const ushort* __restrict__ xsb,
    const float* __restrict__ dbc, const float* __restrict__ A_log,
    float2* __restrict__ cb)
{
    const int b    = blockIdx.x >> 6;
    const int c    = (blockIdx.x >> 3) & 7;
    const int dblk = blockIdx.x & 7;
    const int d = dblk * 128 + (threadIdx.x >> 1);
    const int j = threadIdx.x & 1;

    float A[8];
#pragma unroll
    for (int s = 0; s < 8; ++s) A[s] = -__expf(A_log[d * D_STATE + j * 8 + s]);

    const int r0 = b * LL + c * LC;
    const float* pd  = delta + (size_t)r0 * D_INNER + d;
    const ushort* px = xsb   + (size_t)r0 * D_INNER + d;
    const float* pB  = dbc   + (size_t)r0 * 64 + 32 + j * 8;

    float h[8] = {}, S[8] = {};
    float dt = *pd, x = bf2f(*px);
    float4 B0 = *(const float4*)pB, B1 = *(const float4*)(pB + 4);

    for (int l = 0; l < LC; ++l) {
        pd += D_INNER; px += D_INNER; pB += 64;
        const float dt_n = *pd, x_n = bf2f(*px);
        const float4 B0_n = *(const float4*)pB, B1_n = *(const float4*)(pB + 4);

        const float dx = dt * x;
        float Bs[8] = {B0.x, B0.y, B0.z, B0.w, B1.x, B1.y, B1.z, B1.w};
#pragma unroll
        for (int s = 0; s < 8; ++s) {
            const float sA = dt * A[s];
            S[s] += sA;
            h[s] = fmaf(__expf(sA), h[s], dx * Bs[s]);
        }
        dt = dt_n; x = x_n; B0 = B0_n; B1 = B1_n;
    }
    float2* cp = cb + ((size_t)(b * NCHUNK + c) * D_INNER + d) * D_STATE + j * 8;
#pragma unroll
    for (int s = 0; s < 8; ++s) cp[s] = make_float2(S[s], h[s]);
}

__global__ __launch_bounds__(256) void scan2_k(
    const float* __restrict__ delta, const ushort* __restrict__ xsb,
    const float* __restrict__ dbc, const ushort* __restrict__ xrb,
    const float* __restrict__ A_log, const float* __restrict__ Dp,
    const float2* __restrict__ cb, ushort* __restrict__ yb)
{
    const int b    = blockIdx.x >> 6;
    const int c    = (blockIdx.x >> 3) & 7;
    const int dblk = blockIdx.x & 7;
    const int d = dblk * 128 + (threadIdx.x >> 1);
    const int j = threadIdx.x & 1;

    float A[8];
#pragma unroll
    for (int s = 0; s < 8; ++s) A[s] = -__expf(A_log[d * D_STATE + j * 8 + s]);
    const float Dd = Dp[d];

    float h[8] = {};
    for (int q = 0; q < NCHUNK - 1; ++q) {
        if (q < c) {
            const float2* cp = cb + ((size_t)(b * NCHUNK + q) * D_INNER + d) * D_STATE + j * 8;
#pragma unroll
            for (int s = 0; s < 8; ++s) {
                float2 v = cp[s];
                h[s] = fmaf(__expf(v.x), h[s], v.y);
            }
        }
    }

    const int r0 = b * LL + c * LC;
    const float* pd  = delta + (size_t)r0 * D_INNER + d;
    const ushort* px = xsb   + (size_t)r0 * D_INNER + d;
    const float* pB  = dbc   + (size_t)r0 * 64 + 32 + j * 8;
    const float* pC  = dbc   + (size_t)r0 * 64 + 48 + j * 8;
    const ushort* pr = xrb   + (size_t)r0 * 2 * D_INNER + D_INNER + d;
    ushort*      py  = yb    + (size_t)r0 * D_INNER + d;

    float dt = *pd, x = bf2f(*px), res = bf2f(*pr);
    float4 B0 = *(const float4*)pB, B1 = *(const float4*)(pB + 4);
    float4 C0 = *(const float4*)pC, C1 = *(const float4*)(pC + 4);

    for (int l = 0; l < LC; ++l) {
        pd += D_INNER; px += D_INNER; pB += 64; pC += 64; pr += 2 * D_INNER;
        const float dt_n = *pd, x_n = bf2f(*px), res_n = bf2f(*pr);
        const float4 B0_n = *(const float4*)pB, B1_n = *(const float4*)(pB + 4);
        const float4 C0_n = *(const float4*)pC, C1_n = *(const float4*)(pC + 4);

        const float dx = dt * x;
        float Bs[8] = {B0.x, B0.y, B0.z, B0.w, B1.x, B1.y, B1.z, B1.w};
        float Cs[8] = {C0.x, C0.y, C0.z, C0.w, C1.x, C1.y, C1.z, C1.w};
        float p = 0.f;
#pragma unroll
        for (int s = 0; s < 8; ++s) {
            h[s] = fmaf(__expf(dt * A[s]), h[s], dx * Bs[s]);
            p = fmaf(h[s], Cs[s], p);
        }
        p += __shfl_xor(p, 1);
        if (j == 0) {
            const float g = res / (1.f + __expf(-res));
            py[(size_t)l * D_INNER] = f2bf((p + x * Dd) * g);
        }
        dt = dt_n; x = x_n; res = res_n;
        B0 = B0_n; B1 = B1_n; C0 = C0_n; C1 = C1_n;
    }
}

// ---------------- final stats ----------------
__global__ __launch_bounds__(512) void stats_k(
    const float* __restrict__ m, float* __restrict__ out)
{
    const int b = blockIdx.x;
    const int dm = threadIdx.x;
    const float* p = m + (size_t)b * LL * D_MODEL + dm;
    float s = 0.f;
    for (int l = 0; l < LL; ++l) s += p[(size_t)l * D_MODEL];
    const float mean = s * (1.f / LL);
    float ss = 0.f;
    for (int l = 0; l < LL; ++l) {
        float v = p[(size_t)l * D_MODEL] - mean;
        ss += v * v;
    }
    out[b * (2 * D_MODEL) + dm] = mean;
    out[b * (2 * D_MODEL) + D_MODEL + dm] = sqrtf(ss * (1.f / (LL - 1)));
}

// ---------------- host ----------------
extern "C" void kernel_launch(void* const* d_in, const int* in_sizes, int n_in,
                              void* d_out, int out_size, void* d_ws, size_t ws_size,
                              hipStream_t stream) {
    const float* x            = (const float*)d_in[0];
    const float* proj_w       = (const float*)d_in[1];
    const float* proj_b       = (const float*)d_in[2];
    const float* norm_w       = (const float*)d_in[3];
    const float* in_w         = (const float*)d_in[4];
    const float* conv_w       = (const float*)d_in[5];
    const float* conv_b       = (const float*)d_in[6];
    const float* xproj_w      = (const float*)d_in[7];
    const float* dt_w         = (const float*)d_in[8];
    const float* dt_b         = (const float*)d_in[9];
    const float* A_log        = (const float*)d_in[10];
    const float* Dp           = (const float*)d_in[11];
    const float* out_w        = (const float*)d_in[12];
    const float* final_norm_w = (const float*)d_in[13];

    // fp32 region
    float* ws    = (float*)d_ws;
    float* h     = ws;                                  // 4096*512
    float* dbc   = h    + (size_t)M_ROWS * D_MODEL;     // 4096*64
    float* dlt   = dbc  + (size_t)M_ROWS * 64;          // 4096*1024 (+ final-norm buf)
    float* dpart = dlt  + (size_t)M_ROWS * D_INNER;     // 4*4096*64
    // bf16 region
    ushort* xyb   = (ushort*)(dpart + (size_t)4 * M_ROWS * 64); // 4096*1280 (x, then y)
    ushort* xnb   = xyb   + (size_t)M_ROWS * D_IN;      // 4096*512
    ushort* xrb   = xnb   + (size_t)M_ROWS * D_MODEL;   // 4096*2048
    ushort* xsb   = xrb   + (size_t)M_ROWS * 2 * D_INNER; // 4096*1024
    ushort* pwb   = xsb   + (size_t)M_ROWS * D_INNER;   // 512*1280
    ushort* iwb4  = pwb   + (size_t)D_MODEL * D_IN;     // 4*2048*512
    ushort* owb4  = iwb4  + (size_t)N_LAYER * 2 * D_INNER * D_MODEL; // 4*512*1024
    ushort* xpwb4 = owb4  + (size_t)N_LAYER * D_MODEL * D_INNER;     // 4*64*1024
    ushort* dtwb4 = xpwb4 + (size_t)N_LAYER * 64 * D_INNER;          // 4*1024*32
    ushort* dltb  = dtwb4 + (size_t)N_LAYER * D_INNER * DT_RANK;     // 4096*32
    float2* cbuf  = (float2*)(dltb + (size_t)M_ROWS * DT_RANK);

    // ---- one-time casts (all layers hoisted) ----
    cast_bf16_k<<<(M_ROWS * D_IN / 4 + 255) / 256, 256, 0, stream>>>(x, xyb, M_ROWS * D_IN / 4);
    cast_bf16_k<<<(D_MODEL * D_IN / 4 + 255) / 256, 256, 0, stream>>>(proj_w, pwb, D_MODEL * D_IN / 4);
    cast_bf16_k<<<(N_LAYER * 2 * D_INNER * D_MODEL / 4 + 255) / 256, 256, 0, stream>>>(
        in_w, iwb4, N_LAYER * 2 * D_INNER * D_MODEL / 4);
    cast_bf16_k<<<(N_LAYER * D_MODEL * D_INNER / 4 + 255) / 256, 256, 0, stream>>>(
        out_w, owb4, N_LAYER * D_MODEL * D_INNER / 4);
    cast_bf16_k<<<(N_LAYER * 64 * D_INNER / 4 + 255) / 256, 256, 0, stream>>>(
        xproj_w, xpwb4, N_LAYER * 64 * D_INNER / 4);
    cast_bf16_k<<<(N_LAYER * D_INNER * DT_RANK / 4 + 255) / 256, 256, 0, stream>>>(
        dt_w, dtwb4, N_LAYER * D_INNER * DT_RANK / 4);

    // h = x @ proj_w^T + proj_b   (BM=64: 512 blocks)
    gemm_bf16<64, 64, true, false, 0, false><<<dim3(D_MODEL / 64, M_ROWS / 64), 256, 0, stream>>>(
        xyb, pwb, proj_b, h, M_ROWS, D_MODEL, D_IN, D_IN, D_IN);

    for (int i = 0; i < N_LAYER; ++i) {
        const ushort* iwb  = iwb4  + (size_t)i * 2 * D_INNER * D_MODEL;
        const ushort* owb  = owb4  + (size_t)i * D_MODEL * D_INNER;
        const ushort* xpwb = xpwb4 + (size_t)i * 64 * D_INNER;
        const ushort* dtwb = dtwb4 + (size_t)i * D_INNER * DT_RANK;

        rmsnorm_k<true><<<M_ROWS, 256, 0, stream>>>(h, norm_w + (size_t)i * D_MODEL, nullptr, xnb);

        // xr(bf16) = xn @ in_w^T   (BM=128,BN=64: 1024 blocks)
        gemm_bf16<128, 64, false, false, 0, true><<<dim3(2 * D_INNER / 64, M_ROWS / 128), 256, 0, stream>>>(
            xnb, iwb, nullptr, xrb, M_ROWS, 2 * D_INNER, D_MODEL, D_MODEL, D_MODEL);

        conv_silu_k<<<M_ROWS * D_INNER / 256, 256, 0, stream>>>(
            xrb, conv_w + (size_t)i * D_INNER * D_CONV, conv_b + (size_t)i * D_INNER, xsb);

        // dbc partials = xs @ xproj_w^T, split-K=4 (256 blocks)
        gemm_bf16<128, 32, false, false, 0, false><<<dim3(2, M_ROWS / 128, 4), 256, 0, stream>>>(
            xsb, xpwb, nullptr, dpart, M_ROWS, 64, D_INNER / 4, D_INNER, D_INNER);
        reduce_dbc_k<<<M_ROWS * 64 / 256, 256, 0, stream>>>(dpart, dbc, dltb);

        // dlt = softplus(delta @ dt_w^T + dt_b)   (BM=64: 1024 blocks, K=32)
        gemm_bf16<64, 64, true, false, 1, false><<<dim3(D_INNER / 64, M_ROWS / 64), 256, 0, stream>>>(
            dltb, dtwb, dt_b + (size_t)i * D_INNER, dlt, M_ROWS, D_INNER, DT_RANK, DT_RANK, DT_RANK);

        scan1_k<<<BB * NCHUNK * (D_INNER / 128), 256, 0, stream>>>(
            dlt, xsb, dbc, A_log + (size_t)i * D_INNER * D_STATE, cbuf);
        scan2_k<<<BB * NCHUNK * (D_INNER / 128), 256, 0, stream>>>(
            dlt, xsb, dbc, xrb, A_log + (size_t)i * D_INNER * D_STATE,
            Dp + (size_t)i * D_INNER, cbuf, xyb);

        // h += y @ out_w^T   (BM=64: 512 blocks)
        gemm_bf16<64, 64, false, true, 0, false><<<dim3(D_MODEL / 64, M_ROWS / 64), 256, 0, stream>>>(
            xyb, owb, nullptr, h, M_ROWS, D_MODEL, D_INNER, D_INNER, D_INNER);
    }

    rmsnorm_k<false><<<M_ROWS, 256, 0, stream>>>(h, final_norm_w, dlt, nullptr);
    stats_k<<<BB, D_MODEL, 0, stream>>>(dlt, (float*)d_out);
}

// Round 9
// 803.122 us; speedup vs baseline: 5.5958x; 1.0522x over previous
//
#include <hip/hip_runtime.h>
#include <math.h>

// ---------------- dims (fixed by the problem) ----------------
#define D_IN     1280
#define D_MODEL  512
#define N_LAYER  4
#define D_STATE  16
#define D_CONV   4
#define D_INNER  1024
#define DT_RANK  32
#define BB       8
#define LL       512
#define M_ROWS   (BB*LL)          // 4096
#define NCHUNK   16
#define LC       (LL/NCHUNK)      // 32

typedef short bf16x8 __attribute__((ext_vector_type(8)));
typedef float f32x4  __attribute__((ext_vector_type(4)));

__device__ __forceinline__ ushort f2bf(float f) {
    unsigned u = __float_as_uint(f);
    u = (u + 0x7FFF + ((u >> 16) & 1)) >> 16;   // RNE
    return (ushort)u;
}
__device__ __forceinline__ float bf2f(ushort u) {
    return __uint_as_float((unsigned)u << 16);
}

// ---------------- fp32 -> bf16 cast (n multiple of 4) ----------------
__global__ __launch_bounds__(256) void cast_bf16_k(
    const float* __restrict__ in, ushort* __restrict__ out, int n4)
{
    int i = blockIdx.x * 256 + threadIdx.x;
    if (i < n4) {
        float4 v = *(const float4*)(in + (size_t)i * 4);
        *(ushort4*)(out + (size_t)i * 4) =
            make_ushort4(f2bf(v.x), f2bf(v.y), f2bf(v.z), f2bf(v.w));
    }
}

// ---- split-K reduce for dbc: sum 4 partials; also emit delta cols as bf16 ----
__global__ __launch_bounds__(256) void reduce_dbc_k(
    const float* __restrict__ part, float* __restrict__ dbc,
    ushort* __restrict__ dltb)
{
    const int i = blockIdx.x * 256 + threadIdx.x;   // over 4096*64
    const int c = i & 63;
    float s = part[i] + part[i + M_ROWS * 64] + part[i + 2 * M_ROWS * 64]
            + part[i + 3 * M_ROWS * 64];
    dbc[i] = s;
    if (c < 32) dltb[(i >> 6) * 32 + c] = f2bf(s);
}

// ---------------- bf16 MFMA GEMM: C[M,N] = A[M,K] @ W[N,K]^T ------------------
// BM=128: 4 waves 2x2 (wave tile 64 x BN/2). BM=64: 4 waves 1x4 (64 x BN/4).
// Split-K via gridDim.z. ACT: 0=none, 1=softplus.
// OUTBF: bf16 output via LDS-staged coalesced epilogue (no 32B partial-line RMW).
template<int BM, int BN, bool BIAS, bool ACCUM, int ACT, bool OUTBF>
__global__ __launch_bounds__(256) void gemm_bf16(
    const ushort* __restrict__ A, const ushort* __restrict__ W,
    const float* __restrict__ bias, void* __restrict__ Cv,
    int M, int N, int K, int lda, int ldw)
{
    constexpr int BK = 32;
    constexpr int LDA = BK + 8;                 // 40 ushorts = 80 B rows
    constexpr int WC = (BM == 128) ? 2 : 4;     // wave cols
    constexpr int HN = BN / WC;                 // wave N-tile
    constexpr int FN = HN / 16;                 // N frags per wave
    constexpr int AL = BM / 64;                 // A-tile uint4 loads/thread
    constexpr int BL = (BN * 4 + 255) / 256;    // B-tile uint4 loads/thread
    constexpr int SM_G = (BM + BN) * LDA;
    constexpr int SM_C = OUTBF ? BM * (BN + 8) : 0;
    constexpr int SM   = (SM_G > SM_C) ? SM_G : SM_C;
    __shared__ ushort smem[SM];
    ushort* lA = smem;
    ushort* lB = smem + BM * LDA;
    const int tid  = threadIdx.x;
    const int lane = tid & 63;
    const int wid  = tid >> 6;
    const int wr = (BM == 128) ? (wid >> 1) : 0;
    const int wc = (BM == 128) ? (wid & 1) : wid;
    const int bm = blockIdx.y * BM, bn = blockIdx.x * BN;
    const int koff = blockIdx.z * K;
    const size_t cz = (size_t)blockIdx.z * M * N;
    const int l15 = lane & 15, lk = lane >> 4;

    f32x4 acc[4][FN];
#pragma unroll
    for (int i = 0; i < 4; ++i)
#pragma unroll
        for (int j = 0; j < FN; ++j) acc[i][j] = (f32x4)0.f;

    for (int kk = 0; kk < K; kk += BK) {
        uint4 va[AL], vb[BL];
#pragma unroll
        for (int i = 0; i < AL; ++i) {
            int c = i * 256 + tid, row = c >> 2, k0 = (c & 3) * 8;
            va[i] = *(const uint4*)(A + (size_t)(bm + row) * lda + koff + kk + k0);
        }
#pragma unroll
        for (int i = 0; i < BL; ++i) {
            int c = i * 256 + tid;
            if ((BN * 4 % 256 == 0) || c < BN * 4) {
                int row = c >> 2, k0 = (c & 3) * 8;
                vb[i] = *(const uint4*)(W + (size_t)(bn + row) * ldw + koff + kk + k0);
            }
        }
        __syncthreads();
#pragma unroll
        for (int i = 0; i < AL; ++i) {
            int c = i * 256 + tid, row = c >> 2, k0 = (c & 3) * 8;
            *(uint4*)&lA[row * LDA + k0] = va[i];
        }
#pragma unroll
        for (int i = 0; i < BL; ++i) {
            int c = i * 256 + tid;
            if ((BN * 4 % 256 == 0) || c < BN * 4) {
                int row = c >> 2, k0 = (c & 3) * 8;
                *(uint4*)&lB[row * LDA + k0] = vb[i];
            }
        }
        __syncthreads();

        bf16x8 af[4], bw[FN];
#pragma unroll
        for (int fm = 0; fm < 4; ++fm)
            af[fm] = *(const bf16x8*)&lA[(wr * 64 + fm * 16 + l15) * LDA + lk * 8];
#pragma unroll
        for (int fn = 0; fn < FN; ++fn)
            bw[fn] = *(const bf16x8*)&lB[(wc * HN + fn * 16 + l15) * LDA + lk * 8];
#pragma unroll
        for (int fm = 0; fm < 4; ++fm)
#pragma unroll
            for (int fn = 0; fn < FN; ++fn)
                acc[fm][fn] = __builtin_amdgcn_mfma_f32_16x16x32_bf16(
                    af[fm], bw[fn], acc[fm][fn], 0, 0, 0);
    }

    if (OUTBF) {
        __syncthreads();                      // done with lA/lB
        ushort* cst = smem;                   // [BM][BN+8]
#pragma unroll
        for (int fm = 0; fm < 4; ++fm) {
#pragma unroll
            for (int fn = 0; fn < FN; ++fn) {
                int col = wc * HN + fn * 16 + l15;
                float bv = BIAS ? bias[bn + col] : 0.f;
#pragma unroll
                for (int j = 0; j < 4; ++j) {
                    int row = wr * 64 + fm * 16 + lk * 4 + j;
                    float r = acc[fm][fn][j] + bv;
                    if (ACT == 1) r = (r > 20.f) ? r : log1pf(expf(r));
                    cst[row * (BN + 8) + col] = f2bf(r);
                }
            }
        }
        __syncthreads();
        ushort* Cb = (ushort*)Cv + cz;
        constexpr int NV = BM * BN / 8;       // uint4 count
#pragma unroll
        for (int k = 0; k < NV / 256; ++k) {
            int i = k * 256 + tid;
            int row = i / (BN / 8), c8 = i % (BN / 8);
            uint4 v = *(uint4*)&cst[row * (BN + 8) + c8 * 8];
            *(uint4*)&Cb[(size_t)(bm + row) * N + bn + c8 * 8] = v;
        }
    } else {
        float* Cf = (float*)Cv + cz;
#pragma unroll
        for (int fm = 0; fm < 4; ++fm) {
#pragma unroll
            for (int fn = 0; fn < FN; ++fn) {
                int col = bn + wc * HN + fn * 16 + l15;
                float bv = BIAS ? bias[col] : 0.f;
#pragma unroll
                for (int j = 0; j < 4; ++j) {
                    int row = bm + wr * 64 + fm * 16 + lk * 4 + j;
                    float r = acc[fm][fn][j] + bv;
                    if (ACT == 1) r = (r > 20.f) ? r : log1pf(expf(r));
                    float* cp = Cf + (size_t)row * N + col;
                    if (ACCUM) r += *cp;
                    *cp = r;
                }
            }
        }
    }
}

// ---------------- RMSNorm over last dim D=512 ---------------------------------
template<bool BF16OUT>
__global__ __launch_bounds__(256) void rmsnorm_k(
    const float* __restrict__ X, const float* __restrict__ w,
    float* __restrict__ Yf, ushort* __restrict__ Yb)
{
    const int r = blockIdx.x;
    const float* x = X + (size_t)r * D_MODEL;
    float2 v = *(const float2*)(x + threadIdx.x * 2);
    float ss = v.x * v.x + v.y * v.y;
#pragma unroll
    for (int off = 32; off > 0; off >>= 1) ss += __shfl_down(ss, off);
    __shared__ float wsum[4];
    if ((threadIdx.x & 63) == 0) wsum[threadIdx.x >> 6] = ss;
    __syncthreads();
    float tot = wsum[0] + wsum[1] + wsum[2] + wsum[3];
    float rs = rsqrtf(tot * (1.f / D_MODEL) + 1e-5f);
    float2 wv = *(const float2*)(w + threadIdx.x * 2);
    float a = v.x * rs * wv.x, b = v.y * rs * wv.y;
    if (BF16OUT)
        *(ushort2*)(Yb + (size_t)r * D_MODEL + threadIdx.x * 2) =
            make_ushort2(f2bf(a), f2bf(b));
    else
        *(float2*)(Yf + (size_t)r * D_MODEL + threadIdx.x * 2) = make_float2(a, b);
}

// ------- depthwise causal conv1d (k=4, bf16 in) + bias + silu -> bf16 xs ------
__global__ __launch_bounds__(256) void conv_silu_k(
    const ushort* __restrict__ xrb, const float* __restrict__ cw,
    const float* __restrict__ cb, ushort* __restrict__ xsb)
{
    const int idx = blockIdx.x * 256 + threadIdx.x;
    const int d = idx & (D_INNER - 1);
    const int r = idx >> 10;
    const int l = r & (LL - 1);
    const ushort* base = xrb + (size_t)r * (2 * D_INNER) + d;
    float4 w = *(const float4*)(cw + d * 4);
    float acc = cb[d];
    if (l >= 3) acc += bf2f(base[-3 * 2 * D_INNER]) * w.x;
    if (l >= 2) acc += bf2f(base[-2 * 2 * D_INNER]) * w.y;
    if (l >= 1) acc += bf2f(base[-1 * 2 * D_INNER]) * w.z;
    acc += bf2f(base[0]) * w.w;
    xsb[idx] = f2bf(acc / (1.f + __expf(-acc)));
}

// ---------------- selective scan, chunk-parallel, 8 states/thread -------------
// Lane layout: j = tid&1 -> states j*8..j*8+7; d = dblk*128 + (tid>>1).
__global__ __launch_bounds__(256) void scan1_k(
    const ushort* __restrict__ dltS, const ushort* __restrict__ xsb,
    const float* __restrict__ dbc, const float* __restrict__ A_log,
    float2* __restrict__ cb)
{
    const int b    = blockIdx.x >> 7;            // 16*8 blocks per batch
    const int c    = (blockIdx.x >> 3) & 15;
    const int dblk = blockIdx.x & 7;
    const int d = dblk * 128 + (threadIdx.x >> 1);
    const int j = threadIdx.x & 1;

    float A[8];
#pragma unroll
    for (int s = 0; s < 8; ++s) A[s] = -__expf(A_log[d * D_STATE + j * 8 + s]);

    const int r0 = b * LL + c * LC;
    const ushort* pd = dltS + (size_t)r0 * D_INNER + d;
    const ushort* px = xsb  + (size_t)r0 * D_INNER + d;
    const float* pB  = dbc  + (size_t)r0 * 64 + 32 + j * 8;

    float h[8] = {}, S[8] = {};
    float dt = bf2f(*pd), x = bf2f(*px);
    float4 B0 = *(const float4*)pB, B1 = *(const float4*)(pB + 4);

    for (int l = 0; l < LC; ++l) {
        pd += D_INNER; px += D_INNER; pB += 64;
        const float dt_n = bf2f(*pd), x_n = bf2f(*px);
        const float4 B0_n = *(const float4*)pB, B1_n = *(const float4*)(pB + 4);

        const float dx = dt * x;
        float Bs[8] = {B0.x, B0.y, B0.z, B0.w, B1.x, B1.y, B1.z, B1.w};
#pragma unroll
        for (int s = 0; s < 8; ++s) {
            const float sA = dt * A[s];
            S[s] += sA;
            h[s] = fmaf(__expf(sA), h[s], dx * Bs[s]);
        }
        dt = dt_n; x = x_n; B0 = B0_n; B1 = B1_n;
    }
    float2* cp = cb + ((size_t)(b * NCHUNK + c) * D_INNER + d) * D_STATE + j * 8;
#pragma unroll
    for (int s = 0; s < 8; ++s) cp[s] = make_float2(S[s], h[s]);
}

__global__ __launch_bounds__(256) void scan2_k(
    const ushort* __restrict__ dltS, const ushort* __restrict__ xsb,
    const float* __restrict__ dbc, const ushort* __restrict__ xrb,
    const float* __restrict__ A_log, const float* __restrict__ Dp,
    const float2* __restrict__ cb, ushort* __restrict__ yb)
{
    const int b    = blockIdx.x >> 7;
    const int c    = (blockIdx.x >> 3) & 15;
    const int dblk = blockIdx.x & 7;
    const int d = dblk * 128 + (threadIdx.x >> 1);
    const int j = threadIdx.x & 1;

    float A[8];
#pragma unroll
    for (int s = 0; s < 8; ++s) A[s] = -__expf(A_log[d * D_STATE + j * 8 + s]);
    const float Dd = Dp[d];

    float h[8] = {};
    for (int q = 0; q < NCHUNK - 1; ++q) {
        if (q < c) {
            const float2* cp = cb + ((size_t)(b * NCHUNK + q) * D_INNER + d) * D_STATE + j * 8;
#pragma unroll
            for (int s = 0; s < 8; ++s) {
                float2 v = cp[s];
                h[s] = fmaf(__expf(v.x), h[s], v.y);
            }
        }
    }

    const int r0 = b * LL + c * LC;
    const ushort* pd = dltS + (size_t)r0 * D_INNER + d;
    const ushort* px = xsb  + (size_t)r0 * D_INNER + d;
    const float* pB  = dbc  + (size_t)r0 * 64 + 32 + j * 8;
    const float* pC  = dbc  + (size_t)r0 * 64 + 48 + j * 8;
    const ushort* pr = xrb  + (size_t)r0 * 2 * D_INNER + D_INNER + d;
    ushort*      py  = yb   + (size_t)r0 * D_INNER + d;

    float dt = bf2f(*pd), x = bf2f(*px), res = bf2f(*pr);
    float4 B0 = *(const float4*)pB, B1 = *(const float4*)(pB + 4);
    float4 C0 = *(const float4*)pC, C1 = *(const float4*)(pC + 4);

    for (int l = 0; l < LC; ++l) {
        pd += D_INNER; px += D_INNER; pB += 64; pC += 64; pr += 2 * D_INNER;
        const float dt_n = bf2f(*pd), x_n = bf2f(*px), res_n = bf2f(*pr);
        const float4 B0_n = *(const float4*)pB, B1_n = *(const float4*)(pB + 4);
        const float4 C0_n = *(const float4*)pC, C1_n = *(const float4*)(pC + 4);

        const float dx = dt * x;
        float Bs[8] = {B0.x, B0.y, B0.z, B0.w, B1.x, B1.y, B1.z, B1.w};
        float Cs[8] = {C0.x, C0.y, C0.z, C0.w, C1.x, C1.y, C1.z, C1.w};
        float p = 0.f;
#pragma unroll
        for (int s = 0; s < 8; ++s) {
            h[s] = fmaf(__expf(dt * A[s]), h[s], dx * Bs[s]);
            p = fmaf(h[s], Cs[s], p);
        }
        p += __shfl_xor(p, 1);
        if (j == 0) {
            const float g = res / (1.f + __expf(-res));
            py[(size_t)l * D_INNER] = f2bf((p + x * Dd) * g);
        }
        dt = dt_n; x = x_n; res = res_n;
        B0 = B0_n; B1 = B1_n; C0 = C0_n; C1 = C1_n;
    }
}

// ---------------- final stats ----------------
__global__ __launch_bounds__(512) void stats_k(
    const float* __restrict__ m, float* __restrict__ out)
{
    const int b = blockIdx.x;
    const int dm = threadIdx.x;
    const float* p = m + (size_t)b * LL * D_MODEL + dm;
    float s = 0.f;
    for (int l = 0; l < LL; ++l) s += p[(size_t)l * D_MODEL];
    const float mean = s * (1.f / LL);
    float ss = 0.f;
    for (int l = 0; l < LL; ++l) {
        float v = p[(size_t)l * D_MODEL] - mean;
        ss += v * v;
    }
    out[b * (2 * D_MODEL) + dm] = mean;
    out[b * (2 * D_MODEL) + D_MODEL + dm] = sqrtf(ss * (1.f / (LL - 1)));
}

// ---------------- host ----------------
extern "C" void kernel_launch(void* const* d_in, const int* in_sizes, int n_in,
                              void* d_out, int out_size, void* d_ws, size_t ws_size,
                              hipStream_t stream) {
    const float* x            = (const float*)d_in[0];
    const float* proj_w       = (const float*)d_in[1];
    const float* proj_b       = (const float*)d_in[2];
    const float* norm_w       = (const float*)d_in[3];
    const float* in_w         = (const float*)d_in[4];
    const float* conv_w       = (const float*)d_in[5];
    const float* conv_b       = (const float*)d_in[6];
    const float* xproj_w      = (const float*)d_in[7];
    const float* dt_w         = (const float*)d_in[8];
    const float* dt_b         = (const float*)d_in[9];
    const float* A_log        = (const float*)d_in[10];
    const float* Dp           = (const float*)d_in[11];
    const float* out_w        = (const float*)d_in[12];
    const float* final_norm_w = (const float*)d_in[13];

    // fp32 region
    float* ws    = (float*)d_ws;
    float* h     = ws;                                  // 4096*512
    float* dbc   = h    + (size_t)M_ROWS * D_MODEL;     // 4096*64
    float* dpart = dbc  + (size_t)M_ROWS * 64;          // 4*4096*64
    // bf16 region
    ushort* xyb   = (ushort*)(dpart + (size_t)4 * M_ROWS * 64); // 4096*1280 (x, then y)
    ushort* xnb   = xyb   + (size_t)M_ROWS * D_IN;      // 4096*512
    ushort* xrb   = xnb   + (size_t)M_ROWS * D_MODEL;   // 4096*2048 (also fp32 fnorm alias)
    ushort* xsb   = xrb   + (size_t)M_ROWS * 2 * D_INNER; // 4096*1024
    ushort* dltS  = xsb   + (size_t)M_ROWS * D_INNER;   // 4096*1024 (bf16 softplus dt)
    ushort* dltb  = dltS  + (size_t)M_ROWS * D_INNER;   // 4096*32 (delta pre-GEMM bf16)
    ushort* pwb   = dltb  + (size_t)M_ROWS * DT_RANK;   // 512*1280
    ushort* iwb4  = pwb   + (size_t)D_MODEL * D_IN;     // 4*2048*512
    ushort* owb4  = iwb4  + (size_t)N_LAYER * 2 * D_INNER * D_MODEL; // 4*512*1024
    ushort* xpwb4 = owb4  + (size_t)N_LAYER * D_MODEL * D_INNER;     // 4*64*1024
    ushort* dtwb4 = xpwb4 + (size_t)N_LAYER * 64 * D_INNER;          // 4*1024*32
    float2* cbuf  = (float2*)(dtwb4 + (size_t)N_LAYER * D_INNER * DT_RANK); // 16.8MB (LAST)
    float* fnorm  = (float*)xrb;                        // alias (xrb dead at final norm)

    // ---- one-time casts (all layers hoisted) ----
    cast_bf16_k<<<(M_ROWS * D_IN / 4 + 255) / 256, 256, 0, stream>>>(x, xyb, M_ROWS * D_IN / 4);
    cast_bf16_k<<<(D_MODEL * D_IN / 4 + 255) / 256, 256, 0, stream>>>(proj_w, pwb, D_MODEL * D_IN / 4);
    cast_bf16_k<<<(N_LAYER * 2 * D_INNER * D_MODEL / 4 + 255) / 256, 256, 0, stream>>>(
        in_w, iwb4, N_LAYER * 2 * D_INNER * D_MODEL / 4);
    cast_bf16_k<<<(N_LAYER * D_MODEL * D_INNER / 4 + 255) / 256, 256, 0, stream>>>(
        out_w, owb4, N_LAYER * D_MODEL * D_INNER / 4);
    cast_bf16_k<<<(N_LAYER * 64 * D_INNER / 4 + 255) / 256, 256, 0, stream>>>(
        xproj_w, xpwb4, N_LAYER * 64 * D_INNER / 4);
    cast_bf16_k<<<(N_LAYER * D_INNER * DT_RANK / 4 + 255) / 256, 256, 0, stream>>>(
        dt_w, dtwb4, N_LAYER * D_INNER * DT_RANK / 4);

    // h = x @ proj_w^T + proj_b
    gemm_bf16<64, 64, true, false, 0, false><<<dim3(D_MODEL / 64, M_ROWS / 64), 256, 0, stream>>>(
        xyb, pwb, proj_b, h, M_ROWS, D_MODEL, D_IN, D_IN, D_IN);

    for (int i = 0; i < N_LAYER; ++i) {
        const ushort* iwb  = iwb4  + (size_t)i * 2 * D_INNER * D_MODEL;
        const ushort* owb  = owb4  + (size_t)i * D_MODEL * D_INNER;
        const ushort* xpwb = xpwb4 + (size_t)i * 64 * D_INNER;
        const ushort* dtwb = dtwb4 + (size_t)i * D_INNER * DT_RANK;

        rmsnorm_k<true><<<M_ROWS, 256, 0, stream>>>(h, norm_w + (size_t)i * D_MODEL, nullptr, xnb);

        // xr(bf16) = xn @ in_w^T   (coalesced bf16 epilogue)
        gemm_bf16<128, 64, false, false, 0, true><<<dim3(2 * D_INNER / 64, M_ROWS / 128), 256, 0, stream>>>(
            xnb, iwb, nullptr, xrb, M_ROWS, 2 * D_INNER, D_MODEL, D_MODEL, D_MODEL);

        conv_silu_k<<<M_ROWS * D_INNER / 256, 256, 0, stream>>>(
            xrb, conv_w + (size_t)i * D_INNER * D_CONV, conv_b + (size_t)i * D_INNER, xsb);

        // dbc partials = xs @ xproj_w^T, split-K=4
        gemm_bf16<128, 32, false, false, 0, false><<<dim3(2, M_ROWS / 128, 4), 256, 0, stream>>>(
            xsb, xpwb, nullptr, dpart, M_ROWS, 64, D_INNER / 4, D_INNER, D_INNER);
        reduce_dbc_k<<<M_ROWS * 64 / 256, 256, 0, stream>>>(dpart, dbc, dltb);

        // dltS(bf16) = softplus(delta @ dt_w^T + dt_b)
        gemm_bf16<64, 64, true, false, 1, true><<<dim3(D_INNER / 64, M_ROWS / 64), 256, 0, stream>>>(
            dltb, dtwb, dt_b + (size_t)i * D_INNER, dltS, M_ROWS, D_INNER, DT_RANK, DT_RANK, DT_RANK);

        scan1_k<<<BB * NCHUNK * (D_INNER / 128), 256, 0, stream>>>(
            dltS, xsb, dbc, A_log + (size_t)i * D_INNER * D_STATE, cbuf);
        scan2_k<<<BB * NCHUNK * (D_INNER / 128), 256, 0, stream>>>(
            dltS, xsb, dbc, xrb, A_log + (size_t)i * D_INNER * D_STATE,
            Dp + (size_t)i * D_INNER, cbuf, xyb);

        // h += y @ out_w^T
        gemm_bf16<64, 64, false, true, 0, false><<<dim3(D_MODEL / 64, M_ROWS / 64), 256, 0, stream>>>(
            xyb, owb, nullptr, h, M_ROWS, D_MODEL, D_INNER, D_INNER, D_INNER);
    }

    rmsnorm_k<false><<<M_ROWS, 256, 0, stream>>>(h, final_norm_w, fnorm, nullptr);
    stats_k<<<BB, D_MODEL, 0, stream>>>(fnorm, (float*)d_out);
}

// Round 10
// 690.058 us; speedup vs baseline: 6.5126x; 1.1638x over previous
//
#include <hip/hip_runtime.h>
#include <math.h>

// ---------------- dims (fixed by the problem) ----------------
#define D_IN     1280
#define D_MODEL  512
#define N_LAYER  4
#define D_STATE  16
#define D_CONV   4
#define D_INNER  1024
#define DT_RANK  32
#define BB       8
#define LL       512
#define M_ROWS   (BB*LL)          // 4096
#define NCHUNK   16
#define LC       (LL/NCHUNK)      // 32

typedef short bf16x8 __attribute__((ext_vector_type(8)));
typedef float f32x4  __attribute__((ext_vector_type(4)));

__device__ __forceinline__ ushort f2bf(float f) {
    unsigned u = __float_as_uint(f);
    u = (u + 0x7FFF + ((u >> 16) & 1)) >> 16;   // RNE
    return (ushort)u;
}
__device__ __forceinline__ float bf2f(ushort u) {
    return __uint_as_float((unsigned)u << 16);
}

// ---------------- fp32 -> bf16 cast (n multiple of 4) ----------------
__global__ __launch_bounds__(256) void cast_bf16_k(
    const float* __restrict__ in, ushort* __restrict__ out, int n4)
{
    int i = blockIdx.x * 256 + threadIdx.x;
    if (i < n4) {
        float4 v = *(const float4*)(in + (size_t)i * 4);
        *(ushort4*)(out + (size_t)i * 4) =
            make_ushort4(f2bf(v.x), f2bf(v.y), f2bf(v.z), f2bf(v.w));
    }
}

// ---- split-K reduce for dbc: sum 4 partials; also emit delta cols as bf16 ----
__global__ __launch_bounds__(256) void reduce_dbc_k(
    const float* __restrict__ part, float* __restrict__ dbc,
    ushort* __restrict__ dltb)
{
    const int i = blockIdx.x * 256 + threadIdx.x;   // over 4096*64
    const int c = i & 63;
    float s = part[i] + part[i + M_ROWS * 64] + part[i + 2 * M_ROWS * 64]
            + part[i + 3 * M_ROWS * 64];
    dbc[i] = s;
    if (c < 32) dltb[(i >> 6) * 32 + c] = f2bf(s);
}

// ============ in_proj GEMM, m97-structure: 128x128 tile, BK=32, =============
// 4 waves 2x2 (wave tile 64x64, 16 MFMA/K-step), global_load_lds width-16
// staging into linear LDS, bf16 output via LDS-staged coalesced epilogue.
// Shapes fixed: A[4096,512] @ W[2048,512]^T -> C[4096,2048] bf16.
__global__ __launch_bounds__(256) void gemm_in_k(
    const ushort* __restrict__ A, const ushort* __restrict__ W,
    ushort* __restrict__ C)
{
    constexpr int BM = 128, BN = 128, BK = 32;
    constexpr int KDIM = D_MODEL, NDIM = 2 * D_INNER;
    __shared__ ushort smem[BM * (BN + 8)];        // 34816 B; staging uses first 16 KB
    ushort* lA = smem;                            // [128][32] linear
    ushort* lB = smem + BM * BK;                  // [128][32] linear
    const int tid = threadIdx.x, lane = tid & 63, wid = tid >> 6;
    const int wr = wid >> 1, wc = wid & 1;
    const int bm = blockIdx.y * BM, bn = blockIdx.x * BN;
    const int l15 = lane & 15, lk = lane >> 4;
    const int srow = lane >> 2, scol = (lane & 3) * 8;   // staging: 16 rows/chunk

    f32x4 acc[4][4];
#pragma unroll
    for (int i = 0; i < 4; ++i)
#pragma unroll
        for (int j = 0; j < 4; ++j) acc[i][j] = (f32x4)0.f;

    for (int kk = 0; kk < KDIM; kk += BK) {
        // stage A,B tiles: each wave DMAs 2 chunks (16 rows x 64 B) of each
#pragma unroll
        for (int i = 0; i < 2; ++i) {
            const int ch = wid * 2 + i;
            const ushort* ga = A + (size_t)(bm + ch * 16 + srow) * KDIM + kk + scol;
            __builtin_amdgcn_global_load_lds(
                (const __attribute__((address_space(1))) void*)ga,
                (__attribute__((address_space(3))) void*)(lA + ch * 512), 16, 0, 0);
            const ushort* gb = W + (size_t)(bn + ch * 16 + srow) * KDIM + kk + scol;
            __builtin_amdgcn_global_load_lds(
                (const __attribute__((address_space(1))) void*)gb,
                (__attribute__((address_space(3))) void*)(lB + ch * 512), 16, 0, 0);
        }
        __syncthreads();   // drains vmcnt; tiles ready

        bf16x8 af[4], bw[4];
#pragma unroll
        for (int fm = 0; fm < 4; ++fm)
            af[fm] = *(const bf16x8*)&lA[(wr * 64 + fm * 16 + l15) * BK + lk * 8];
#pragma unroll
        for (int fn = 0; fn < 4; ++fn)
            bw[fn] = *(const bf16x8*)&lB[(wc * 64 + fn * 16 + l15) * BK + lk * 8];
#pragma unroll
        for (int fm = 0; fm < 4; ++fm)
#pragma unroll
            for (int fn = 0; fn < 4; ++fn)
                acc[fm][fn] = __builtin_amdgcn_mfma_f32_16x16x32_bf16(
                    af[fm], bw[fn], acc[fm][fn], 0, 0, 0);
        __syncthreads();   // protect LDS before next stage
    }

    // epilogue: stage C tile in LDS, stream out coalesced
    ushort* cst = smem;                           // [128][136]
#pragma unroll
    for (int fm = 0; fm < 4; ++fm) {
#pragma unroll
        for (int fn = 0; fn < 4; ++fn) {
            const int col = wc * 64 + fn * 16 + l15;
#pragma unroll
            for (int j = 0; j < 4; ++j) {
                const int row = wr * 64 + fm * 16 + lk * 4 + j;
                cst[row * (BN + 8) + col] = f2bf(acc[fm][fn][j]);
            }
        }
    }
    __syncthreads();
#pragma unroll
    for (int k = 0; k < 8; ++k) {
        const int i = k * 256 + tid;              // 0..2047 uint4s
        const int row = i >> 4, c8 = i & 15;
        *(uint4*)&C[(size_t)(bm + row) * NDIM + bn + c8 * 8] =
            *(uint4*)&cst[row * (BN + 8) + c8 * 8];
    }
}

// ---------------- bf16 MFMA GEMM (general): C = A @ W^T -----------------------
// BM=128: 4 waves 2x2. BM=64: 4 waves 1x4. Split-K via gridDim.z.
// ACT: 0=none, 1=softplus. OUTBF: bf16 out via LDS-staged epilogue.
template<int BM, int BN, bool BIAS, bool ACCUM, int ACT, bool OUTBF>
__global__ __launch_bounds__(256) void gemm_bf16(
    const ushort* __restrict__ A, const ushort* __restrict__ W,
    const float* __restrict__ bias, void* __restrict__ Cv,
    int M, int N, int K, int lda, int ldw)
{
    constexpr int BK = 32;
    constexpr int LDA = BK + 8;
    constexpr int WC = (BM == 128) ? 2 : 4;
    constexpr int HN = BN / WC;
    constexpr int FN = HN / 16;
    constexpr int AL = BM / 64;
    constexpr int BL = (BN * 4 + 255) / 256;
    constexpr int SM_G = (BM + BN) * LDA;
    constexpr int SM_C = OUTBF ? BM * (BN + 8) : 0;
    constexpr int SM   = (SM_G > SM_C) ? SM_G : SM_C;
    __shared__ ushort smem[SM];
    ushort* lA = smem;
    ushort* lB = smem + BM * LDA;
    const int tid  = threadIdx.x;
    const int lane = tid & 63;
    const int wid  = tid >> 6;
    const int wr = (BM == 128) ? (wid >> 1) : 0;
    const int wc = (BM == 128) ? (wid & 1) : wid;
    const int bm = blockIdx.y * BM, bn = blockIdx.x * BN;
    const int koff = blockIdx.z * K;
    const size_t cz = (size_t)blockIdx.z * M * N;
    const int l15 = lane & 15, lk = lane >> 4;

    f32x4 acc[4][FN];
#pragma unroll
    for (int i = 0; i < 4; ++i)
#pragma unroll
        for (int j = 0; j < FN; ++j) acc[i][j] = (f32x4)0.f;

    for (int kk = 0; kk < K; kk += BK) {
        uint4 va[AL], vb[BL];
#pragma unroll
        for (int i = 0; i < AL; ++i) {
            int c = i * 256 + tid, row = c >> 2, k0 = (c & 3) * 8;
            va[i] = *(const uint4*)(A + (size_t)(bm + row) * lda + koff + kk + k0);
        }
#pragma unroll
        for (int i = 0; i < BL; ++i) {
            int c = i * 256 + tid;
            if ((BN * 4 % 256 == 0) || c < BN * 4) {
                int row = c >> 2, k0 = (c & 3) * 8;
                vb[i] = *(const uint4*)(W + (size_t)(bn + row) * ldw + koff + kk + k0);
            }
        }
        __syncthreads();
#pragma unroll
        for (int i = 0; i < AL; ++i) {
            int c = i * 256 + tid, row = c >> 2, k0 = (c & 3) * 8;
            *(uint4*)&lA[row * LDA + k0] = va[i];
        }
#pragma unroll
        for (int i = 0; i < BL; ++i) {
            int c = i * 256 + tid;
            if ((BN * 4 % 256 == 0) || c < BN * 4) {
                int row = c >> 2, k0 = (c & 3) * 8;
                *(uint4*)&lB[row * LDA + k0] = vb[i];
            }
        }
        __syncthreads();

        bf16x8 af[4], bw[FN];
#pragma unroll
        for (int fm = 0; fm < 4; ++fm)
            af[fm] = *(const bf16x8*)&lA[(wr * 64 + fm * 16 + l15) * LDA + lk * 8];
#pragma unroll
        for (int fn = 0; fn < FN; ++fn)
            bw[fn] = *(const bf16x8*)&lB[(wc * HN + fn * 16 + l15) * LDA + lk * 8];
#pragma unroll
        for (int fm = 0; fm < 4; ++fm)
#pragma unroll
            for (int fn = 0; fn < FN; ++fn)
                acc[fm][fn] = __builtin_amdgcn_mfma_f32_16x16x32_bf16(
                    af[fm], bw[fn], acc[fm][fn], 0, 0, 0);
    }

    if (OUTBF) {
        __syncthreads();
        ushort* cst = smem;
#pragma unroll
        for (int fm = 0; fm < 4; ++fm) {
#pragma unroll
            for (int fn = 0; fn < FN; ++fn) {
                int col = wc * HN + fn * 16 + l15;
                float bv = BIAS ? bias[bn + col] : 0.f;
#pragma unroll
                for (int j = 0; j < 4; ++j) {
                    int row = wr * 64 + fm * 16 + lk * 4 + j;
                    float r = acc[fm][fn][j] + bv;
                    if (ACT == 1) r = (r > 20.f) ? r : log1pf(expf(r));
                    cst[row * (BN + 8) + col] = f2bf(r);
                }
            }
        }
        __syncthreads();
        ushort* Cb = (ushort*)Cv + cz;
        constexpr int NV = BM * BN / 8;
#pragma unroll
        for (int k = 0; k < NV / 256; ++k) {
            int i = k * 256 + tid;
            int row = i / (BN / 8), c8 = i % (BN / 8);
            uint4 v = *(uint4*)&cst[row * (BN + 8) + c8 * 8];
            *(uint4*)&Cb[(size_t)(bm + row) * N + bn + c8 * 8] = v;
        }
    } else {
        float* Cf = (float*)Cv + cz;
#pragma unroll
        for (int fm = 0; fm < 4; ++fm) {
#pragma unroll
            for (int fn = 0; fn < FN; ++fn) {
                int col = bn + wc * HN + fn * 16 + l15;
                float bv = BIAS ? bias[col] : 0.f;
#pragma unroll
                for (int j = 0; j < 4; ++j) {
                    int row = bm + wr * 64 + fm * 16 + lk * 4 + j;
                    float r = acc[fm][fn][j] + bv;
                    if (ACT == 1) r = (r > 20.f) ? r : log1pf(expf(r));
                    float* cp = Cf + (size_t)row * N + col;
                    if (ACCUM) r += *cp;
                    *cp = r;
                }
            }
        }
    }
}

// ---------------- RMSNorm over last dim D=512 ---------------------------------
template<bool BF16OUT>
__global__ __launch_bounds__(256) void rmsnorm_k(
    const float* __restrict__ X, const float* __restrict__ w,
    float* __restrict__ Yf, ushort* __restrict__ Yb)
{
    const int r = blockIdx.x;
    const float* x = X + (size_t)r * D_MODEL;
    float2 v = *(const float2*)(x + threadIdx.x * 2);
    float ss = v.x * v.x + v.y * v.y;
#pragma unroll
    for (int off = 32; off > 0; off >>= 1) ss += __shfl_down(ss, off);
    __shared__ float wsum[4];
    if ((threadIdx.x & 63) == 0) wsum[threadIdx.x >> 6] = ss;
    __syncthreads();
    float tot = wsum[0] + wsum[1] + wsum[2] + wsum[3];
    float rs = rsqrtf(tot * (1.f / D_MODEL) + 1e-5f);
    float2 wv = *(const float2*)(w + threadIdx.x * 2);
    float a = v.x * rs * wv.x, b = v.y * rs * wv.y;
    if (BF16OUT)
        *(ushort2*)(Yb + (size_t)r * D_MODEL + threadIdx.x * 2) =
            make_ushort2(f2bf(a), f2bf(b));
    else
        *(float2*)(Yf + (size_t)r * D_MODEL + threadIdx.x * 2) = make_float2(a, b);
}

// ------- depthwise causal conv1d (k=4, bf16 in) + bias + silu -> bf16 xs ------
__global__ __launch_bounds__(256) void conv_silu_k(
    const ushort* __restrict__ xrb, const float* __restrict__ cw,
    const float* __restrict__ cb, ushort* __restrict__ xsb)
{
    const int idx = blockIdx.x * 256 + threadIdx.x;
    const int d = idx & (D_INNER - 1);
    const int r = idx >> 10;
    const int l = r & (LL - 1);
    const ushort* base = xrb + (size_t)r * (2 * D_INNER) + d;
    float4 w = *(const float4*)(cw + d * 4);
    float acc = cb[d];
    if (l >= 3) acc += bf2f(base[-3 * 2 * D_INNER]) * w.x;
    if (l >= 2) acc += bf2f(base[-2 * 2 * D_INNER]) * w.y;
    if (l >= 1) acc += bf2f(base[-1 * 2 * D_INNER]) * w.z;
    acc += bf2f(base[0]) * w.w;
    xsb[idx] = f2bf(acc / (1.f + __expf(-acc)));
}

// ---------------- selective scan, chunk-parallel, 8 states/thread -------------
__global__ __launch_bounds__(256) void scan1_k(
    const ushort* __restrict__ dltS, const ushort* __restrict__ xsb,
    const float* __restrict__ dbc, const float* __restrict__ A_log,
    float2* __restrict__ cb)
{
    const int b    = blockIdx.x >> 7;
    const int c    = (blockIdx.x >> 3) & 15;
    const int dblk = blockIdx.x & 7;
    const int d = dblk * 128 + (threadIdx.x >> 1);
    const int j = threadIdx.x & 1;

    float A[8];
#pragma unroll
    for (int s = 0; s < 8; ++s) A[s] = -__expf(A_log[d * D_STATE + j * 8 + s]);

    const int r0 = b * LL + c * LC;
    const ushort* pd = dltS + (size_t)r0 * D_INNER + d;
    const ushort* px = xsb  + (size_t)r0 * D_INNER + d;
    const float* pB  = dbc  + (size_t)r0 * 64 + 32 + j * 8;

    float h[8] = {}, S[8] = {};
    float dt = bf2f(*pd), x = bf2f(*px);
    float4 B0 = *(const float4*)pB, B1 = *(const float4*)(pB + 4);

    for (int l = 0; l < LC; ++l) {
        pd += D_INNER; px += D_INNER; pB += 64;
        const float dt_n = bf2f(*pd), x_n = bf2f(*px);
        const float4 B0_n = *(const float4*)pB, B1_n = *(const float4*)(pB + 4);

        const float dx = dt * x;
        float Bs[8] = {B0.x, B0.y, B0.z, B0.w, B1.x, B1.y, B1.z, B1.w};
#pragma unroll
        for (int s = 0; s < 8; ++s) {
            const float sA = dt * A[s];
            S[s] += sA;
            h[s] = fmaf(__expf(sA), h[s], dx * Bs[s]);
        }
        dt = dt_n; x = x_n; B0 = B0_n; B1 = B1_n;
    }
    float2* cp = cb + ((size_t)(b * NCHUNK + c) * D_INNER + d) * D_STATE + j * 8;
#pragma unroll
    for (int s = 0; s < 8; ++s) cp[s] = make_float2(S[s], h[s]);
}

__global__ __launch_bounds__(256) void scan2_k(
    const ushort* __restrict__ dltS, const ushort* __restrict__ xsb,
    const float* __restrict__ dbc, const ushort* __restrict__ xrb,
    const float* __restrict__ A_log, const float* __restrict__ Dp,
    const float2* __restrict__ cb, ushort* __restrict__ yb)
{
    const int b    = blockIdx.x >> 7;
    const int c    = (blockIdx.x >> 3) & 15;
    const int dblk = blockIdx.x & 7;
    const int d = dblk * 128 + (threadIdx.x >> 1);
    const int j = threadIdx.x & 1;

    float A[8];
#pragma unroll
    for (int s = 0; s < 8; ++s) A[s] = -__expf(A_log[d * D_STATE + j * 8 + s]);
    const float Dd = Dp[d];

    float h[8] = {};
    for (int q = 0; q < NCHUNK - 1; ++q) {
        if (q < c) {
            const float2* cp = cb + ((size_t)(b * NCHUNK + q) * D_INNER + d) * D_STATE + j * 8;
#pragma unroll
            for (int s = 0; s < 8; ++s) {
                float2 v = cp[s];
                h[s] = fmaf(__expf(v.x), h[s], v.y);
            }
        }
    }

    const int r0 = b * LL + c * LC;
    const ushort* pd = dltS + (size_t)r0 * D_INNER + d;
    const ushort* px = xsb  + (size_t)r0 * D_INNER + d;
    const float* pB  = dbc  + (size_t)r0 * 64 + 32 + j * 8;
    const float* pC  = dbc  + (size_t)r0 * 64 + 48 + j * 8;
    const ushort* pr = xrb  + (size_t)r0 * 2 * D_INNER + D_INNER + d;
    ushort*      py  = yb   + (size_t)r0 * D_INNER + d;

    float dt = bf2f(*pd), x = bf2f(*px), res = bf2f(*pr);
    float4 B0 = *(const float4*)pB, B1 = *(const float4*)(pB + 4);
    float4 C0 = *(const float4*)pC, C1 = *(const float4*)(pC + 4);

    for (int l = 0; l < LC; ++l) {
        pd += D_INNER; px += D_INNER; pB += 64; pC += 64; pr += 2 * D_INNER;
        const float dt_n = bf2f(*pd), x_n = bf2f(*px), res_n = bf2f(*pr);
        const float4 B0_n = *(const float4*)pB, B1_n = *(const float4*)(pB + 4);
        const float4 C0_n = *(const float4*)pC, C1_n = *(const float4*)(pC + 4);

        const float dx = dt * x;
        float Bs[8] = {B0.x, B0.y, B0.z, B0.w, B1.x, B1.y, B1.z, B1.w};
        float Cs[8] = {C0.x, C0.y, C0.z, C0.w, C1.x, C1.y, C1.z, C1.w};
        float p = 0.f;
#pragma unroll
        for (int s = 0; s < 8; ++s) {
            h[s] = fmaf(__expf(dt * A[s]), h[s], dx * Bs[s]);
            p = fmaf(h[s], Cs[s], p);
        }
        p += __shfl_xor(p, 1);
        if (j == 0) {
            const float g = res / (1.f + __expf(-res));
            py[(size_t)l * D_INNER] = f2bf((p + x * Dd) * g);
        }
        dt = dt_n; x = x_n; res = res_n;
        B0 = B0_n; B1 = B1_n; C0 = C0_n; C1 = C1_n;
    }
}

// ---------------- final stats ----------------
__global__ __launch_bounds__(512) void stats_k(
    const float* __restrict__ m, float* __restrict__ out)
{
    const int b = blockIdx.x;
    const int dm = threadIdx.x;
    const float* p = m + (size_t)b * LL * D_MODEL + dm;
    float s = 0.f;
    for (int l = 0; l < LL; ++l) s += p[(size_t)l * D_MODEL];
    const float mean = s * (1.f / LL);
    float ss = 0.f;
    for (int l = 0; l < LL; ++l) {
        float v = p[(size_t)l * D_MODEL] - mean;
        ss += v * v;
    }
    out[b * (2 * D_MODEL) + dm] = mean;
    out[b * (2 * D_MODEL) + D_MODEL + dm] = sqrtf(ss * (1.f / (LL - 1)));
}

// ---------------- host ----------------
extern "C" void kernel_launch(void* const* d_in, const int* in_sizes, int n_in,
                              void* d_out, int out_size, void* d_ws, size_t ws_size,
                              hipStream_t stream) {
    const float* x            = (const float*)d_in[0];
    const float* proj_w       = (const float*)d_in[1];
    const float* proj_b       = (const float*)d_in[2];
    const float* norm_w       = (const float*)d_in[3];
    const float* in_w         = (const float*)d_in[4];
    const float* conv_w       = (const float*)d_in[5];
    const float* conv_b       = (const float*)d_in[6];
    const float* xproj_w      = (const float*)d_in[7];
    const float* dt_w         = (const float*)d_in[8];
    const float* dt_b         = (const float*)d_in[9];
    const float* A_log        = (const float*)d_in[10];
    const float* Dp           = (const float*)d_in[11];
    const float* out_w        = (const float*)d_in[12];
    const float* final_norm_w = (const float*)d_in[13];

    // fp32 region
    float* ws    = (float*)d_ws;
    float* h     = ws;                                  // 4096*512
    float* dbc   = h    + (size_t)M_ROWS * D_MODEL;     // 4096*64
    float* dpart = dbc  + (size_t)M_ROWS * 64;          // 4*4096*64
    // bf16 region
    ushort* xyb   = (ushort*)(dpart + (size_t)4 * M_ROWS * 64); // 4096*1280 (x, then y)
    ushort* xnb   = xyb   + (size_t)M_ROWS * D_IN;      // 4096*512
    ushort* xrb   = xnb   + (size_t)M_ROWS * D_MODEL;   // 4096*2048 (also fp32 fnorm alias)
    ushort* xsb   = xrb   + (size_t)M_ROWS * 2 * D_INNER; // 4096*1024
    ushort* dltS  = xsb   + (size_t)M_ROWS * D_INNER;   // 4096*1024 (bf16 softplus dt)
    ushort* dltb  = dltS  + (size_t)M_ROWS * D_INNER;   // 4096*32
    ushort* pwb   = dltb  + (size_t)M_ROWS * DT_RANK;   // 512*1280
    ushort* iwb4  = pwb   + (size_t)D_MODEL * D_IN;     // 4*2048*512
    ushort* owb4  = iwb4  + (size_t)N_LAYER * 2 * D_INNER * D_MODEL; // 4*512*1024
    ushort* xpwb4 = owb4  + (size_t)N_LAYER * D_MODEL * D_INNER;     // 4*64*1024
    ushort* dtwb4 = xpwb4 + (size_t)N_LAYER * 64 * D_INNER;          // 4*1024*32
    float2* cbuf  = (float2*)(dtwb4 + (size_t)N_LAYER * D_INNER * DT_RANK); // 16.8MB
    float* fnorm  = (float*)xrb;                        // alias (xrb dead at final norm)

    // ---- one-time casts ----
    cast_bf16_k<<<(M_ROWS * D_IN / 4 + 255) / 256, 256, 0, stream>>>(x, xyb, M_ROWS * D_IN / 4);
    cast_bf16_k<<<(D_MODEL * D_IN / 4 + 255) / 256, 256, 0, stream>>>(proj_w, pwb, D_MODEL * D_IN / 4);
    cast_bf16_k<<<(N_LAYER * 2 * D_INNER * D_MODEL / 4 + 255) / 256, 256, 0, stream>>>(
        in_w, iwb4, N_LAYER * 2 * D_INNER * D_MODEL / 4);
    cast_bf16_k<<<(N_LAYER * D_MODEL * D_INNER / 4 + 255) / 256, 256, 0, stream>>>(
        out_w, owb4, N_LAYER * D_MODEL * D_INNER / 4);
    cast_bf16_k<<<(N_LAYER * 64 * D_INNER / 4 + 255) / 256, 256, 0, stream>>>(
        xproj_w, xpwb4, N_LAYER * 64 * D_INNER / 4);
    cast_bf16_k<<<(N_LAYER * D_INNER * DT_RANK / 4 + 255) / 256, 256, 0, stream>>>(
        dt_w, dtwb4, N_LAYER * D_INNER * DT_RANK / 4);

    // h = x @ proj_w^T + proj_b
    gemm_bf16<64, 64, true, false, 0, false><<<dim3(D_MODEL / 64, M_ROWS / 64), 256, 0, stream>>>(
        xyb, pwb, proj_b, h, M_ROWS, D_MODEL, D_IN, D_IN, D_IN);

    for (int i = 0; i < N_LAYER; ++i) {
        const ushort* iwb  = iwb4  + (size_t)i * 2 * D_INNER * D_MODEL;
        const ushort* owb  = owb4  + (size_t)i * D_MODEL * D_INNER;
        const ushort* xpwb = xpwb4 + (size_t)i * 64 * D_INNER;
        const ushort* dtwb = dtwb4 + (size_t)i * D_INNER * DT_RANK;

        rmsnorm_k<true><<<M_ROWS, 256, 0, stream>>>(h, norm_w + (size_t)i * D_MODEL, nullptr, xnb);

        // xr(bf16) = xn @ in_w^T   (m97-structure MFMA kernel)
        gemm_in_k<<<dim3(2 * D_INNER / 128, M_ROWS / 128), 256, 0, stream>>>(xnb, iwb, xrb);

        conv_silu_k<<<M_ROWS * D_INNER / 256, 256, 0, stream>>>(
            xrb, conv_w + (size_t)i * D_INNER * D_CONV, conv_b + (size_t)i * D_INNER, xsb);

        // dbc partials = xs @ xproj_w^T, split-K=4
        gemm_bf16<128, 32, false, false, 0, false><<<dim3(2, M_ROWS / 128, 4), 256, 0, stream>>>(
            xsb, xpwb, nullptr, dpart, M_ROWS, 64, D_INNER / 4, D_INNER, D_INNER);
        reduce_dbc_k<<<M_ROWS * 64 / 256, 256, 0, stream>>>(dpart, dbc, dltb);

        // dltS(bf16) = softplus(delta @ dt_w^T + dt_b)
        gemm_bf16<64, 64, true, false, 1, true><<<dim3(D_INNER / 64, M_ROWS / 64), 256, 0, stream>>>(
            dltb, dtwb, dt_b + (size_t)i * D_INNER, dltS, M_ROWS, D_INNER, DT_RANK, DT_RANK, DT_RANK);

        scan1_k<<<BB * NCHUNK * (D_INNER / 128), 256, 0, stream>>>(
            dltS, xsb, dbc, A_log + (size_t)i * D_INNER * D_STATE, cbuf);
        scan2_k<<<BB * NCHUNK * (D_INNER / 128), 256, 0, stream>>>(
            dltS, xsb, dbc, xrb, A_log + (size_t)i * D_INNER * D_STATE,
            Dp + (size_t)i * D_INNER, cbuf, xyb);

        // h += y @ out_w^T
        gemm_bf16<64, 64, false, true, 0, false><<<dim3(D_MODEL / 64, M_ROWS / 64), 256, 0, stream>>>(
            xyb, owb, nullptr, h, M_ROWS, D_MODEL, D_INNER, D_INNER, D_INNER);
    }

    rmsnorm_k<false><<<M_ROWS, 256, 0, stream>>>(h, final_norm_w, fnorm, nullptr);
    stats_k<<<BB, D_MODEL, 0, stream>>>(fnorm, (float*)d_out);
}

// Round 12
// 630.631 us; speedup vs baseline: 7.1263x; 1.0942x over previous
//
#include <hip/hip_runtime.h>
#include <math.h>

// ---------------- dims (fixed by the problem) ----------------
#define D_IN     1280
#define D_MODEL  512
#define N_LAYER  4
#define D_STATE  16
#define D_CONV   4
#define D_INNER  1024
#define DT_RANK  32
#define BB       8
#define LL       512
#define M_ROWS   (BB*LL)          // 4096
#define NCHUNK   16
#define LC       (LL/NCHUNK)      // 32

typedef short bf16x8 __attribute__((ext_vector_type(8)));
typedef float f32x4  __attribute__((ext_vector_type(4)));

__device__ __forceinline__ ushort f2bf(float f) {
    unsigned u = __float_as_uint(f);
    u = (u + 0x7FFF + ((u >> 16) & 1)) >> 16;   // RNE
    return (ushort)u;
}
__device__ __forceinline__ float bf2f(ushort u) {
    return __uint_as_float((unsigned)u << 16);
}

// ---------------- fp32 -> bf16 cast (n multiple of 4) ----------------
__global__ __launch_bounds__(256) void cast_bf16_k(
    const float* __restrict__ in, ushort* __restrict__ out, int n4)
{
    int i = blockIdx.x * 256 + threadIdx.x;
    if (i < n4) {
        float4 v = *(const float4*)(in + (size_t)i * 4);
        *(ushort4*)(out + (size_t)i * 4) =
            make_ushort4(f2bf(v.x), f2bf(v.y), f2bf(v.z), f2bf(v.w));
    }
}

// ---- split-K reduce for dbc: sum 4 partials; also emit delta cols as bf16 ----
__global__ __launch_bounds__(256) void reduce_dbc_k(
    const float* __restrict__ part, float* __restrict__ dbc,
    ushort* __restrict__ dltb)
{
    const int i = blockIdx.x * 256 + threadIdx.x;   // over 4096*64
    const int c = i & 63;
    float s = part[i] + part[i + M_ROWS * 64] + part[i + 2 * M_ROWS * 64]
            + part[i + 3 * M_ROWS * 64];
    dbc[i] = s;
    if (c < 32) dltb[(i >> 6) * 32 + c] = f2bf(s);
}

// ============ m97-structure GEMM: 128xBN tile, BK=32, global_load_lds =========
// 4 waves 2x2, wave tile 64 x BN/2. Linear LDS staging (16B DMA per lane).
// OUTBF: bf16 out via LDS-staged coalesced epilogue; else fp32 (BIAS/ACCUM).
template<int BN, int NDIM, int KDIM, bool BIAS, bool ACCUM, bool OUTBF>
__global__ __launch_bounds__(256) void gemm_gl(
    const ushort* __restrict__ A, const ushort* __restrict__ W,
    const float* __restrict__ bias, void* __restrict__ Cv)
{
    constexpr int BM = 128, BK = 32;
    constexpr int ACH = BM / 16;                // 8 A-chunks (16 rows x 64B)
    constexpr int TC  = (BM + BN) / 16;         // total chunks
    constexpr int PW  = TC / 4;                 // chunks per wave
    constexpr int HN  = BN / 2;
    constexpr int FN  = BN / 32;
    constexpr int SM_STAGE = (BM + BN) * BK;
    constexpr int SM_C = OUTBF ? BM * (BN + 8) : 0;
    constexpr int SM = (SM_STAGE > SM_C) ? SM_STAGE : SM_C;
    __shared__ ushort smem[SM];
    ushort* lA = smem;
    ushort* lB = smem + BM * BK;
    const int tid = threadIdx.x, lane = tid & 63, wid = tid >> 6;
    const int wr = wid >> 1, wc = wid & 1;
    const int bm = blockIdx.y * BM, bn = blockIdx.x * BN;
    const int l15 = lane & 15, lk = lane >> 4;
    const int srow = lane >> 2, scol = (lane & 3) * 8;

    f32x4 acc[4][FN];
#pragma unroll
    for (int i = 0; i < 4; ++i)
#pragma unroll
        for (int j = 0; j < FN; ++j) acc[i][j] = (f32x4)0.f;

    for (int kk = 0; kk < KDIM; kk += BK) {
#pragma unroll
        for (int i = 0; i < PW; ++i) {
            const int ch = wid * PW + i;
            const ushort* g = (ch < ACH)
                ? A + (size_t)(bm + ch * 16 + srow) * KDIM + kk + scol
                : W + (size_t)(bn + (ch - ACH) * 16 + srow) * KDIM + kk + scol;
            __builtin_amdgcn_global_load_lds(
                (const __attribute__((address_space(1))) void*)g,
                (__attribute__((address_space(3))) void*)(smem + ch * 512), 16, 0, 0);
        }
        __syncthreads();   // drains vmcnt; tiles ready

        bf16x8 af[4], bw[FN];
#pragma unroll
        for (int fm = 0; fm < 4; ++fm)
            af[fm] = *(const bf16x8*)&lA[(wr * 64 + fm * 16 + l15) * BK + lk * 8];
#pragma unroll
        for (int fn = 0; fn < FN; ++fn)
            bw[fn] = *(const bf16x8*)&lB[(wc * HN + fn * 16 + l15) * BK + lk * 8];
#pragma unroll
        for (int fm = 0; fm < 4; ++fm)
#pragma unroll
            for (int fn = 0; fn < FN; ++fn)
                acc[fm][fn] = __builtin_amdgcn_mfma_f32_16x16x32_bf16(
                    af[fm], bw[fn], acc[fm][fn], 0, 0, 0);
        __syncthreads();
    }

    if (OUTBF) {
        ushort* cst = smem;                     // [BM][BN+8]
#pragma unroll
        for (int fm = 0; fm < 4; ++fm) {
#pragma unroll
            for (int fn = 0; fn < FN; ++fn) {
                const int col = wc * HN + fn * 16 + l15;
                const float bv = BIAS ? bias[bn + col] : 0.f;
#pragma unroll
                for (int j = 0; j < 4; ++j) {
                    const int row = wr * 64 + fm * 16 + lk * 4 + j;
                    cst[row * (BN + 8) + col] = f2bf(acc[fm][fn][j] + bv);
                }
            }
        }
        __syncthreads();
        ushort* Cb = (ushort*)Cv;
        constexpr int NV = BM * BN / 8;
#pragma unroll
        for (int k = 0; k < NV / 256; ++k) {
            const int i = k * 256 + tid;
            const int row = i / (BN / 8), c8 = i % (BN / 8);
            *(uint4*)&Cb[(size_t)(bm + row) * NDIM + bn + c8 * 8] =
                *(uint4*)&cst[row * (BN + 8) + c8 * 8];
        }
    } else {
        float* Cf = (float*)Cv;
#pragma unroll
        for (int fm = 0; fm < 4; ++fm) {
#pragma unroll
            for (int fn = 0; fn < FN; ++fn) {
                const int col = bn + wc * HN + fn * 16 + l15;
                const float bv = BIAS ? bias[col] : 0.f;
#pragma unroll
                for (int j = 0; j < 4; ++j) {
                    const int row = bm + wr * 64 + fm * 16 + lk * 4 + j;
                    float r = acc[fm][fn][j] + bv;
                    float* cp = Cf + (size_t)row * NDIM + col;
                    if (ACCUM) r += *cp;
                    *cp = r;
                }
            }
        }
    }
}

// ---------------- bf16 MFMA GEMM (reg-staged; small shapes) -------------------
template<int BM, int BN, bool BIAS, bool ACCUM, int ACT, bool OUTBF>
__global__ __launch_bounds__(256) void gemm_bf16(
    const ushort* __restrict__ A, const ushort* __restrict__ W,
    const float* __restrict__ bias, void* __restrict__ Cv,
    int M, int N, int K, int lda, int ldw)
{
    constexpr int BK = 32;
    constexpr int LDA = BK + 8;
    constexpr int WC = (BM == 128) ? 2 : 4;
    constexpr int HN = BN / WC;
    constexpr int FN = HN / 16;
    constexpr int AL = BM / 64;
    constexpr int BL = (BN * 4 + 255) / 256;
    constexpr int SM_G = (BM + BN) * LDA;
    constexpr int SM_C = OUTBF ? BM * (BN + 8) : 0;
    constexpr int SM   = (SM_G > SM_C) ? SM_G : SM_C;
    __shared__ ushort smem[SM];
    ushort* lA = smem;
    ushort* lB = smem + BM * LDA;
    const int tid  = threadIdx.x;
    const int lane = tid & 63;
    const int wid  = tid >> 6;
    const int wr = (BM == 128) ? (wid >> 1) : 0;
    const int wc = (BM == 128) ? (wid & 1) : wid;
    const int bm = blockIdx.y * BM, bn = blockIdx.x * BN;
    const int koff = blockIdx.z * K;
    const size_t cz = (size_t)blockIdx.z * M * N;
    const int l15 = lane & 15, lk = lane >> 4;

    f32x4 acc[4][FN];
#pragma unroll
    for (int i = 0; i < 4; ++i)
#pragma unroll
        for (int j = 0; j < FN; ++j) acc[i][j] = (f32x4)0.f;

    for (int kk = 0; kk < K; kk += BK) {
        uint4 va[AL], vb[BL];
#pragma unroll
        for (int i = 0; i < AL; ++i) {
            int c = i * 256 + tid, row = c >> 2, k0 = (c & 3) * 8;
            va[i] = *(const uint4*)(A + (size_t)(bm + row) * lda + koff + kk + k0);
        }
#pragma unroll
        for (int i = 0; i < BL; ++i) {
            int c = i * 256 + tid;
            if ((BN * 4 % 256 == 0) || c < BN * 4) {
                int row = c >> 2, k0 = (c & 3) * 8;
                vb[i] = *(const uint4*)(W + (size_t)(bn + row) * ldw + koff + kk + k0);
            }
        }
        __syncthreads();
#pragma unroll
        for (int i = 0; i < AL; ++i) {
            int c = i * 256 + tid, row = c >> 2, k0 = (c & 3) * 8;
            *(uint4*)&lA[row * LDA + k0] = va[i];
        }
#pragma unroll
        for (int i = 0; i < BL; ++i) {
            int c = i * 256 + tid;
            if ((BN * 4 % 256 == 0) || c < BN * 4) {
                int row = c >> 2, k0 = (c & 3) * 8;
                *(uint4*)&lB[row * LDA + k0] = vb[i];
            }
        }
        __syncthreads();

        bf16x8 af[4], bw[FN];
#pragma unroll
        for (int fm = 0; fm < 4; ++fm)
            af[fm] = *(const bf16x8*)&lA[(wr * 64 + fm * 16 + l15) * LDA + lk * 8];
#pragma unroll
        for (int fn = 0; fn < FN; ++fn)
            bw[fn] = *(const bf16x8*)&lB[(wc * HN + fn * 16 + l15) * LDA + lk * 8];
#pragma unroll
        for (int fm = 0; fm < 4; ++fm)
#pragma unroll
            for (int fn = 0; fn < FN; ++fn)
                acc[fm][fn] = __builtin_amdgcn_mfma_f32_16x16x32_bf16(
                    af[fm], bw[fn], acc[fm][fn], 0, 0, 0);
    }

    if (OUTBF) {
        __syncthreads();
        ushort* cst = smem;
#pragma unroll
        for (int fm = 0; fm < 4; ++fm) {
#pragma unroll
            for (int fn = 0; fn < FN; ++fn) {
                int col = wc * HN + fn * 16 + l15;
                float bv = BIAS ? bias[bn + col] : 0.f;
#pragma unroll
                for (int j = 0; j < 4; ++j) {
                    int row = wr * 64 + fm * 16 + lk * 4 + j;
                    float r = acc[fm][fn][j] + bv;
                    if (ACT == 1) r = (r > 20.f) ? r : log1pf(expf(r));
                    cst[row * (BN + 8) + col] = f2bf(r);
                }
            }
        }
        __syncthreads();
        ushort* Cb = (ushort*)Cv + cz;
        constexpr int NV = BM * BN / 8;
#pragma unroll
        for (int k = 0; k < NV / 256; ++k) {
            int i = k * 256 + tid;
            int row = i / (BN / 8), c8 = i % (BN / 8);
            uint4 v = *(uint4*)&cst[row * (BN + 8) + c8 * 8];
            *(uint4*)&Cb[(size_t)(bm + row) * N + bn + c8 * 8] = v;
        }
    } else {
        float* Cf = (float*)Cv + cz;
#pragma unroll
        for (int fm = 0; fm < 4; ++fm) {
#pragma unroll
            for (int fn = 0; fn < FN; ++fn) {
                int col = bn + wc * HN + fn * 16 + l15;
                float bv = BIAS ? bias[col] : 0.f;
#pragma unroll
                for (int j = 0; j < 4; ++j) {
                    int row = bm + wr * 64 + fm * 16 + lk * 4 + j;
                    float r = acc[fm][fn][j] + bv;
                    if (ACT == 1) r = (r > 20.f) ? r : log1pf(expf(r));
                    float* cp = Cf + (size_t)row * N + col;
                    if (ACCUM) r += *cp;
                    *cp = r;
                }
            }
        }
    }
}

// ---------------- RMSNorm over last dim D=512 ---------------------------------
template<bool BF16OUT>
__global__ __launch_bounds__(256) void rmsnorm_k(
    const float* __restrict__ X, const float* __restrict__ w,
    float* __restrict__ Yf, ushort* __restrict__ Yb)
{
    const int r = blockIdx.x;
    const float* x = X + (size_t)r * D_MODEL;
    float2 v = *(const float2*)(x + threadIdx.x * 2);
    float ss = v.x * v.x + v.y * v.y;
#pragma unroll
    for (int off = 32; off > 0; off >>= 1) ss += __shfl_down(ss, off);
    __shared__ float wsum[4];
    if ((threadIdx.x & 63) == 0) wsum[threadIdx.x >> 6] = ss;
    __syncthreads();
    float tot = wsum[0] + wsum[1] + wsum[2] + wsum[3];
    float rs = rsqrtf(tot * (1.f / D_MODEL) + 1e-5f);
    float2 wv = *(const float2*)(w + threadIdx.x * 2);
    float a = v.x * rs * wv.x, b = v.y * rs * wv.y;
    if (BF16OUT)
        *(ushort2*)(Yb + (size_t)r * D_MODEL + threadIdx.x * 2) =
            make_ushort2(f2bf(a), f2bf(b));
    else
        *(float2*)(Yf + (size_t)r * D_MODEL + threadIdx.x * 2) = make_float2(a, b);
}

// ------- depthwise causal conv1d (k=4, bf16 in) + bias + silu -> bf16 xs ------
__global__ __launch_bounds__(256) void conv_silu_k(
    const ushort* __restrict__ xrb, const float* __restrict__ cw,
    const float* __restrict__ cb, ushort* __restrict__ xsb)
{
    const int idx = blockIdx.x * 256 + threadIdx.x;
    const int d = idx & (D_INNER - 1);
    const int r = idx >> 10;
    const int l = r & (LL - 1);
    const ushort* base = xrb + (size_t)r * (2 * D_INNER) + d;
    float4 w = *(const float4*)(cw + d * 4);
    float acc = cb[d];
    if (l >= 3) acc += bf2f(base[-3 * 2 * D_INNER]) * w.x;
    if (l >= 2) acc += bf2f(base[-2 * 2 * D_INNER]) * w.y;
    if (l >= 1) acc += bf2f(base[-1 * 2 * D_INNER]) * w.z;
    acc += bf2f(base[0]) * w.w;
    xsb[idx] = f2bf(acc / (1.f + __expf(-acc)));
}

// ---------------- selective scan, chunk-parallel, 4 states/thread -------------
// 4 threads per d (j = tid&3, states j*4..j*4+3); d = dblk*64 + (tid>>2).
// Depth-3 software pipeline: 4 named register buffer groups, step-4 loop.
// Phase 1 stores {P = prod(dA), h_local} so phase 2's fold is exp-free.
__global__ __launch_bounds__(256) void scan1_k(
    const ushort* __restrict__ dltS, const ushort* __restrict__ xsb,
    const float* __restrict__ dbc, const float* __restrict__ A_log,
    float2* __restrict__ cb)
{
    const int b    = blockIdx.x >> 8;
    const int c    = (blockIdx.x >> 4) & 15;
    const int dblk = blockIdx.x & 15;
    const int d = dblk * 64 + (threadIdx.x >> 2);
    const int j = threadIdx.x & 3;

    float A[4];
#pragma unroll
    for (int s = 0; s < 4; ++s) A[s] = -__expf(A_log[d * D_STATE + j * 4 + s]);

    const int r0 = b * LL + c * LC;
    const ushort* pd = dltS + (size_t)r0 * D_INNER + d;
    const ushort* px = xsb  + (size_t)r0 * D_INNER + d;
    const float* pB  = dbc  + (size_t)r0 * 64 + 32 + j * 4;

    float h[4] = {}, P[4] = {1.f, 1.f, 1.f, 1.f};
    float dt_A, dt_B, dt_C, dt_D, xv_A, xv_B, xv_C, xv_D;
    float4 Bq_A, Bq_B, Bq_C, Bq_D;

#define LD1(G, L) { dt_##G = bf2f(pd[(size_t)(L) * D_INNER]); \
                    xv_##G = bf2f(px[(size_t)(L) * D_INNER]); \
                    Bq_##G = *(const float4*)(pB + (size_t)(L) * 64); }
#define CP1(G) { const float dx = dt_##G * xv_##G; \
    const float dA0 = __expf(dt_##G * A[0]), dA1 = __expf(dt_##G * A[1]); \
    const float dA2 = __expf(dt_##G * A[2]), dA3 = __expf(dt_##G * A[3]); \
    P[0] *= dA0; h[0] = fmaf(dA0, h[0], dx * Bq_##G.x); \
    P[1] *= dA1; h[1] = fmaf(dA1, h[1], dx * Bq_##G.y); \
    P[2] *= dA2; h[2] = fmaf(dA2, h[2], dx * Bq_##G.z); \
    P[3] *= dA3; h[3] = fmaf(dA3, h[3], dx * Bq_##G.w); }

    LD1(A, 0) LD1(B, 1) LD1(C, 2) LD1(D, 3)
    for (int l = 0; l < LC; l += 4) {          // tail over-reads stay inside d_ws
        CP1(A) LD1(A, l + 4)
        CP1(B) LD1(B, l + 5)
        CP1(C) LD1(C, l + 6)
        CP1(D) LD1(D, l + 7)
    }
#undef LD1
#undef CP1
    float2* cp = cb + ((size_t)(b * NCHUNK + c) * D_INNER + d) * D_STATE + j * 4;
#pragma unroll
    for (int s = 0; s < 4; ++s) cp[s] = make_float2(P[s], h[s]);
}

__global__ __launch_bounds__(256) void scan2_k(
    const ushort* __restrict__ dltS, const ushort* __restrict__ xsb,
    const float* __restrict__ dbc, const ushort* __restrict__ xrb,
    const float* __restrict__ A_log, const float* __restrict__ Dp,
    const float2* __restrict__ cb, ushort* __restrict__ yb)
{
    const int b    = blockIdx.x >> 8;
    const int c    = (blockIdx.x >> 4) & 15;
    const int dblk = blockIdx.x & 15;
    const int d = dblk * 64 + (threadIdx.x >> 2);
    const int j = threadIdx.x & 3;

    float A[4];
#pragma unroll
    for (int s = 0; s < 4; ++s) A[s] = -__expf(A_log[d * D_STATE + j * 4 + s]);
    const float Dd = Dp[d];

    // fold predecessor summaries (P-form: no exp)
    float h[4] = {};
    for (int q = 0; q < NCHUNK - 1; ++q) {
        if (q < c) {
            const float2* cp = cb + ((size_t)(b * NCHUNK + q) * D_INNER + d) * D_STATE + j * 4;
#pragma unroll
            for (int s = 0; s < 4; ++s) {
                float2 v = cp[s];
                h[s] = fmaf(v.x, h[s], v.y);
            }
        }
    }

    const int r0 = b * LL + c * LC;
    const ushort* pd = dltS + (size_t)r0 * D_INNER + d;
    const ushort* px = xsb  + (size_t)r0 * D_INNER + d;
    const float* pB  = dbc  + (size_t)r0 * 64 + 32 + j * 4;
    const float* pC  = dbc  + (size_t)r0 * 64 + 48 + j * 4;
    const ushort* pr = xrb  + (size_t)r0 * 2 * D_INNER + D_INNER + d;
    ushort*      py  = yb   + (size_t)r0 * D_INNER + d;

    float dt_A, dt_B, dt_C, dt_D, xv_A, xv_B, xv_C, xv_D, rs_A, rs_B, rs_C, rs_D;
    float4 Bq_A, Bq_B, Bq_C, Bq_D, Cq_A, Cq_B, Cq_C, Cq_D;

#define LD2(G, L) { dt_##G = bf2f(pd[(size_t)(L) * D_INNER]); \
                    xv_##G = bf2f(px[(size_t)(L) * D_INNER]); \
                    rs_##G = bf2f(pr[(size_t)(L) * 2 * D_INNER]); \
                    Bq_##G = *(const float4*)(pB + (size_t)(L) * 64); \
                    Cq_##G = *(const float4*)(pC + (size_t)(L) * 64); }
#define CP2(G, L) { const float dx = dt_##G * xv_##G; \
    const float dA0 = __expf(dt_##G * A[0]), dA1 = __expf(dt_##G * A[1]); \
    const float dA2 = __expf(dt_##G * A[2]), dA3 = __expf(dt_##G * A[3]); \
    float p; \
    h[0] = fmaf(dA0, h[0], dx * Bq_##G.x); p  = h[0] * Cq_##G.x; \
    h[1] = fmaf(dA1, h[1], dx * Bq_##G.y); p = fmaf(h[1], Cq_##G.y, p); \
    h[2] = fmaf(dA2, h[2], dx * Bq_##G.z); p = fmaf(h[2], Cq_##G.z, p); \
    h[3] = fmaf(dA3, h[3], dx * Bq_##G.w); p = fmaf(h[3], Cq_##G.w, p); \
    p += __shfl_xor(p, 1); \
    p += __shfl_xor(p, 2); \
    if (j == 0) { \
        const float g = rs_##G / (1.f + __expf(-rs_##G)); \
        py[(size_t)(L) * D_INNER] = f2bf((p + xv_##G * Dd) * g); \
    } }

    LD2(A, 0) LD2(B, 1) LD2(C, 2) LD2(D, 3)
    for (int l = 0; l < LC; l += 4) {          // tail over-reads stay inside d_ws
        CP2(A, l)     LD2(A, l + 4)
        CP2(B, l + 1) LD2(B, l + 5)
        CP2(C, l + 2) LD2(C, l + 6)
        CP2(D, l + 3) LD2(D, l + 7)
    }
#undef LD2
#undef CP2
}

// ---------------- final stats ----------------
__global__ __launch_bounds__(512) void stats_k(
    const float* __restrict__ m, float* __restrict__ out)
{
    const int b = blockIdx.x;
    const int dm = threadIdx.x;
    const float* p = m + (size_t)b * LL * D_MODEL + dm;
    float s = 0.f;
    for (int l = 0; l < LL; ++l) s += p[(size_t)l * D_MODEL];
    const float mean = s * (1.f / LL);
    float ss = 0.f;
    for (int l = 0; l < LL; ++l) {
        float v = p[(size_t)l * D_MODEL] - mean;
        ss += v * v;
    }
    out[b * (2 * D_MODEL) + dm] = mean;
    out[b * (2 * D_MODEL) + D_MODEL + dm] = sqrtf(ss * (1.f / (LL - 1)));
}

// ---------------- host ----------------
extern "C" void kernel_launch(void* const* d_in, const int* in_sizes, int n_in,
                              void* d_out, int out_size, void* d_ws, size_t ws_size,
                              hipStream_t stream) {
    const float* x            = (const float*)d_in[0];
    const float* proj_w       = (const float*)d_in[1];
    const float* proj_b       = (const float*)d_in[2];
    const float* norm_w       = (const float*)d_in[3];
    const float* in_w         = (const float*)d_in[4];
    const float* conv_w       = (const float*)d_in[5];
    const float* conv_b       = (const float*)d_in[6];
    const float* xproj_w      = (const float*)d_in[7];
    const float* dt_w         = (const float*)d_in[8];
    const float* dt_b         = (const float*)d_in[9];
    const float* A_log        = (const float*)d_in[10];
    const float* Dp           = (const float*)d_in[11];
    const float* out_w        = (const float*)d_in[12];
    const float* final_norm_w = (const float*)d_in[13];

    // fp32 region
    float* ws    = (float*)d_ws;
    float* h     = ws;                                  // 4096*512
    float* dbc   = h    + (size_t)M_ROWS * D_MODEL;     // 4096*64
    float* dpart = dbc  + (size_t)M_ROWS * 64;          // 4*4096*64
    // bf16 region
    ushort* xyb   = (ushort*)(dpart + (size_t)4 * M_ROWS * 64); // 4096*1280 (x, then y)
    ushort* xnb   = xyb   + (size_t)M_ROWS * D_IN;      // 4096*512
    ushort* xrb   = xnb   + (size_t)M_ROWS * D_MODEL;   // 4096*2048 (also fp32 fnorm alias)
    ushort* xsb   = xrb   + (size_t)M_ROWS * 2 * D_INNER; // 4096*1024
    ushort* dltS  = xsb   + (size_t)M_ROWS * D_INNER;   // 4096*1024 (bf16 softplus dt)
    ushort* dltb  = dltS  + (size_t)M_ROWS * D_INNER;   // 4096*32
    ushort* pwb   = dltb  + (size_t)M_ROWS * DT_RANK;   // 512*1280
    ushort* iwb4  = pwb   + (size_t)D_MODEL * D_IN;     // 4*2048*512
    ushort* owb4  = iwb4  + (size_t)N_LAYER * 2 * D_INNER * D_MODEL; // 4*512*1024
    ushort* xpwb4 = owb4  + (size_t)N_LAYER * D_MODEL * D_INNER;     // 4*64*1024
    ushort* dtwb4 = xpwb4 + (size_t)N_LAYER * 64 * D_INNER;          // 4*1024*32
    float2* cbuf  = (float2*)(dtwb4 + (size_t)N_LAYER * D_INNER * DT_RANK); // 16.8MB
    float* fnorm  = (float*)xrb;                        // alias (xrb dead at final norm)

    // ---- one-time casts ----
    cast_bf16_k<<<(M_ROWS * D_IN / 4 + 255) / 256, 256, 0, stream>>>(x, xyb, M_ROWS * D_IN / 4);
    cast_bf16_k<<<(D_MODEL * D_IN / 4 + 255) / 256, 256, 0, stream>>>(proj_w, pwb, D_MODEL * D_IN / 4);
    cast_bf16_k<<<(N_LAYER * 2 * D_INNER * D_MODEL / 4 + 255) / 256, 256, 0, stream>>>(
        in_w, iwb4, N_LAYER * 2 * D_INNER * D_MODEL / 4);
    cast_bf16_k<<<(N_LAYER * D_MODEL * D_INNER / 4 + 255) / 256, 256, 0, stream>>>(
        out_w, owb4, N_LAYER * D_MODEL * D_INNER / 4);
    cast_bf16_k<<<(N_LAYER * 64 * D_INNER / 4 + 255) / 256, 256, 0, stream>>>(
        xproj_w, xpwb4, N_LAYER * 64 * D_INNER / 4);
    cast_bf16_k<<<(N_LAYER * D_INNER * DT_RANK / 4 + 255) / 256, 256, 0, stream>>>(
        dt_w, dtwb4, N_LAYER * D_INNER * DT_RANK / 4);

    // h = x @ proj_w^T + proj_b   (m97 structure, BN=64)
    gemm_gl<64, D_MODEL, D_IN, true, false, false>
        <<<dim3(D_MODEL / 64, M_ROWS / 128), 256, 0, stream>>>(xyb, pwb, proj_b, h);

    for (int i = 0; i < N_LAYER; ++i) {
        const ushort* iwb  = iwb4  + (size_t)i * 2 * D_INNER * D_MODEL;
        const ushort* owb  = owb4  + (size_t)i * D_MODEL * D_INNER;
        const ushort* xpwb = xpwb4 + (size_t)i * 64 * D_INNER;
        const ushort* dtwb = dtwb4 + (size_t)i * D_INNER * DT_RANK;

        rmsnorm_k<true><<<M_ROWS, 256, 0, stream>>>(h, norm_w + (size_t)i * D_MODEL, nullptr, xnb);

        // xr(bf16) = xn @ in_w^T   (m97 structure, BN=128)
        gemm_gl<128, 2 * D_INNER, D_MODEL, false, false, true>
            <<<dim3(2 * D_INNER / 128, M_ROWS / 128), 256, 0, stream>>>(xnb, iwb, nullptr, xrb);

        conv_silu_k<<<M_ROWS * D_INNER / 256, 256, 0, stream>>>(
            xrb, conv_w + (size_t)i * D_INNER * D_CONV, conv_b + (size_t)i * D_INNER, xsb);

        // dbc partials = xs @ xproj_w^T, split-K=4
        gemm_bf16<128, 32, false, false, 0, false><<<dim3(2, M_ROWS / 128, 4), 256, 0, stream>>>(
            xsb, xpwb, nullptr, dpart, M_ROWS, 64, D_INNER / 4, D_INNER, D_INNER);
        reduce_dbc_k<<<M_ROWS * 64 / 256, 256, 0, stream>>>(dpart, dbc, dltb);

        // dltS(bf16) = softplus(delta @ dt_w^T + dt_b)
        gemm_bf16<64, 64, true, false, 1, true><<<dim3(D_INNER / 64, M_ROWS / 64), 256, 0, stream>>>(
            dltb, dtwb, dt_b + (size_t)i * D_INNER, dltS, M_ROWS, D_INNER, DT_RANK, DT_RANK, DT_RANK);

        scan1_k<<<BB * NCHUNK * (D_INNER / 64), 256, 0, stream>>>(
            dltS, xsb, dbc, A_log + (size_t)i * D_INNER * D_STATE, cbuf);
        scan2_k<<<BB * NCHUNK * (D_INNER / 64), 256, 0, stream>>>(
            dltS, xsb, dbc, xrb, A_log + (size_t)i * D_INNER * D_STATE,
            Dp + (size_t)i * D_INNER, cbuf, xyb);

        // h += y @ out_w^T   (m97 structure, BN=64)
        gemm_gl<64, D_MODEL, D_INNER, false, true, false>
            <<<dim3(D_MODEL / 64, M_ROWS / 128), 256, 0, stream>>>(xyb, owb, nullptr, h);
    }

    rmsnorm_k<false><<<M_ROWS, 256, 0, stream>>>(h, final_norm_w, fnorm, nullptr);
    stats_k<<<BB, D_MODEL, 0, stream>>>(fnorm, (float*)d_out);
}

// Round 13
// 603.345 us; speedup vs baseline: 7.4486x; 1.0452x over previous
//
#include <hip/hip_runtime.h>
#include <math.h>

// ---------------- dims (fixed by the problem) ----------------
#define D_IN     1280
#define D_MODEL  512
#define N_LAYER  4
#define D_STATE  16
#define D_CONV   4
#define D_INNER  1024
#define DT_RANK  32
#define BB       8
#define LL       512
#define M_ROWS   (BB*LL)          // 4096
#define NCHUNK   16
#define LC       (LL/NCHUNK)      // 32

typedef short bf16x8 __attribute__((ext_vector_type(8)));
typedef float f32x4  __attribute__((ext_vector_type(4)));

__device__ __forceinline__ ushort f2bf(float f) {
    unsigned u = __float_as_uint(f);
    u = (u + 0x7FFF + ((u >> 16) & 1)) >> 16;   // RNE
    return (ushort)u;
}
__device__ __forceinline__ float bf2f(ushort u) {
    return __uint_as_float((unsigned)u << 16);
}

// ---------------- fp32 -> bf16 cast (n multiple of 4) ----------------
__global__ __launch_bounds__(256) void cast_bf16_k(
    const float* __restrict__ in, ushort* __restrict__ out, int n4)
{
    int i = blockIdx.x * 256 + threadIdx.x;
    if (i < n4) {
        float4 v = *(const float4*)(in + (size_t)i * 4);
        *(ushort4*)(out + (size_t)i * 4) =
            make_ushort4(f2bf(v.x), f2bf(v.y), f2bf(v.z), f2bf(v.w));
    }
}

// ---- split-K reduce for dbc: sum 4 partials; also emit delta cols as bf16 ----
__global__ __launch_bounds__(256) void reduce_dbc_k(
    const float* __restrict__ part, float* __restrict__ dbc,
    ushort* __restrict__ dltb)
{
    const int i = blockIdx.x * 256 + threadIdx.x;   // over 4096*64
    const int c = i & 63;
    float s = part[i] + part[i + M_ROWS * 64] + part[i + 2 * M_ROWS * 64]
            + part[i + 3 * M_ROWS * 64];
    dbc[i] = s;
    if (c < 32) dltb[(i >> 6) * 32 + c] = f2bf(s);
}

// ============ m97-structure GEMM: 128xBN tile, BK=32, global_load_lds =========
template<int BN, int NDIM, int KDIM, bool BIAS, bool ACCUM, bool OUTBF>
__global__ __launch_bounds__(256) void gemm_gl(
    const ushort* __restrict__ A, const ushort* __restrict__ W,
    const float* __restrict__ bias, void* __restrict__ Cv)
{
    constexpr int BM = 128, BK = 32;
    constexpr int ACH = BM / 16;
    constexpr int TC  = (BM + BN) / 16;
    constexpr int PW  = TC / 4;
    constexpr int HN  = BN / 2;
    constexpr int FN  = BN / 32;
    constexpr int SM_STAGE = (BM + BN) * BK;
    constexpr int SM_C = OUTBF ? BM * (BN + 8) : 0;
    constexpr int SM = (SM_STAGE > SM_C) ? SM_STAGE : SM_C;
    __shared__ ushort smem[SM];
    ushort* lA = smem;
    ushort* lB = smem + BM * BK;
    const int tid = threadIdx.x, lane = tid & 63, wid = tid >> 6;
    const int wr = wid >> 1, wc = wid & 1;
    const int bm = blockIdx.y * BM, bn = blockIdx.x * BN;
    const int l15 = lane & 15, lk = lane >> 4;
    const int srow = lane >> 2, scol = (lane & 3) * 8;

    f32x4 acc[4][FN];
#pragma unroll
    for (int i = 0; i < 4; ++i)
#pragma unroll
        for (int j = 0; j < FN; ++j) acc[i][j] = (f32x4)0.f;

    for (int kk = 0; kk < KDIM; kk += BK) {
#pragma unroll
        for (int i = 0; i < PW; ++i) {
            const int ch = wid * PW + i;
            const ushort* g = (ch < ACH)
                ? A + (size_t)(bm + ch * 16 + srow) * KDIM + kk + scol
                : W + (size_t)(bn + (ch - ACH) * 16 + srow) * KDIM + kk + scol;
            __builtin_amdgcn_global_load_lds(
                (const __attribute__((address_space(1))) void*)g,
                (__attribute__((address_space(3))) void*)(smem + ch * 512), 16, 0, 0);
        }
        __syncthreads();

        bf16x8 af[4], bw[FN];
#pragma unroll
        for (int fm = 0; fm < 4; ++fm)
            af[fm] = *(const bf16x8*)&lA[(wr * 64 + fm * 16 + l15) * BK + lk * 8];
#pragma unroll
        for (int fn = 0; fn < FN; ++fn)
            bw[fn] = *(const bf16x8*)&lB[(wc * HN + fn * 16 + l15) * BK + lk * 8];
#pragma unroll
        for (int fm = 0; fm < 4; ++fm)
#pragma unroll
            for (int fn = 0; fn < FN; ++fn)
                acc[fm][fn] = __builtin_amdgcn_mfma_f32_16x16x32_bf16(
                    af[fm], bw[fn], acc[fm][fn], 0, 0, 0);
        __syncthreads();
    }

    if (OUTBF) {
        ushort* cst = smem;
#pragma unroll
        for (int fm = 0; fm < 4; ++fm) {
#pragma unroll
            for (int fn = 0; fn < FN; ++fn) {
                const int col = wc * HN + fn * 16 + l15;
                const float bv = BIAS ? bias[bn + col] : 0.f;
#pragma unroll
                for (int j = 0; j < 4; ++j) {
                    const int row = wr * 64 + fm * 16 + lk * 4 + j;
                    cst[row * (BN + 8) + col] = f2bf(acc[fm][fn][j] + bv);
                }
            }
        }
        __syncthreads();
        ushort* Cb = (ushort*)Cv;
        constexpr int NV = BM * BN / 8;
#pragma unroll
        for (int k = 0; k < NV / 256; ++k) {
            const int i = k * 256 + tid;
            const int row = i / (BN / 8), c8 = i % (BN / 8);
            *(uint4*)&Cb[(size_t)(bm + row) * NDIM + bn + c8 * 8] =
                *(uint4*)&cst[row * (BN + 8) + c8 * 8];
        }
    } else {
        float* Cf = (float*)Cv;
#pragma unroll
        for (int fm = 0; fm < 4; ++fm) {
#pragma unroll
            for (int fn = 0; fn < FN; ++fn) {
                const int col = bn + wc * HN + fn * 16 + l15;
                const float bv = BIAS ? bias[col] : 0.f;
#pragma unroll
                for (int j = 0; j < 4; ++j) {
                    const int row = bm + wr * 64 + fm * 16 + lk * 4 + j;
                    float r = acc[fm][fn][j] + bv;
                    float* cp = Cf + (size_t)row * NDIM + col;
                    if (ACCUM) r += *cp;
                    *cp = r;
                }
            }
        }
    }
}

// ---------------- bf16 MFMA GEMM (reg-staged; small shapes) -------------------
template<int BM, int BN, bool BIAS, bool ACCUM, int ACT, bool OUTBF>
__global__ __launch_bounds__(256) void gemm_bf16(
    const ushort* __restrict__ A, const ushort* __restrict__ W,
    const float* __restrict__ bias, void* __restrict__ Cv,
    int M, int N, int K, int lda, int ldw)
{
    constexpr int BK = 32;
    constexpr int LDA = BK + 8;
    constexpr int WC = (BM == 128) ? 2 : 4;
    constexpr int HN = BN / WC;
    constexpr int FN = HN / 16;
    constexpr int AL = BM / 64;
    constexpr int BL = (BN * 4 + 255) / 256;
    constexpr int SM_G = (BM + BN) * LDA;
    constexpr int SM_C = OUTBF ? BM * (BN + 8) : 0;
    constexpr int SM   = (SM_G > SM_C) ? SM_G : SM_C;
    __shared__ ushort smem[SM];
    ushort* lA = smem;
    ushort* lB = smem + BM * LDA;
    const int tid  = threadIdx.x;
    const int lane = tid & 63;
    const int wid  = tid >> 6;
    const int wr = (BM == 128) ? (wid >> 1) : 0;
    const int wc = (BM == 128) ? (wid & 1) : wid;
    const int bm = blockIdx.y * BM, bn = blockIdx.x * BN;
    const int koff = blockIdx.z * K;
    const size_t cz = (size_t)blockIdx.z * M * N;
    const int l15 = lane & 15, lk = lane >> 4;

    f32x4 acc[4][FN];
#pragma unroll
    for (int i = 0; i < 4; ++i)
#pragma unroll
        for (int j = 0; j < FN; ++j) acc[i][j] = (f32x4)0.f;

    for (int kk = 0; kk < K; kk += BK) {
        uint4 va[AL], vb[BL];
#pragma unroll
        for (int i = 0; i < AL; ++i) {
            int c = i * 256 + tid, row = c >> 2, k0 = (c & 3) * 8;
            va[i] = *(const uint4*)(A + (size_t)(bm + row) * lda + koff + kk + k0);
        }
#pragma unroll
        for (int i = 0; i < BL; ++i) {
            int c = i * 256 + tid;
            if ((BN * 4 % 256 == 0) || c < BN * 4) {
                int row = c >> 2, k0 = (c & 3) * 8;
                vb[i] = *(const uint4*)(W + (size_t)(bn + row) * ldw + koff + kk + k0);
            }
        }
        __syncthreads();
#pragma unroll
        for (int i = 0; i < AL; ++i) {
            int c = i * 256 + tid, row = c >> 2, k0 = (c & 3) * 8;
            *(uint4*)&lA[row * LDA + k0] = va[i];
        }
#pragma unroll
        for (int i = 0; i < BL; ++i) {
            int c = i * 256 + tid;
            if ((BN * 4 % 256 == 0) || c < BN * 4) {
                int row = c >> 2, k0 = (c & 3) * 8;
                *(uint4*)&lB[row * LDA + k0] = vb[i];
            }
        }
        __syncthreads();

        bf16x8 af[4], bw[FN];
#pragma unroll
        for (int fm = 0; fm < 4; ++fm)
            af[fm] = *(const bf16x8*)&lA[(wr * 64 + fm * 16 + l15) * LDA + lk * 8];
#pragma unroll
        for (int fn = 0; fn < FN; ++fn)
            bw[fn] = *(const bf16x8*)&lB[(wc * HN + fn * 16 + l15) * LDA + lk * 8];
#pragma unroll
        for (int fm = 0; fm < 4; ++fm)
#pragma unroll
            for (int fn = 0; fn < FN; ++fn)
                acc[fm][fn] = __builtin_amdgcn_mfma_f32_16x16x32_bf16(
                    af[fm], bw[fn], acc[fm][fn], 0, 0, 0);
    }

    if (OUTBF) {
        __syncthreads();
        ushort* cst = smem;
#pragma unroll
        for (int fm = 0; fm < 4; ++fm) {
#pragma unroll
            for (int fn = 0; fn < FN; ++fn) {
                int col = wc * HN + fn * 16 + l15;
                float bv = BIAS ? bias[bn + col] : 0.f;
#pragma unroll
                for (int j = 0; j < 4; ++j) {
                    int row = wr * 64 + fm * 16 + lk * 4 + j;
                    float r = acc[fm][fn][j] + bv;
                    if (ACT == 1) r = (r > 20.f) ? r : log1pf(expf(r));
                    cst[row * (BN + 8) + col] = f2bf(r);
                }
            }
        }
        __syncthreads();
        ushort* Cb = (ushort*)Cv + cz;
        constexpr int NV = BM * BN / 8;
#pragma unroll
        for (int k = 0; k < NV / 256; ++k) {
            int i = k * 256 + tid;
            int row = i / (BN / 8), c8 = i % (BN / 8);
            uint4 v = *(uint4*)&cst[row * (BN + 8) + c8 * 8];
            *(uint4*)&Cb[(size_t)(bm + row) * N + bn + c8 * 8] = v;
        }
    } else {
        float* Cf = (float*)Cv + cz;
#pragma unroll
        for (int fm = 0; fm < 4; ++fm) {
#pragma unroll
            for (int fn = 0; fn < FN; ++fn) {
                int col = bn + wc * HN + fn * 16 + l15;
                float bv = BIAS ? bias[col] : 0.f;
#pragma unroll
                for (int j = 0; j < 4; ++j) {
                    int row = bm + wr * 64 + fm * 16 + lk * 4 + j;
                    float r = acc[fm][fn][j] + bv;
                    if (ACT == 1) r = (r > 20.f) ? r : log1pf(expf(r));
                    float* cp = Cf + (size_t)row * N + col;
                    if (ACCUM) r += *cp;
                    *cp = r;
                }
            }
        }
    }
}

// ---------------- RMSNorm over last dim D=512 ---------------------------------
template<bool BF16OUT>
__global__ __launch_bounds__(256) void rmsnorm_k(
    const float* __restrict__ X, const float* __restrict__ w,
    float* __restrict__ Yf, ushort* __restrict__ Yb)
{
    const int r = blockIdx.x;
    const float* x = X + (size_t)r * D_MODEL;
    float2 v = *(const float2*)(x + threadIdx.x * 2);
    float ss = v.x * v.x + v.y * v.y;
#pragma unroll
    for (int off = 32; off > 0; off >>= 1) ss += __shfl_down(ss, off);
    __shared__ float wsum[4];
    if ((threadIdx.x & 63) == 0) wsum[threadIdx.x >> 6] = ss;
    __syncthreads();
    float tot = wsum[0] + wsum[1] + wsum[2] + wsum[3];
    float rs = rsqrtf(tot * (1.f / D_MODEL) + 1e-5f);
    float2 wv = *(const float2*)(w + threadIdx.x * 2);
    float a = v.x * rs * wv.x, b = v.y * rs * wv.y;
    if (BF16OUT)
        *(ushort2*)(Yb + (size_t)r * D_MODEL + threadIdx.x * 2) =
            make_ushort2(f2bf(a), f2bf(b));
    else
        *(float2*)(Yf + (size_t)r * D_MODEL + threadIdx.x * 2) = make_float2(a, b);
}

// ------- depthwise causal conv1d, rolling window: 4 timesteps per thread ------
__global__ __launch_bounds__(256) void conv_silu_k(
    const ushort* __restrict__ xrb, const float* __restrict__ cw,
    const float* __restrict__ cb, ushort* __restrict__ xsb)
{
    const int idx = blockIdx.x * 256 + threadIdx.x;   // M_ROWS*D_INNER/4 threads
    const int d = idx & (D_INNER - 1);
    const int g = idx >> 10;                          // row group (4 rows)
    const int r0 = g * 4;
    const int l0 = r0 & (LL - 1);
    const ushort* base = xrb + (size_t)r0 * (2 * D_INNER) + d;
    const float4 w = *(const float4*)(cw + d * 4);
    const float bias = cb[d];

    float xm3 = 0.f, xm2 = 0.f, xm1 = 0.f;
    if (l0 != 0) {
        xm3 = bf2f(base[-3 * 2 * D_INNER]);
        xm2 = bf2f(base[-2 * 2 * D_INNER]);
        xm1 = bf2f(base[-1 * 2 * D_INNER]);
    }
    const float v0 = bf2f(base[0]);
    const float v1 = bf2f(base[1 * 2 * D_INNER]);
    const float v2 = bf2f(base[2 * 2 * D_INNER]);
    const float v3 = bf2f(base[3 * 2 * D_INNER]);

    float o0 = bias + xm3 * w.x + xm2 * w.y + xm1 * w.z + v0 * w.w;
    float o1 = bias + xm2 * w.x + xm1 * w.y + v0 * w.z + v1 * w.w;
    float o2 = bias + xm1 * w.x + v0 * w.y + v1 * w.z + v2 * w.w;
    float o3 = bias + v0 * w.x + v1 * w.y + v2 * w.z + v3 * w.w;
    o0 = o0 / (1.f + __expf(-o0));
    o1 = o1 / (1.f + __expf(-o1));
    o2 = o2 / (1.f + __expf(-o2));
    o3 = o3 / (1.f + __expf(-o3));
    ushort* out = xsb + (size_t)r0 * D_INNER + d;
    out[0] = f2bf(o0);
    out[1 * D_INNER] = f2bf(o1);
    out[2 * D_INNER] = f2bf(o2);
    out[3 * D_INNER] = f2bf(o3);
}

// ---------------- selective scan, chunk-parallel, 4 states/thread -------------
// 4 threads per d (j = tid&3, states j*4..j*4+3); d = dblk*64 + (tid>>2).
// Loads batched in 4-step groups (U/V double-buffer) -> ~20 loads in flight.
// Phase 1 stores {P = prod(dA), h_local}; phase 2's fold is exp-free.
__global__ __launch_bounds__(256, 4) void scan1_k(
    const ushort* __restrict__ dltS, const ushort* __restrict__ xsb,
    const float* __restrict__ dbc, const float* __restrict__ A_log,
    float2* __restrict__ cb)
{
    const int b    = blockIdx.x >> 8;
    const int c    = (blockIdx.x >> 4) & 15;
    const int dblk = blockIdx.x & 15;
    const int d = dblk * 64 + (threadIdx.x >> 2);
    const int j = threadIdx.x & 3;

    float A[4];
#pragma unroll
    for (int s = 0; s < 4; ++s) A[s] = -__expf(A_log[d * D_STATE + j * 4 + s]);

    const int r0 = b * LL + c * LC;
    const ushort* pd = dltS + (size_t)r0 * D_INNER + d;
    const ushort* px = xsb  + (size_t)r0 * D_INNER + d;
    const float* pB  = dbc  + (size_t)r0 * 64 + 32 + j * 4;

    float h[4] = {}, P[4] = {1.f, 1.f, 1.f, 1.f};
    float dtU[4], xvU[4], dtV[4], xvV[4];
    float4 BqU[4], BqV[4];

#define LD1(S, L) { \
    _Pragma("unroll") for (int u = 0; u < 4; ++u) { \
        dt##S[u] = bf2f(pd[(size_t)((L) + u) * D_INNER]); \
        xv##S[u] = bf2f(px[(size_t)((L) + u) * D_INNER]); \
        Bq##S[u] = *(const float4*)(pB + (size_t)((L) + u) * 64); \
    } }
#define CP1(S) { \
    _Pragma("unroll") for (int u = 0; u < 4; ++u) { \
        const float dx = dt##S[u] * xv##S[u]; \
        const float e0 = __expf(dt##S[u] * A[0]); \
        const float e1 = __expf(dt##S[u] * A[1]); \
        const float e2 = __expf(dt##S[u] * A[2]); \
        const float e3 = __expf(dt##S[u] * A[3]); \
        P[0] *= e0; h[0] = fmaf(e0, h[0], dx * Bq##S[u].x); \
        P[1] *= e1; h[1] = fmaf(e1, h[1], dx * Bq##S[u].y); \
        P[2] *= e2; h[2] = fmaf(e2, h[2], dx * Bq##S[u].z); \
        P[3] *= e3; h[3] = fmaf(e3, h[3], dx * Bq##S[u].w); \
    } }

    LD1(U, 0)
    for (int l = 0; l < LC; l += 8) {     // tail over-reads stay inside d_ws
        LD1(V, l + 4)
        CP1(U)
        LD1(U, l + 8)
        CP1(V)
    }
#undef LD1
#undef CP1
    float2* cp = cb + ((size_t)(b * NCHUNK + c) * D_INNER + d) * D_STATE + j * 4;
#pragma unroll
    for (int s = 0; s < 4; ++s) cp[s] = make_float2(P[s], h[s]);
}

__global__ __launch_bounds__(256, 3) void scan2_k(
    const ushort* __restrict__ dltS, const ushort* __restrict__ xsb,
    const float* __restrict__ dbc, const ushort* __restrict__ xrb,
    const float* __restrict__ A_log, const float* __restrict__ Dp,
    const float2* __restrict__ cb, ushort* __restrict__ yb)
{
    const int b    = blockIdx.x >> 8;
    const int c    = (blockIdx.x >> 4) & 15;
    const int dblk = blockIdx.x & 15;
    const int d = dblk * 64 + (threadIdx.x >> 2);
    const int j = threadIdx.x & 3;

    float A[4];
#pragma unroll
    for (int s = 0; s < 4; ++s) A[s] = -__expf(A_log[d * D_STATE + j * 4 + s]);
    const float Dd = Dp[d];

    // fold predecessor summaries (P-form: no exp)
    float h[4] = {};
    for (int q = 0; q < NCHUNK - 1; ++q) {
        if (q < c) {
            const float2* cp = cb + ((size_t)(b * NCHUNK + q) * D_INNER + d) * D_STATE + j * 4;
#pragma unroll
            for (int s = 0; s < 4; ++s) {
                float2 v = cp[s];
                h[s] = fmaf(v.x, h[s], v.y);
            }
        }
    }

    const int r0 = b * LL + c * LC;
    const ushort* pd = dltS + (size_t)r0 * D_INNER + d;
    const ushort* px = xsb  + (size_t)r0 * D_INNER + d;
    const float* pB  = dbc  + (size_t)r0 * 64 + 32 + j * 4;
    const float* pC  = dbc  + (size_t)r0 * 64 + 48 + j * 4;
    const ushort* pr = xrb  + (size_t)r0 * 2 * D_INNER + D_INNER + d;
    ushort*      py  = yb   + (size_t)r0 * D_INNER + d;

    float dtU[4], xvU[4], rgU[4], dtV[4], xvV[4], rgV[4];
    float4 BqU[4], CqU[4], BqV[4], CqV[4];

#define LD2(S, L) { \
    _Pragma("unroll") for (int u = 0; u < 4; ++u) { \
        dt##S[u] = bf2f(pd[(size_t)((L) + u) * D_INNER]); \
        xv##S[u] = bf2f(px[(size_t)((L) + u) * D_INNER]); \
        rg##S[u] = bf2f(pr[(size_t)((L) + u) * 2 * D_INNER]); \
        Bq##S[u] = *(const float4*)(pB + (size_t)((L) + u) * 64); \
        Cq##S[u] = *(const float4*)(pC + (size_t)((L) + u) * 64); \
    } }
#define CP2(S, L) { \
    _Pragma("unroll") for (int u = 0; u < 4; ++u) { \
        const float dx = dt##S[u] * xv##S[u]; \
        const float e0 = __expf(dt##S[u] * A[0]); \
        const float e1 = __expf(dt##S[u] * A[1]); \
        const float e2 = __expf(dt##S[u] * A[2]); \
        const float e3 = __expf(dt##S[u] * A[3]); \
        float p; \
        h[0] = fmaf(e0, h[0], dx * Bq##S[u].x); p  = h[0] * Cq##S[u].x; \
        h[1] = fmaf(e1, h[1], dx * Bq##S[u].y); p = fmaf(h[1], Cq##S[u].y, p); \
        h[2] = fmaf(e2, h[2], dx * Bq##S[u].z); p = fmaf(h[2], Cq##S[u].z, p); \
        h[3] = fmaf(e3, h[3], dx * Bq##S[u].w); p = fmaf(h[3], Cq##S[u].w, p); \
        p += __shfl_xor(p, 1); \
        p += __shfl_xor(p, 2); \
        if (j == 0) { \
            const float g = rg##S[u] / (1.f + __expf(-rg##S[u])); \
            py[(size_t)((L) + u) * D_INNER] = f2bf((p + xv##S[u] * Dd) * g); \
        } \
    } }

    LD2(U, 0)
    for (int l = 0; l < LC; l += 8) {     // tail over-reads stay inside d_ws
        LD2(V, l + 4)
        CP2(U, l)
        LD2(U, l + 8)
        CP2(V, l + 4)
    }
#undef LD2
#undef CP2
}

// ---------------- final stats ----------------
__global__ __launch_bounds__(512) void stats_k(
    const float* __restrict__ m, float* __restrict__ out)
{
    const int b = blockIdx.x;
    const int dm = threadIdx.x;
    const float* p = m + (size_t)b * LL * D_MODEL + dm;
    float s = 0.f;
    for (int l = 0; l < LL; ++l) s += p[(size_t)l * D_MODEL];
    const float mean = s * (1.f / LL);
    float ss = 0.f;
    for (int l = 0; l < LL; ++l) {
        float v = p[(size_t)l * D_MODEL] - mean;
        ss += v * v;
    }
    out[b * (2 * D_MODEL) + dm] = mean;
    out[b * (2 * D_MODEL) + D_MODEL + dm] = sqrtf(ss * (1.f / (LL - 1)));
}

// ---------------- host ----------------
extern "C" void kernel_launch(void* const* d_in, const int* in_sizes, int n_in,
                              void* d_out, int out_size, void* d_ws, size_t ws_size,
                              hipStream_t stream) {
    const float* x            = (const float*)d_in[0];
    const float* proj_w       = (const float*)d_in[1];
    const float* proj_b       = (const float*)d_in[2];
    const float* norm_w       = (const float*)d_in[3];
    const float* in_w         = (const float*)d_in[4];
    const float* conv_w       = (const float*)d_in[5];
    const float* conv_b       = (const float*)d_in[6];
    const float* xproj_w      = (const float*)d_in[7];
    const float* dt_w         = (const float*)d_in[8];
    const float* dt_b         = (const float*)d_in[9];
    const float* A_log        = (const float*)d_in[10];
    const float* Dp           = (const float*)d_in[11];
    const float* out_w        = (const float*)d_in[12];
    const float* final_norm_w = (const float*)d_in[13];

    // fp32 region
    float* ws    = (float*)d_ws;
    float* h     = ws;                                  // 4096*512
    float* dbc   = h    + (size_t)M_ROWS * D_MODEL;     // 4096*64
    float* dpart = dbc  + (size_t)M_ROWS * 64;          // 4*4096*64
    // bf16 region
    ushort* xyb   = (ushort*)(dpart + (size_t)4 * M_ROWS * 64); // 4096*1280 (x, then y)
    ushort* xnb   = xyb   + (size_t)M_ROWS * D_IN;      // 4096*512
    ushort* xrb   = xnb   + (size_t)M_ROWS * D_MODEL;   // 4096*2048 (also fp32 fnorm alias)
    ushort* xsb   = xrb   + (size_t)M_ROWS * 2 * D_INNER; // 4096*1024
    ushort* dltS  = xsb   + (size_t)M_ROWS * D_INNER;   // 4096*1024 (bf16 softplus dt)
    ushort* dltb  = dltS  + (size_t)M_ROWS * D_INNER;   // 4096*32
    ushort* pwb   = dltb  + (size_t)M_ROWS * DT_RANK;   // 512*1280
    ushort* iwb4  = pwb   + (size_t)D_MODEL * D_IN;     // 4*2048*512
    ushort* owb4  = iwb4  + (size_t)N_LAYER * 2 * D_INNER * D_MODEL; // 4*512*1024
    ushort* xpwb4 = owb4  + (size_t)N_LAYER * D_MODEL * D_INNER;     // 4*64*1024
    ushort* dtwb4 = xpwb4 + (size_t)N_LAYER * 64 * D_INNER;          // 4*1024*32
    float2* cbuf  = (float2*)(dtwb4 + (size_t)N_LAYER * D_INNER * DT_RANK); // 16.8MB
    float* fnorm  = (float*)xrb;                        // alias (xrb dead at final norm)

    // ---- one-time casts ----
    cast_bf16_k<<<(M_ROWS * D_IN / 4 + 255) / 256, 256, 0, stream>>>(x, xyb, M_ROWS * D_IN / 4);
    cast_bf16_k<<<(D_MODEL * D_IN / 4 + 255) / 256, 256, 0, stream>>>(proj_w, pwb, D_MODEL * D_IN / 4);
    cast_bf16_k<<<(N_LAYER * 2 * D_INNER * D_MODEL / 4 + 255) / 256, 256, 0, stream>>>(
        in_w, iwb4, N_LAYER * 2 * D_INNER * D_MODEL / 4);
    cast_bf16_k<<<(N_LAYER * D_MODEL * D_INNER / 4 + 255) / 256, 256, 0, stream>>>(
        out_w, owb4, N_LAYER * D_MODEL * D_INNER / 4);
    cast_bf16_k<<<(N_LAYER * 64 * D_INNER / 4 + 255) / 256, 256, 0, stream>>>(
        xproj_w, xpwb4, N_LAYER * 64 * D_INNER / 4);
    cast_bf16_k<<<(N_LAYER * D_INNER * DT_RANK / 4 + 255) / 256, 256, 0, stream>>>(
        dt_w, dtwb4, N_LAYER * D_INNER * DT_RANK / 4);

    // h = x @ proj_w^T + proj_b   (m97 structure, BN=64)
    gemm_gl<64, D_MODEL, D_IN, true, false, false>
        <<<dim3(D_MODEL / 64, M_ROWS / 128), 256, 0, stream>>>(xyb, pwb, proj_b, h);

    for (int i = 0; i < N_LAYER; ++i) {
        const ushort* iwb  = iwb4  + (size_t)i * 2 * D_INNER * D_MODEL;
        const ushort* owb  = owb4  + (size_t)i * D_MODEL * D_INNER;
        const ushort* xpwb = xpwb4 + (size_t)i * 64 * D_INNER;
        const ushort* dtwb = dtwb4 + (size_t)i * D_INNER * DT_RANK;

        rmsnorm_k<true><<<M_ROWS, 256, 0, stream>>>(h, norm_w + (size_t)i * D_MODEL, nullptr, xnb);

        // xr(bf16) = xn @ in_w^T   (m97 structure, BN=128)
        gemm_gl<128, 2 * D_INNER, D_MODEL, false, false, true>
            <<<dim3(2 * D_INNER / 128, M_ROWS / 128), 256, 0, stream>>>(xnb, iwb, nullptr, xrb);

        conv_silu_k<<<M_ROWS * D_INNER / 4 / 256, 256, 0, stream>>>(
            xrb, conv_w + (size_t)i * D_INNER * D_CONV, conv_b + (size_t)i * D_INNER, xsb);

        // dbc partials = xs @ xproj_w^T, split-K=4
        gemm_bf16<128, 32, false, false, 0, false><<<dim3(2, M_ROWS / 128, 4), 256, 0, stream>>>(
            xsb, xpwb, nullptr, dpart, M_ROWS, 64, D_INNER / 4, D_INNER, D_INNER);
        reduce_dbc_k<<<M_ROWS * 64 / 256, 256, 0, stream>>>(dpart, dbc, dltb);

        // dltS(bf16) = softplus(delta @ dt_w^T + dt_b)
        gemm_bf16<64, 64, true, false, 1, true><<<dim3(D_INNER / 64, M_ROWS / 64), 256, 0, stream>>>(
            dltb, dtwb, dt_b + (size_t)i * D_INNER, dltS, M_ROWS, D_INNER, DT_RANK, DT_RANK, DT_RANK);

        scan1_k<<<BB * NCHUNK * (D_INNER / 64), 256, 0, stream>>>(
            dltS, xsb, dbc, A_log + (size_t)i * D_INNER * D_STATE, cbuf);
        scan2_k<<<BB * NCHUNK * (D_INNER / 64), 256, 0, stream>>>(
            dltS, xsb, dbc, xrb, A_log + (size_t)i * D_INNER * D_STATE,
            Dp + (size_t)i * D_INNER, cbuf, xyb);

        // h += y @ out_w^T   (m97 structure, BN=64)
        gemm_gl<64, D_MODEL, D_INNER, false, true, false>
            <<<dim3(D_MODEL / 64, M_ROWS / 128), 256, 0, stream>>>(xyb, owb, nullptr, h);
    }

    rmsnorm_k<false><<<M_ROWS, 256, 0, stream>>>(h, final_norm_w, fnorm, nullptr);
    stats_k<<<BB, D_MODEL, 0, stream>>>(fnorm, (float*)d_out);
}

// Round 14
// 583.549 us; speedup vs baseline: 7.7013x; 1.0339x over previous
//
#include <hip/hip_runtime.h>
#include <math.h>

// ---------------- dims (fixed by the problem) ----------------
#define D_IN     1280
#define D_MODEL  512
#define N_LAYER  4
#define D_STATE  16
#define D_CONV   4
#define D_INNER  1024
#define DT_RANK  32
#define BB       8
#define LL       512
#define M_ROWS   (BB*LL)          // 4096
#define NCHUNK   16
#define LC       (LL/NCHUNK)      // 32

typedef short bf16x8 __attribute__((ext_vector_type(8)));
typedef float f32x4  __attribute__((ext_vector_type(4)));

__device__ __forceinline__ ushort f2bf(float f) {
    unsigned u = __float_as_uint(f);
    u = (u + 0x7FFF + ((u >> 16) & 1)) >> 16;   // RNE
    return (ushort)u;
}
__device__ __forceinline__ float bf2f(ushort u) {
    return __uint_as_float((unsigned)u << 16);
}

// ---------------- fp32 -> bf16 cast (n multiple of 4) ----------------
__global__ __launch_bounds__(256) void cast_bf16_k(
    const float* __restrict__ in, ushort* __restrict__ out, int n4)
{
    int i = blockIdx.x * 256 + threadIdx.x;
    if (i < n4) {
        float4 v = *(const float4*)(in + (size_t)i * 4);
        *(ushort4*)(out + (size_t)i * 4) =
            make_ushort4(f2bf(v.x), f2bf(v.y), f2bf(v.z), f2bf(v.w));
    }
}

// ---- split-K reduce for dbc: sum 4 partials; also emit delta cols as bf16 ----
__global__ __launch_bounds__(256) void reduce_dbc_k(
    const float* __restrict__ part, float* __restrict__ dbc,
    ushort* __restrict__ dltb)
{
    const int i = blockIdx.x * 256 + threadIdx.x;   // over 4096*64
    const int c = i & 63;
    float s = part[i] + part[i + M_ROWS * 64] + part[i + 2 * M_ROWS * 64]
            + part[i + 3 * M_ROWS * 64];
    dbc[i] = s;
    if (c < 32) dltb[(i >> 6) * 32 + c] = f2bf(s);
}

// ============ m97-structure GEMM: 128xBN tile, BK=32, global_load_lds =========
template<int BN, int NDIM, int KDIM, bool BIAS, bool ACCUM, bool OUTBF>
__global__ __launch_bounds__(256) void gemm_gl(
    const ushort* __restrict__ A, const ushort* __restrict__ W,
    const float* __restrict__ bias, void* __restrict__ Cv)
{
    constexpr int BM = 128, BK = 32;
    constexpr int ACH = BM / 16;
    constexpr int TC  = (BM + BN) / 16;
    constexpr int PW  = TC / 4;
    constexpr int HN  = BN / 2;
    constexpr int FN  = BN / 32;
    constexpr int SM_STAGE = (BM + BN) * BK;
    constexpr int SM_C = OUTBF ? BM * (BN + 8) : 0;
    constexpr int SM = (SM_STAGE > SM_C) ? SM_STAGE : SM_C;
    __shared__ ushort smem[SM];
    ushort* lA = smem;
    ushort* lB = smem + BM * BK;
    const int tid = threadIdx.x, lane = tid & 63, wid = tid >> 6;
    const int wr = wid >> 1, wc = wid & 1;
    const int bm = blockIdx.y * BM, bn = blockIdx.x * BN;
    const int l15 = lane & 15, lk = lane >> 4;
    const int srow = lane >> 2, scol = (lane & 3) * 8;

    f32x4 acc[4][FN];
#pragma unroll
    for (int i = 0; i < 4; ++i)
#pragma unroll
        for (int j = 0; j < FN; ++j) acc[i][j] = (f32x4)0.f;

    for (int kk = 0; kk < KDIM; kk += BK) {
#pragma unroll
        for (int i = 0; i < PW; ++i) {
            const int ch = wid * PW + i;
            const ushort* g = (ch < ACH)
                ? A + (size_t)(bm + ch * 16 + srow) * KDIM + kk + scol
                : W + (size_t)(bn + (ch - ACH) * 16 + srow) * KDIM + kk + scol;
            __builtin_amdgcn_global_load_lds(
                (const __attribute__((address_space(1))) void*)g,
                (__attribute__((address_space(3))) void*)(smem + ch * 512), 16, 0, 0);
        }
        __syncthreads();

        bf16x8 af[4], bw[FN];
#pragma unroll
        for (int fm = 0; fm < 4; ++fm)
            af[fm] = *(const bf16x8*)&lA[(wr * 64 + fm * 16 + l15) * BK + lk * 8];
#pragma unroll
        for (int fn = 0; fn < FN; ++fn)
            bw[fn] = *(const bf16x8*)&lB[(wc * HN + fn * 16 + l15) * BK + lk * 8];
#pragma unroll
        for (int fm = 0; fm < 4; ++fm)
#pragma unroll
            for (int fn = 0; fn < FN; ++fn)
                acc[fm][fn] = __builtin_amdgcn_mfma_f32_16x16x32_bf16(
                    af[fm], bw[fn], acc[fm][fn], 0, 0, 0);
        __syncthreads();
    }

    if (OUTBF) {
        ushort* cst = smem;
#pragma unroll
        for (int fm = 0; fm < 4; ++fm) {
#pragma unroll
            for (int fn = 0; fn < FN; ++fn) {
                const int col = wc * HN + fn * 16 + l15;
                const float bv = BIAS ? bias[bn + col] : 0.f;
#pragma unroll
                for (int j = 0; j < 4; ++j) {
                    const int row = wr * 64 + fm * 16 + lk * 4 + j;
                    cst[row * (BN + 8) + col] = f2bf(acc[fm][fn][j] + bv);
                }
            }
        }
        __syncthreads();
        ushort* Cb = (ushort*)Cv;
        constexpr int NV = BM * BN / 8;
#pragma unroll
        for (int k = 0; k < NV / 256; ++k) {
            const int i = k * 256 + tid;
            const int row = i / (BN / 8), c8 = i % (BN / 8);
            *(uint4*)&Cb[(size_t)(bm + row) * NDIM + bn + c8 * 8] =
                *(uint4*)&cst[row * (BN + 8) + c8 * 8];
        }
    } else {
        float* Cf = (float*)Cv;
#pragma unroll
        for (int fm = 0; fm < 4; ++fm) {
#pragma unroll
            for (int fn = 0; fn < FN; ++fn) {
                const int col = bn + wc * HN + fn * 16 + l15;
                const float bv = BIAS ? bias[col] : 0.f;
#pragma unroll
                for (int j = 0; j < 4; ++j) {
                    const int row = bm + wr * 64 + fm * 16 + lk * 4 + j;
                    float r = acc[fm][fn][j] + bv;
                    float* cp = Cf + (size_t)row * NDIM + col;
                    if (ACCUM) r += *cp;
                    *cp = r;
                }
            }
        }
    }
}

// ---------------- bf16 MFMA GEMM (reg-staged; small shapes) -------------------
template<int BM, int BN, bool BIAS, bool ACCUM, int ACT, bool OUTBF>
__global__ __launch_bounds__(256) void gemm_bf16(
    const ushort* __restrict__ A, const ushort* __restrict__ W,
    const float* __restrict__ bias, void* __restrict__ Cv,
    int M, int N, int K, int lda, int ldw)
{
    constexpr int BK = 32;
    constexpr int LDA = BK + 8;
    constexpr int WC = (BM == 128) ? 2 : 4;
    constexpr int HN = BN / WC;
    constexpr int FN = HN / 16;
    constexpr int AL = BM / 64;
    constexpr int BL = (BN * 4 + 255) / 256;
    constexpr int SM_G = (BM + BN) * LDA;
    constexpr int SM_C = OUTBF ? BM * (BN + 8) : 0;
    constexpr int SM   = (SM_G > SM_C) ? SM_G : SM_C;
    __shared__ ushort smem[SM];
    ushort* lA = smem;
    ushort* lB = smem + BM * LDA;
    const int tid  = threadIdx.x;
    const int lane = tid & 63;
    const int wid  = tid >> 6;
    const int wr = (BM == 128) ? (wid >> 1) : 0;
    const int wc = (BM == 128) ? (wid & 1) : wid;
    const int bm = blockIdx.y * BM, bn = blockIdx.x * BN;
    const int koff = blockIdx.z * K;
    const size_t cz = (size_t)blockIdx.z * M * N;
    const int l15 = lane & 15, lk = lane >> 4;

    f32x4 acc[4][FN];
#pragma unroll
    for (int i = 0; i < 4; ++i)
#pragma unroll
        for (int j = 0; j < FN; ++j) acc[i][j] = (f32x4)0.f;

    for (int kk = 0; kk < K; kk += BK) {
        uint4 va[AL], vb[BL];
#pragma unroll
        for (int i = 0; i < AL; ++i) {
            int c = i * 256 + tid, row = c >> 2, k0 = (c & 3) * 8;
            va[i] = *(const uint4*)(A + (size_t)(bm + row) * lda + koff + kk + k0);
        }
#pragma unroll
        for (int i = 0; i < BL; ++i) {
            int c = i * 256 + tid;
            if ((BN * 4 % 256 == 0) || c < BN * 4) {
                int row = c >> 2, k0 = (c & 3) * 8;
                vb[i] = *(const uint4*)(W + (size_t)(bn + row) * ldw + koff + kk + k0);
            }
        }
        __syncthreads();
#pragma unroll
        for (int i = 0; i < AL; ++i) {
            int c = i * 256 + tid, row = c >> 2, k0 = (c & 3) * 8;
            *(uint4*)&lA[row * LDA + k0] = va[i];
        }
#pragma unroll
        for (int i = 0; i < BL; ++i) {
            int c = i * 256 + tid;
            if ((BN * 4 % 256 == 0) || c < BN * 4) {
                int row = c >> 2, k0 = (c & 3) * 8;
                *(uint4*)&lB[row * LDA + k0] = vb[i];
            }
        }
        __syncthreads();

        bf16x8 af[4], bw[FN];
#pragma unroll
        for (int fm = 0; fm < 4; ++fm)
            af[fm] = *(const bf16x8*)&lA[(wr * 64 + fm * 16 + l15) * LDA + lk * 8];
#pragma unroll
        for (int fn = 0; fn < FN; ++fn)
            bw[fn] = *(const bf16x8*)&lB[(wc * HN + fn * 16 + l15) * LDA + lk * 8];
#pragma unroll
        for (int fm = 0; fm < 4; ++fm)
#pragma unroll
            for (int fn = 0; fn < FN; ++fn)
                acc[fm][fn] = __builtin_amdgcn_mfma_f32_16x16x32_bf16(
                    af[fm], bw[fn], acc[fm][fn], 0, 0, 0);
    }

    if (OUTBF) {
        __syncthreads();
        ushort* cst = smem;
#pragma unroll
        for (int fm = 0; fm < 4; ++fm) {
#pragma unroll
            for (int fn = 0; fn < FN; ++fn) {
                int col = wc * HN + fn * 16 + l15;
                float bv = BIAS ? bias[bn + col] : 0.f;
#pragma unroll
                for (int j = 0; j < 4; ++j) {
                    int row = wr * 64 + fm * 16 + lk * 4 + j;
                    float r = acc[fm][fn][j] + bv;
                    if (ACT == 1) r = (r > 20.f) ? r : log1pf(expf(r));
                    cst[row * (BN + 8) + col] = f2bf(r);
                }
            }
        }
        __syncthreads();
        ushort* Cb = (ushort*)Cv + cz;
        constexpr int NV = BM * BN / 8;
#pragma unroll
        for (int k = 0; k < NV / 256; ++k) {
            int i = k * 256 + tid;
            int row = i / (BN / 8), c8 = i % (BN / 8);
            uint4 v = *(uint4*)&cst[row * (BN + 8) + c8 * 8];
            *(uint4*)&Cb[(size_t)(bm + row) * N + bn + c8 * 8] = v;
        }
    } else {
        float* Cf = (float*)Cv + cz;
#pragma unroll
        for (int fm = 0; fm < 4; ++fm) {
#pragma unroll
            for (int fn = 0; fn < FN; ++fn) {
                int col = bn + wc * HN + fn * 16 + l15;
                float bv = BIAS ? bias[col] : 0.f;
#pragma unroll
                for (int j = 0; j < 4; ++j) {
                    int row = bm + wr * 64 + fm * 16 + lk * 4 + j;
                    float r = acc[fm][fn][j] + bv;
                    if (ACT == 1) r = (r > 20.f) ? r : log1pf(expf(r));
                    float* cp = Cf + (size_t)row * N + col;
                    if (ACCUM) r += *cp;
                    *cp = r;
                }
            }
        }
    }
}

// ---------------- RMSNorm over last dim D=512 ---------------------------------
template<bool BF16OUT>
__global__ __launch_bounds__(256) void rmsnorm_k(
    const float* __restrict__ X, const float* __restrict__ w,
    float* __restrict__ Yf, ushort* __restrict__ Yb)
{
    const int r = blockIdx.x;
    const float* x = X + (size_t)r * D_MODEL;
    float2 v = *(const float2*)(x + threadIdx.x * 2);
    float ss = v.x * v.x + v.y * v.y;
#pragma unroll
    for (int off = 32; off > 0; off >>= 1) ss += __shfl_down(ss, off);
    __shared__ float wsum[4];
    if ((threadIdx.x & 63) == 0) wsum[threadIdx.x >> 6] = ss;
    __syncthreads();
    float tot = wsum[0] + wsum[1] + wsum[2] + wsum[3];
    float rs = rsqrtf(tot * (1.f / D_MODEL) + 1e-5f);
    float2 wv = *(const float2*)(w + threadIdx.x * 2);
    float a = v.x * rs * wv.x, b = v.y * rs * wv.y;
    if (BF16OUT)
        *(ushort2*)(Yb + (size_t)r * D_MODEL + threadIdx.x * 2) =
            make_ushort2(f2bf(a), f2bf(b));
    else
        *(float2*)(Yf + (size_t)r * D_MODEL + threadIdx.x * 2) = make_float2(a, b);
}

// ------- depthwise causal conv1d, rolling window: 4 timesteps per thread ------
__global__ __launch_bounds__(256) void conv_silu_k(
    const ushort* __restrict__ xrb, const float* __restrict__ cw,
    const float* __restrict__ cb, ushort* __restrict__ xsb)
{
    const int idx = blockIdx.x * 256 + threadIdx.x;   // M_ROWS*D_INNER/4 threads
    const int d = idx & (D_INNER - 1);
    const int g = idx >> 10;                          // row group (4 rows)
    const int r0 = g * 4;
    const int l0 = r0 & (LL - 1);
    const ushort* base = xrb + (size_t)r0 * (2 * D_INNER) + d;
    const float4 w = *(const float4*)(cw + d * 4);
    const float bias = cb[d];

    float xm3 = 0.f, xm2 = 0.f, xm1 = 0.f;
    if (l0 != 0) {
        xm3 = bf2f(base[-3 * 2 * D_INNER]);
        xm2 = bf2f(base[-2 * 2 * D_INNER]);
        xm1 = bf2f(base[-1 * 2 * D_INNER]);
    }
    const float v0 = bf2f(base[0]);
    const float v1 = bf2f(base[1 * 2 * D_INNER]);
    const float v2 = bf2f(base[2 * 2 * D_INNER]);
    const float v3 = bf2f(base[3 * 2 * D_INNER]);

    float o0 = bias + xm3 * w.x + xm2 * w.y + xm1 * w.z + v0 * w.w;
    float o1 = bias + xm2 * w.x + xm1 * w.y + v0 * w.z + v1 * w.w;
    float o2 = bias + xm1 * w.x + v0 * w.y + v1 * w.z + v2 * w.w;
    float o3 = bias + v0 * w.x + v1 * w.y + v2 * w.z + v3 * w.w;
    o0 = o0 / (1.f + __expf(-o0));
    o1 = o1 / (1.f + __expf(-o1));
    o2 = o2 / (1.f + __expf(-o2));
    o3 = o3 / (1.f + __expf(-o3));
    ushort* out = xsb + (size_t)r0 * D_INNER + d;
    out[0] = f2bf(o0);
    out[1 * D_INNER] = f2bf(o1);
    out[2 * D_INNER] = f2bf(o2);
    out[3 * D_INNER] = f2bf(o3);
}

// ---------------- selective scan, chunk-parallel, LDS-staged ------------------
// Block = (b, c, dblk): 64 d x LC=32 steps. Stage the full chunk into LDS with
// coalesced uint4 loads (one barrier), then run the recurrence out of LDS.
// Thread: d = tid>>2 (local), j = tid&3 (states j*4..j*4+3).
// Phase 1 stores {P = prod(dA), h_local}; phase 2's fold is exp-free.
__global__ __launch_bounds__(256) void scan1_k(
    const ushort* __restrict__ dltS, const ushort* __restrict__ xsb,
    const float* __restrict__ dbc, const float* __restrict__ A_log,
    float2* __restrict__ cb)
{
    const int b    = blockIdx.x >> 8;
    const int c    = (blockIdx.x >> 4) & 15;
    const int dblk = blockIdx.x & 15;
    const int d0   = dblk * 64;
    const int tid  = threadIdx.x;
    const int d    = tid >> 2;
    const int j    = tid & 3;

    __shared__ float sd[LC][64];
    __shared__ float sx[LC][64];
    __shared__ float sB[LC][16];

    const int r0 = b * LL + c * LC;
    {
        const int row = tid >> 3;
        const int q8  = (tid & 7) * 8;
        uint4 v1 = *(const uint4*)(dltS + (size_t)(r0 + row) * D_INNER + d0 + q8);
        uint4 v2 = *(const uint4*)(xsb  + (size_t)(r0 + row) * D_INNER + d0 + q8);
        const int qf = tid & 7;
        float4 bc;
        if (qf < 4) bc = *(const float4*)(dbc + (size_t)(r0 + row) * 64 + 32 + qf * 4);
        const ushort* p1 = (const ushort*)&v1;
        const ushort* p2 = (const ushort*)&v2;
#pragma unroll
        for (int u = 0; u < 8; ++u) {
            sd[row][q8 + u] = bf2f(p1[u]);
            sx[row][q8 + u] = bf2f(p2[u]);
        }
        if (qf < 4) *(float4*)&sB[row][qf * 4] = bc;
    }
    __syncthreads();

    float A[4];
#pragma unroll
    for (int s = 0; s < 4; ++s) A[s] = -__expf(A_log[(d0 + d) * D_STATE + j * 4 + s]);

    float h[4] = {}, P[4] = {1.f, 1.f, 1.f, 1.f};
#pragma unroll
    for (int l = 0; l < LC; ++l) {
        const float dt = sd[l][d];
        const float dx = dt * sx[l][d];
        const float4 Bv = *(const float4*)&sB[l][j * 4];
        const float e0 = __expf(dt * A[0]);
        const float e1 = __expf(dt * A[1]);
        const float e2 = __expf(dt * A[2]);
        const float e3 = __expf(dt * A[3]);
        P[0] *= e0; h[0] = fmaf(e0, h[0], dx * Bv.x);
        P[1] *= e1; h[1] = fmaf(e1, h[1], dx * Bv.y);
        P[2] *= e2; h[2] = fmaf(e2, h[2], dx * Bv.z);
        P[3] *= e3; h[3] = fmaf(e3, h[3], dx * Bv.w);
    }
    float2* cp = cb + ((size_t)(b * NCHUNK + c) * D_INNER + d0 + d) * D_STATE + j * 4;
#pragma unroll
    for (int s = 0; s < 4; ++s) cp[s] = make_float2(P[s], h[s]);
}

__global__ __launch_bounds__(256) void scan2_k(
    const ushort* __restrict__ dltS, const ushort* __restrict__ xsb,
    const float* __restrict__ dbc, const ushort* __restrict__ xrb,
    const float* __restrict__ A_log, const float* __restrict__ Dp,
    const float2* __restrict__ cb, ushort* __restrict__ yb)
{
    const int b    = blockIdx.x >> 8;
    const int c    = (blockIdx.x >> 4) & 15;
    const int dblk = blockIdx.x & 15;
    const int d0   = dblk * 64;
    const int tid  = threadIdx.x;
    const int d    = tid >> 2;
    const int j    = tid & 3;

    __shared__ float  sd[LC][64];
    __shared__ float  sx[LC][64];
    __shared__ float  sr[LC][64];
    __shared__ float  sB[LC][16];
    __shared__ float  sC[LC][16];
    __shared__ ushort sy[LC][64];

    const int r0 = b * LL + c * LC;
    {
        const int row = tid >> 3;
        const int q8  = (tid & 7) * 8;
        uint4 v1 = *(const uint4*)(dltS + (size_t)(r0 + row) * D_INNER + d0 + q8);
        uint4 v2 = *(const uint4*)(xsb  + (size_t)(r0 + row) * D_INNER + d0 + q8);
        uint4 v3 = *(const uint4*)(xrb  + (size_t)(r0 + row) * 2 * D_INNER + D_INNER + d0 + q8);
        const int qf = tid & 7;
        float4 bc = *(const float4*)(dbc + (size_t)(r0 + row) * 64 + 32 + qf * 4);
        const ushort* p1 = (const ushort*)&v1;
        const ushort* p2 = (const ushort*)&v2;
        const ushort* p3 = (const ushort*)&v3;
#pragma unroll
        for (int u = 0; u < 8; ++u) {
            sd[row][q8 + u] = bf2f(p1[u]);
            sx[row][q8 + u] = bf2f(p2[u]);
            sr[row][q8 + u] = bf2f(p3[u]);
        }
        if (qf < 4) *(float4*)&sB[row][qf * 4] = bc;
        else        *(float4*)&sC[row][(qf - 4) * 4] = bc;
    }
    __syncthreads();

    float A[4];
#pragma unroll
    for (int s = 0; s < 4; ++s) A[s] = -__expf(A_log[(d0 + d) * D_STATE + j * 4 + s]);
    const float Dd = Dp[d0 + d];

    // fold predecessor summaries (P-form: no exp)
    float h[4] = {};
    for (int q = 0; q < NCHUNK - 1; ++q) {
        if (q < c) {
            const float2* cp = cb + ((size_t)(b * NCHUNK + q) * D_INNER + d0 + d) * D_STATE + j * 4;
#pragma unroll
            for (int s = 0; s < 4; ++s) {
                float2 v = cp[s];
                h[s] = fmaf(v.x, h[s], v.y);
            }
        }
    }

#pragma unroll
    for (int l = 0; l < LC; ++l) {
        const float dt = sd[l][d];
        const float xv = sx[l][d];
        const float dx = dt * xv;
        const float4 Bv = *(const float4*)&sB[l][j * 4];
        const float4 Cvv = *(const float4*)&sC[l][j * 4];
        const float e0 = __expf(dt * A[0]);
        const float e1 = __expf(dt * A[1]);
        const float e2 = __expf(dt * A[2]);
        const float e3 = __expf(dt * A[3]);
        float p;
        h[0] = fmaf(e0, h[0], dx * Bv.x); p  = h[0] * Cvv.x;
        h[1] = fmaf(e1, h[1], dx * Bv.y); p = fmaf(h[1], Cvv.y, p);
        h[2] = fmaf(e2, h[2], dx * Bv.z); p = fmaf(h[2], Cvv.z, p);
        h[3] = fmaf(e3, h[3], dx * Bv.w); p = fmaf(h[3], Cvv.w, p);
        p += __shfl_xor(p, 1);
        p += __shfl_xor(p, 2);
        if (j == 0) {
            const float rg = sr[l][d];
            const float g = rg / (1.f + __expf(-rg));
            sy[l][d] = f2bf((p + xv * Dd) * g);
        }
    }
    __syncthreads();
    {
        const int row = tid >> 3;
        const int q8  = (tid & 7) * 8;
        uint4 v;
        ushort* pv = (ushort*)&v;
#pragma unroll
        for (int u = 0; u < 8; ++u) pv[u] = sy[row][q8 + u];
        *(uint4*)(yb + (size_t)(r0 + row) * D_INNER + d0 + q8) = v;
    }
}

// ---------------- final stats ----------------
__global__ __launch_bounds__(512) void stats_k(
    const float* __restrict__ m, float* __restrict__ out)
{
    const int b = blockIdx.x;
    const int dm = threadIdx.x;
    const float* p = m + (size_t)b * LL * D_MODEL + dm;
    float s = 0.f;
    for (int l = 0; l < LL; ++l) s += p[(size_t)l * D_MODEL];
    const float mean = s * (1.f / LL);
    float ss = 0.f;
    for (int l = 0; l < LL; ++l) {
        float v = p[(size_t)l * D_MODEL] - mean;
        ss += v * v;
    }
    out[b * (2 * D_MODEL) + dm] = mean;
    out[b * (2 * D_MODEL) + D_MODEL + dm] = sqrtf(ss * (1.f / (LL - 1)));
}

// ---------------- host ----------------
extern "C" void kernel_launch(void* const* d_in, const int* in_sizes, int n_in,
                              void* d_out, int out_size, void* d_ws, size_t ws_size,
                              hipStream_t stream) {
    const float* x            = (const float*)d_in[0];
    const float* proj_w       = (const float*)d_in[1];
    const float* proj_b       = (const float*)d_in[2];
    const float* norm_w       = (const float*)d_in[3];
    const float* in_w         = (const float*)d_in[4];
    const float* conv_w       = (const float*)d_in[5];
    const float* conv_b       = (const float*)d_in[6];
    const float* xproj_w      = (const float*)d_in[7];
    const float* dt_w         = (const float*)d_in[8];
    const float* dt_b         = (const float*)d_in[9];
    const float* A_log        = (const float*)d_in[10];
    const float* Dp           = (const float*)d_in[11];
    const float* out_w        = (const float*)d_in[12];
    const float* final_norm_w = (const float*)d_in[13];

    // fp32 region
    float* ws    = (float*)d_ws;
    float* h     = ws;                                  // 4096*512
    float* dbc   = h    + (size_t)M_ROWS * D_MODEL;     // 4096*64
    float* dpart = dbc  + (size_t)M_ROWS * 64;          // 4*4096*64
    // bf16 region
    ushort* xyb   = (ushort*)(dpart + (size_t)4 * M_ROWS * 64); // 4096*1280 (x, then y)
    ushort* xnb   = xyb   + (size_t)M_ROWS * D_IN;      // 4096*512
    ushort* xrb   = xnb   + (size_t)M_ROWS * D_MODEL;   // 4096*2048 (also fp32 fnorm alias)
    ushort* xsb   = xrb   + (size_t)M_ROWS * 2 * D_INNER; // 4096*1024
    ushort* dltS  = xsb   + (size_t)M_ROWS * D_INNER;   // 4096*1024 (bf16 softplus dt)
    ushort* dltb  = dltS  + (size_t)M_ROWS * D_INNER;   // 4096*32
    ushort* pwb   = dltb  + (size_t)M_ROWS * DT_RANK;   // 512*1280
    ushort* iwb4  = pwb   + (size_t)D_MODEL * D_IN;     // 4*2048*512
    ushort* owb4  = iwb4  + (size_t)N_LAYER * 2 * D_INNER * D_MODEL; // 4*512*1024
    ushort* xpwb4 = owb4  + (size_t)N_LAYER * D_MODEL * D_INNER;     // 4*64*1024
    ushort* dtwb4 = xpwb4 + (size_t)N_LAYER * 64 * D_INNER;          // 4*1024*32
    float2* cbuf  = (float2*)(dtwb4 + (size_t)N_LAYER * D_INNER * DT_RANK); // 16.8MB
    float* fnorm  = (float*)xrb;                        // alias (xrb dead at final norm)

    // ---- one-time casts ----
    cast_bf16_k<<<(M_ROWS * D_IN / 4 + 255) / 256, 256, 0, stream>>>(x, xyb, M_ROWS * D_IN / 4);
    cast_bf16_k<<<(D_MODEL * D_IN / 4 + 255) / 256, 256, 0, stream>>>(proj_w, pwb, D_MODEL * D_IN / 4);
    cast_bf16_k<<<(N_LAYER * 2 * D_INNER * D_MODEL / 4 + 255) / 256, 256, 0, stream>>>(
        in_w, iwb4, N_LAYER * 2 * D_INNER * D_MODEL / 4);
    cast_bf16_k<<<(N_LAYER * D_MODEL * D_INNER / 4 + 255) / 256, 256, 0, stream>>>(
        out_w, owb4, N_LAYER * D_MODEL * D_INNER / 4);
    cast_bf16_k<<<(N_LAYER * 64 * D_INNER / 4 + 255) / 256, 256, 0, stream>>>(
        xproj_w, xpwb4, N_LAYER * 64 * D_INNER / 4);
    cast_bf16_k<<<(N_LAYER * D_INNER * DT_RANK / 4 + 255) / 256, 256, 0, stream>>>(
        dt_w, dtwb4, N_LAYER * D_INNER * DT_RANK / 4);

    // h = x @ proj_w^T + proj_b   (m97 structure, BN=64)
    gemm_gl<64, D_MODEL, D_IN, true, false, false>
        <<<dim3(D_MODEL / 64, M_ROWS / 128), 256, 0, stream>>>(xyb, pwb, proj_b, h);

    for (int i = 0; i < N_LAYER; ++i) {
        const ushort* iwb  = iwb4  + (size_t)i * 2 * D_INNER * D_MODEL;
        const ushort* owb  = owb4  + (size_t)i * D_MODEL * D_INNER;
        const ushort* xpwb = xpwb4 + (size_t)i * 64 * D_INNER;
        const ushort* dtwb = dtwb4 + (size_t)i * D_INNER * DT_RANK;

        rmsnorm_k<true><<<M_ROWS, 256, 0, stream>>>(h, norm_w + (size_t)i * D_MODEL, nullptr, xnb);

        // xr(bf16) = xn @ in_w^T   (m97 structure, BN=128)
        gemm_gl<128, 2 * D_INNER, D_MODEL, false, false, true>
            <<<dim3(2 * D_INNER / 128, M_ROWS / 128), 256, 0, stream>>>(xnb, iwb, nullptr, xrb);

        conv_silu_k<<<M_ROWS * D_INNER / 4 / 256, 256, 0, stream>>>(
            xrb, conv_w + (size_t)i * D_INNER * D_CONV, conv_b + (size_t)i * D_INNER, xsb);

        // dbc partials = xs @ xproj_w^T, split-K=4
        gemm_bf16<128, 32, false, false, 0, false><<<dim3(2, M_ROWS / 128, 4), 256, 0, stream>>>(
            xsb, xpwb, nullptr, dpart, M_ROWS, 64, D_INNER / 4, D_INNER, D_INNER);
        reduce_dbc_k<<<M_ROWS * 64 / 256, 256, 0, stream>>>(dpart, dbc, dltb);

        // dltS(bf16) = softplus(delta @ dt_w^T + dt_b)
        gemm_bf16<64, 64, true, false, 1, true><<<dim3(D_INNER / 64, M_ROWS / 64), 256, 0, stream>>>(
            dltb, dtwb, dt_b + (size_t)i * D_INNER, dltS, M_ROWS, D_INNER, DT_RANK, DT_RANK, DT_RANK);

        scan1_k<<<BB * NCHUNK * (D_INNER / 64), 256, 0, stream>>>(
            dltS, xsb, dbc, A_log + (size_t)i * D_INNER * D_STATE, cbuf);
        scan2_k<<<BB * NCHUNK * (D_INNER / 64), 256, 0, stream>>>(
            dltS, xsb, dbc, xrb, A_log + (size_t)i * D_INNER * D_STATE,
            Dp + (size_t)i * D_INNER, cbuf, xyb);

        // h += y @ out_w^T   (m97 structure, BN=64)
        gemm_gl<64, D_MODEL, D_INNER, false, true, false>
            <<<dim3(D_MODEL / 64, M_ROWS / 128), 256, 0, stream>>>(xyb, owb, nullptr, h);
    }

    rmsnorm_k<false><<<M_ROWS, 256, 0, stream>>>(h, final_norm_w, fnorm, nullptr);
    stats_k<<<BB, D_MODEL, 0, stream>>>(fnorm, (float*)d_out);
}